// Round 1
// baseline (636.543 us; speedup 1.0000x reference)
//
#include <hip/hip_runtime.h>
#include <hip/hip_bf16.h>

#define DIM 768
#define NE 64
#define NFRQ 2048
#define NB 32
#define KDIM 1536               // 2*DIM (Re rows then Im rows)
#define TWO_PI 6.283185307179586f
#define SCALE (300.0f / (float)(DIM * DIM))   // ALPHA / (dim*dim), folded into values

typedef __attribute__((ext_vector_type(8))) short bf16x8;   // 8 bf16 (4 VGPRs)
typedef __attribute__((ext_vector_type(4))) float f32x4;    // MFMA accumulator

// ---------------------------------------------------------------------------
// Kernel 0: router — logits = cls @ W^T + b, top-2, pairwise softmax weights
// ---------------------------------------------------------------------------
__global__ void router_kernel(const float* __restrict__ cls,
                              const float* __restrict__ W,
                              const float* __restrict__ bias,
                              int* __restrict__ sel_e, float* __restrict__ sel_w) {
  int b = blockIdx.x;
  __shared__ float logits[NE];
  int e = threadIdx.x;            // 64 threads
  const float* c = cls + b * DIM;
  const float* w = W + e * DIM;
  float acc = 0.f;
  for (int i = 0; i < DIM; ++i) acc += c[i] * w[i];
  logits[e] = acc + bias[e];
  __syncthreads();
  if (e == 0) {
    int i0 = 0; float l0 = logits[0];
    for (int i = 1; i < NE; ++i) { float v = logits[i]; if (v > l0) { l0 = v; i0 = i; } }
    int i1 = -1; float l1 = -3.4e38f;
    for (int i = 0; i < NE; ++i) {
      if (i == i0) continue;
      float v = logits[i]; if (v > l1) { l1 = v; i1 = i; }
    }
    // softmax->topk->renormalize == pairwise softmax of the two top logits
    float w0 = 1.f / (1.f + expf(l1 - l0));
    sel_e[b * 2]     = i0; sel_e[b * 2 + 1] = i1;
    sel_w[b * 2]     = w0; sel_w[b * 2 + 1] = 1.f - w0;
  }
}

// ---------------------------------------------------------------------------
// Kernel 1: bucket-sort the 4096 nonzeros of each batch by grid row
// ---------------------------------------------------------------------------
__global__ void build_kernel(const float* __restrict__ coeff,
                             const int* __restrict__ lidx,
                             const int* __restrict__ sel_e,
                             const float* __restrict__ sel_w,
                             int* __restrict__ row_start,   // [NB][DIM+1]
                             int* __restrict__ s_col,       // [NB][4096]
                             float* __restrict__ s_val) {   // [NB][4096]
  int b = blockIdx.x;
  __shared__ int cnt[DIM];
  __shared__ int base[DIM];
  for (int i = threadIdx.x; i < DIM; i += blockDim.x) cnt[i] = 0;
  __syncthreads();
  int e0 = sel_e[b * 2], e1 = sel_e[b * 2 + 1];
  float w0 = sel_w[b * 2], w1 = sel_w[b * 2 + 1];
  for (int k = threadIdx.x; k < 2 * NFRQ; k += blockDim.x) {
    int t = k >> 11, j = k & (NFRQ - 1);
    int e = t ? e1 : e0;
    int f = lidx[e * NFRQ + j];
    atomicAdd(&cnt[f / DIM], 1);
  }
  __syncthreads();
  if (threadIdx.x == 0) {
    int acc = 0;
    for (int i = 0; i < DIM; ++i) {
      base[i] = acc;
      row_start[b * (DIM + 1) + i] = acc;
      acc += cnt[i];
    }
    row_start[b * (DIM + 1) + DIM] = acc;   // == 4096
  }
  __syncthreads();
  for (int i = threadIdx.x; i < DIM; i += blockDim.x) cnt[i] = 0;
  __syncthreads();
  for (int k = threadIdx.x; k < 2 * NFRQ; k += blockDim.x) {
    int t = k >> 11, j = k & (NFRQ - 1);
    int e = t ? e1 : e0;
    float w = t ? w1 : w0;
    int f = lidx[e * NFRQ + j];
    int r = f / DIM, c = f - r * DIM;
    int pos = base[r] + atomicAdd(&cnt[r], 1);
    s_col[b * 4096 + pos] = c;
    s_val[b * 4096 + pos] = coeff[e * NFRQ + j] * w * SCALE;
  }
}

// ---------------------------------------------------------------------------
// Kernel 2: twiddle matrix A[y][k] bf16: k<768 -> cos(2πyk/768); k>=768 -> -sin
// ---------------------------------------------------------------------------
__global__ void twiddle_kernel(__hip_bfloat16* __restrict__ A) {
  int y = blockIdx.x;
  for (int r = threadIdx.x; r < DIM; r += blockDim.x) {
    int m = (y * r) % DIM;
    float s, c;
    sincosf((TWO_PI / (float)DIM) * (float)m, &s, &c);
    A[y * KDIM + r]       = __float2bfloat16(c);
    A[y * KDIM + DIM + r] = __float2bfloat16(-s);
  }
}

// ---------------------------------------------------------------------------
// Kernel 3: stage-1 sparse DFT along x, output directly in B^T layout:
// BT[b][x][r] = Re(inter[r,x]), BT[b][x][768+r] = Im(inter[r,x])   (bf16)
// Each thread: one x, 8 consecutive rows -> one 16B Re store + one 16B Im store
// ---------------------------------------------------------------------------
__global__ void stage1_kernel(const int* __restrict__ row_start,
                              const int* __restrict__ s_col,
                              const float* __restrict__ s_val,
                              __hip_bfloat16* __restrict__ BT) {
  int b = blockIdx.y;
  int x0 = blockIdx.x * 64;
  __shared__ float2 tw[DIM];
  for (int i = threadIdx.x; i < DIM; i += 256) {
    float s, c;
    sincosf((TWO_PI / (float)DIM) * (float)i, &s, &c);
    tw[i] = make_float2(c, s);
  }
  __syncthreads();
  const int* rs = row_start + b * (DIM + 1);
  const int* sc = s_col + b * 4096;
  const float* sv = s_val + b * 4096;
  for (int u = threadIdx.x; u < 64 * 96; u += 256) {
    int x_local = u / 96;
    int oct = u % 96;           // consecutive lanes -> consecutive octs (coalesced stores)
    int x = x0 + x_local;
    int r0 = oct * 8;
    float re[8], im[8];
#pragma unroll
    for (int i = 0; i < 8; ++i) { re[i] = 0.f; im[i] = 0.f; }
#pragma unroll
    for (int i = 0; i < 8; ++i) {
      int s = rs[r0 + i], e = rs[r0 + i + 1];
      for (int p = s; p < e; ++p) {
        int c = sc[p];
        float v = sv[p];
        int m = (c * x) % DIM;
        float2 t = tw[m];
        re[i] += v * t.x;
        im[i] += v * t.y;
      }
    }
    union { __hip_bfloat16 h[8]; uint4 v4; } ure, uim;
#pragma unroll
    for (int i = 0; i < 8; ++i) {
      ure.h[i] = __float2bfloat16(re[i]);
      uim.h[i] = __float2bfloat16(im[i]);
    }
    __hip_bfloat16* dst = BT + ((size_t)(b * DIM + x)) * KDIM + r0;
    *(uint4*)(dst)       = ure.v4;
    *(uint4*)(dst + DIM) = uim.v4;
  }
}

// ---------------------------------------------------------------------------
// Kernel 4: out[b] = A[768x1536] * BT[b]^T  (m97-structure gemm_bt, 128² tile)
// A row-major [M=768][K=1536], BT row-major [N=768][K=1536] per batch.
// ---------------------------------------------------------------------------
__device__ inline void gload_lds16(const void* g, void* l) {
  __builtin_amdgcn_global_load_lds((const __attribute__((address_space(1))) void*)g,
                                   (__attribute__((address_space(3))) void*)l, 16, 0, 0);
}

__global__ __launch_bounds__(256) void gemm_kernel(const __hip_bfloat16* __restrict__ A,
                                                   const __hip_bfloat16* __restrict__ BT,
                                                   float* __restrict__ C) {
  int bx = blockIdx.x;            // n tile (x)
  int by = blockIdx.y;            // m tile (y)
  int b  = blockIdx.z;            // batch
  const __hip_bfloat16* Bp = BT + (size_t)b * DIM * KDIM;
  float* Cp = C + (size_t)b * DIM * DIM;
  int y0 = by * 128, x0 = bx * 128;

  __shared__ __align__(16) __hip_bfloat16 As[128 * 32];
  __shared__ __align__(16) __hip_bfloat16 Bs[128 * 32];

  int tid = threadIdx.x;
  int wv = tid >> 6, lane = tid & 63;
  int wr = wv >> 1, wc = wv & 1;        // wave quadrant (64x64)
  int lhi = lane >> 4, llo = lane & 15;

  f32x4 acc[4][4] = {};

  for (int kt = 0; kt < KDIM; kt += 32) {
#pragma unroll
    for (int h = 0; h < 2; ++h) {
      int chunk = tid + h * 256;            // 512 chunks of 16B per 8KB tile
      int row = chunk >> 2, off = (chunk & 3) * 8;
      gload_lds16(A  + (size_t)(y0 + row) * KDIM + kt + off, As + chunk * 8);
      gload_lds16(Bp + (size_t)(x0 + row) * KDIM + kt + off, Bs + chunk * 8);
    }
    __syncthreads();
    bf16x8 af[4], bfr[4];
#pragma unroll
    for (int i = 0; i < 4; ++i) {
      int ar = wr * 64 + i * 16 + llo;
      af[i] = *(const bf16x8*)(As + ar * 32 + lhi * 8);
      int br = wc * 64 + i * 16 + llo;
      bfr[i] = *(const bf16x8*)(Bs + br * 32 + lhi * 8);
    }
#pragma unroll
    for (int i = 0; i < 4; ++i)
#pragma unroll
      for (int j = 0; j < 4; ++j)
        acc[i][j] = __builtin_amdgcn_mfma_f32_16x16x32_bf16(af[i], bfr[j], acc[i][j], 0, 0, 0);
    __syncthreads();
  }
  // C/D layout: col = lane&15, row = (lane>>4)*4 + reg   [m89-verified]
#pragma unroll
  for (int i = 0; i < 4; ++i) {
    int row_base = y0 + wr * 64 + i * 16 + lhi * 4;
#pragma unroll
    for (int j = 0; j < 4; ++j) {
      int col = x0 + wc * 64 + j * 16 + llo;
#pragma unroll
      for (int q = 0; q < 4; ++q)
        Cp[(size_t)(row_base + q) * DIM + col] = acc[i][j][q];
    }
  }
}

// ---------------------------------------------------------------------------
extern "C" void kernel_launch(void* const* d_in, const int* in_sizes, int n_in,
                              void* d_out, int out_size, void* d_ws, size_t ws_size,
                              hipStream_t stream) {
  const float* cls   = (const float*)d_in[0];
  const float* Wr    = (const float*)d_in[1];
  const float* br    = (const float*)d_in[2];
  const float* coeff = (const float*)d_in[3];
  const int*   lidx  = (const int*)d_in[4];
  float* out = (float*)d_out;

  char* ws = (char*)d_ws;
  // ws layout (bytes):
  int*   sel_e     = (int*)(ws + 0);          //      256
  float* sel_w     = (float*)(ws + 256);      //      256
  int*   row_start = (int*)(ws + 512);        //   98,432
  int*   s_col     = (int*)(ws + 99328);      //  524,288
  float* s_val     = (float*)(ws + 623616);   //  524,288
  __hip_bfloat16* A  = (__hip_bfloat16*)(ws + 1147904);  // 2,359,296
  __hip_bfloat16* BT = (__hip_bfloat16*)(ws + 3507200);  // 75,497,472  (total ~79 MB)

  router_kernel<<<NB, 64, 0, stream>>>(cls, Wr, br, sel_e, sel_w);
  build_kernel<<<NB, 256, 0, stream>>>(coeff, lidx, sel_e, sel_w, row_start, s_col, s_val);
  twiddle_kernel<<<DIM, 256, 0, stream>>>(A);
  stage1_kernel<<<dim3(12, NB), 256, 0, stream>>>(row_start, s_col, s_val, BT);
  gemm_kernel<<<dim3(6, 6, NB), 256, 0, stream>>>(A, BT, out);
}

// Round 2
// 422.811 us; speedup vs baseline: 1.5055x; 1.5055x over previous
//
#include <hip/hip_runtime.h>
#include <hip/hip_bf16.h>

#define DIM 768
#define NE 64
#define NFRQ 2048
#define NB 32
#define KDIM 1536               // 2*DIM (Re rows then Im rows)
#define TWO_PI 6.283185307179586f
#define INV768 (1.0f / 768.0f)
#define SCALE (300.0f / (float)(DIM * DIM))   // ALPHA / (dim*dim), folded into values

typedef __attribute__((ext_vector_type(8))) short bf16x8;   // 8 bf16 (4 VGPRs)
typedef __attribute__((ext_vector_type(4))) float f32x4;    // MFMA accumulator

// ---------------------------------------------------------------------------
// Kernel 0: router — logits = cls @ W^T + b, top-2, pairwise softmax weights
// ---------------------------------------------------------------------------
__global__ void router_kernel(const float* __restrict__ cls,
                              const float* __restrict__ W,
                              const float* __restrict__ bias,
                              int* __restrict__ sel_e, float* __restrict__ sel_w) {
  int b = blockIdx.x;
  __shared__ float logits[NE];
  int e = threadIdx.x;            // 64 threads
  const float* c = cls + b * DIM;
  const float* w = W + e * DIM;
  float acc = 0.f;
  for (int i = 0; i < DIM; ++i) acc += c[i] * w[i];
  logits[e] = acc + bias[e];
  __syncthreads();
  if (e == 0) {
    int i0 = 0; float l0 = logits[0];
    for (int i = 1; i < NE; ++i) { float v = logits[i]; if (v > l0) { l0 = v; i0 = i; } }
    int i1 = -1; float l1 = -3.4e38f;
    for (int i = 0; i < NE; ++i) {
      if (i == i0) continue;
      float v = logits[i]; if (v > l1) { l1 = v; i1 = i; }
    }
    // softmax->topk->renormalize == pairwise softmax of the two top logits
    float w0 = 1.f / (1.f + expf(l1 - l0));
    sel_e[b * 2]     = i0; sel_e[b * 2 + 1] = i1;
    sel_w[b * 2]     = w0; sel_w[b * 2 + 1] = 1.f - w0;
  }
}

// ---------------------------------------------------------------------------
// Kernel 1: bucket-sort the 4096 nonzeros of each batch by grid row.
// Store (col-as-float, weighted value) interleaved for 8B inner-loop loads.
// ---------------------------------------------------------------------------
__global__ void build_kernel(const float* __restrict__ coeff,
                             const int* __restrict__ lidx,
                             const int* __restrict__ sel_e,
                             const float* __restrict__ sel_w,
                             int* __restrict__ row_start,   // [NB][DIM+1]
                             float2* __restrict__ s_cv) {   // [NB][4096] (colf, val)
  int b = blockIdx.x;
  __shared__ int cnt[DIM];
  __shared__ int base[DIM];
  for (int i = threadIdx.x; i < DIM; i += blockDim.x) cnt[i] = 0;
  __syncthreads();
  int e0 = sel_e[b * 2], e1 = sel_e[b * 2 + 1];
  float w0 = sel_w[b * 2], w1 = sel_w[b * 2 + 1];
  for (int k = threadIdx.x; k < 2 * NFRQ; k += blockDim.x) {
    int t = k >> 11, j = k & (NFRQ - 1);
    int e = t ? e1 : e0;
    int f = lidx[e * NFRQ + j];
    atomicAdd(&cnt[f / DIM], 1);
  }
  __syncthreads();
  if (threadIdx.x == 0) {
    int acc = 0;
    for (int i = 0; i < DIM; ++i) {
      base[i] = acc;
      row_start[b * (DIM + 1) + i] = acc;
      acc += cnt[i];
    }
    row_start[b * (DIM + 1) + DIM] = acc;   // == 4096
  }
  __syncthreads();
  for (int i = threadIdx.x; i < DIM; i += blockDim.x) cnt[i] = 0;
  __syncthreads();
  for (int k = threadIdx.x; k < 2 * NFRQ; k += blockDim.x) {
    int t = k >> 11, j = k & (NFRQ - 1);
    int e = t ? e1 : e0;
    float w = t ? w1 : w0;
    int f = lidx[e * NFRQ + j];
    int r = f / DIM, c = f - r * DIM;
    int pos = base[r] + atomicAdd(&cnt[r], 1);
    s_cv[b * 4096 + pos] = make_float2((float)c, coeff[e * NFRQ + j] * w * SCALE);
  }
}

// ---------------------------------------------------------------------------
// Kernel 2: twiddle matrix A[y][k] bf16: k<768 -> cos(2πyk/768); k>=768 -> -sin
// ---------------------------------------------------------------------------
__global__ void twiddle_kernel(__hip_bfloat16* __restrict__ A) {
  int y = blockIdx.x;
  for (int r = threadIdx.x; r < DIM; r += blockDim.x) {
    int m = (y * r) % DIM;
    float s, c;
    sincosf((TWO_PI / (float)DIM) * (float)m, &s, &c);
    A[y * KDIM + r]       = __float2bfloat16(c);
    A[y * KDIM + DIM + r] = __float2bfloat16(-s);
  }
}

// ---------------------------------------------------------------------------
// Kernel 3: stage-1 sparse DFT along x, output directly in B^T layout:
// BT[b][x][r] = Re(inter[r,x]), BT[b][x][768+r] = Im(inter[r,x])   (bf16)
// v2: no LDS table — direct v_sin/v_cos (revolutions), c*x exact in fp32
// (< 2^24). 4x grid for occupancy. Inner loop has NO memory latency on the
// critical path (cv loads are L1-resident: 32KB/batch).
// ---------------------------------------------------------------------------
__global__ void stage1_kernel(const int* __restrict__ row_start,
                              const float2* __restrict__ s_cv,
                              __hip_bfloat16* __restrict__ BT) {
  int b = blockIdx.y;
  int x0 = blockIdx.x * 16;                 // 16 x-values per block, 48 x-blocks
  const int* rs = row_start + b * (DIM + 1);
  const float2* cv = s_cv + b * 4096;
  for (int u = threadIdx.x; u < 16 * 96; u += 256) {
    int x_local = u / 96;
    int oct = u % 96;          // consecutive lanes -> consecutive octs (coalesced stores)
    float xf = (float)(x0 + x_local);
    int r0 = oct * 8;
    float re[8], im[8];
#pragma unroll
    for (int i = 0; i < 8; ++i) { re[i] = 0.f; im[i] = 0.f; }
#pragma unroll
    for (int i = 0; i < 8; ++i) {
      int s = rs[r0 + i], e = rs[r0 + i + 1];
      for (int p = s; p < e; ++p) {
        float2 c = cv[p];
        float rev = (c.x * xf) * INV768;    // c.x*xf integral, < 2^24 -> exact
        float f, sn, cs;
        asm("v_fract_f32 %0, %1" : "=v"(f) : "v"(rev));
        asm("v_sin_f32 %0, %1" : "=v"(sn) : "v"(f));   // sin(2*pi*f)
        asm("v_cos_f32 %0, %1" : "=v"(cs) : "v"(f));   // cos(2*pi*f)
        re[i] += c.y * cs;
        im[i] += c.y * sn;
      }
    }
    union { __hip_bfloat16 h[8]; uint4 v4; } ure, uim;
#pragma unroll
    for (int i = 0; i < 8; ++i) {
      ure.h[i] = __float2bfloat16(re[i]);
      uim.h[i] = __float2bfloat16(im[i]);
    }
    __hip_bfloat16* dst = BT + ((size_t)(b * DIM + x0 + x_local)) * KDIM + r0;
    *(uint4*)(dst)       = ure.v4;
    *(uint4*)(dst + DIM) = uim.v4;
  }
}

// ---------------------------------------------------------------------------
// Kernel 4: out[b] = A[768x1536] * BT[b]^T  (m97-structure gemm_bt, 128² tile)
// A row-major [M=768][K=1536], BT row-major [N=768][K=1536] per batch.
// ---------------------------------------------------------------------------
__device__ inline void gload_lds16(const void* g, void* l) {
  __builtin_amdgcn_global_load_lds((const __attribute__((address_space(1))) void*)g,
                                   (__attribute__((address_space(3))) void*)l, 16, 0, 0);
}

__global__ __launch_bounds__(256) void gemm_kernel(const __hip_bfloat16* __restrict__ A,
                                                   const __hip_bfloat16* __restrict__ BT,
                                                   float* __restrict__ C) {
  int bx = blockIdx.x;            // n tile (x)
  int by = blockIdx.y;            // m tile (y)
  int b  = blockIdx.z;            // batch
  const __hip_bfloat16* Bp = BT + (size_t)b * DIM * KDIM;
  float* Cp = C + (size_t)b * DIM * DIM;
  int y0 = by * 128, x0 = bx * 128;

  __shared__ __align__(16) __hip_bfloat16 As[128 * 32];
  __shared__ __align__(16) __hip_bfloat16 Bs[128 * 32];

  int tid = threadIdx.x;
  int wv = tid >> 6, lane = tid & 63;
  int wr = wv >> 1, wc = wv & 1;        // wave quadrant (64x64)
  int lhi = lane >> 4, llo = lane & 15;

  f32x4 acc[4][4] = {};

  for (int kt = 0; kt < KDIM; kt += 32) {
#pragma unroll
    for (int h = 0; h < 2; ++h) {
      int chunk = tid + h * 256;            // 512 chunks of 16B per 8KB tile
      int row = chunk >> 2, off = (chunk & 3) * 8;
      gload_lds16(A  + (size_t)(y0 + row) * KDIM + kt + off, As + chunk * 8);
      gload_lds16(Bp + (size_t)(x0 + row) * KDIM + kt + off, Bs + chunk * 8);
    }
    __syncthreads();
    bf16x8 af[4], bfr[4];
#pragma unroll
    for (int i = 0; i < 4; ++i) {
      int ar = wr * 64 + i * 16 + llo;
      af[i] = *(const bf16x8*)(As + ar * 32 + lhi * 8);
      int br = wc * 64 + i * 16 + llo;
      bfr[i] = *(const bf16x8*)(Bs + br * 32 + lhi * 8);
    }
#pragma unroll
    for (int i = 0; i < 4; ++i)
#pragma unroll
      for (int j = 0; j < 4; ++j)
        acc[i][j] = __builtin_amdgcn_mfma_f32_16x16x32_bf16(af[i], bfr[j], acc[i][j], 0, 0, 0);
    __syncthreads();
  }
  // C/D layout: col = lane&15, row = (lane>>4)*4 + reg   [m89-verified]
#pragma unroll
  for (int i = 0; i < 4; ++i) {
    int row_base = y0 + wr * 64 + i * 16 + lhi * 4;
#pragma unroll
    for (int j = 0; j < 4; ++j) {
      int col = x0 + wc * 64 + j * 16 + llo;
#pragma unroll
      for (int q = 0; q < 4; ++q)
        Cp[(size_t)(row_base + q) * DIM + col] = acc[i][j][q];
    }
  }
}

// ---------------------------------------------------------------------------
extern "C" void kernel_launch(void* const* d_in, const int* in_sizes, int n_in,
                              void* d_out, int out_size, void* d_ws, size_t ws_size,
                              hipStream_t stream) {
  const float* cls   = (const float*)d_in[0];
  const float* Wr    = (const float*)d_in[1];
  const float* br    = (const float*)d_in[2];
  const float* coeff = (const float*)d_in[3];
  const int*   lidx  = (const int*)d_in[4];
  float* out = (float*)d_out;

  char* ws = (char*)d_ws;
  // ws layout (bytes):
  int*    sel_e     = (int*)(ws + 0);          //      256
  float*  sel_w     = (float*)(ws + 256);      //      256
  int*    row_start = (int*)(ws + 512);        //   98,432  (ends 98,944)
  float2* s_cv      = (float2*)(ws + 98944);   // 1,048,576 (ends 1,147,520)
  __hip_bfloat16* A  = (__hip_bfloat16*)(ws + 1147520);  // 2,359,296 (ends 3,506,816)
  __hip_bfloat16* BT = (__hip_bfloat16*)(ws + 3506816);  // 75,497,472 (~79 MB total)

  router_kernel<<<NB, 64, 0, stream>>>(cls, Wr, br, sel_e, sel_w);
  build_kernel<<<NB, 256, 0, stream>>>(coeff, lidx, sel_e, sel_w, row_start, s_cv);
  twiddle_kernel<<<DIM, 256, 0, stream>>>(A);
  stage1_kernel<<<dim3(48, NB), 256, 0, stream>>>(row_start, s_cv, BT);
  gemm_kernel<<<dim3(6, 6, NB), 256, 0, stream>>>(A, BT, out);
}

// Round 3
// 252.010 us; speedup vs baseline: 2.5259x; 1.6778x over previous
//
#include <hip/hip_runtime.h>
#include <hip/hip_bf16.h>

#define DIM 768
#define NE 64
#define NFRQ 2048
#define NB 32
#define KDIM 1536               // 2*DIM (Re rows then Im rows)
#define TWO_PI 6.283185307179586f
#define INV768 (1.0f / 768.0f)
#define SCALE (300.0f / (float)(DIM * DIM))   // ALPHA / (dim*dim), folded into values

typedef __attribute__((ext_vector_type(8))) short bf16x8;   // 8 bf16 (4 VGPRs)
typedef __attribute__((ext_vector_type(4))) float f32x4;    // MFMA accumulator

// ---------------------------------------------------------------------------
// Kernel 0: router — logits = cls @ W^T + b, top-2, pairwise softmax weights
// ---------------------------------------------------------------------------
__global__ void router_kernel(const float* __restrict__ cls,
                              const float* __restrict__ W,
                              const float* __restrict__ bias,
                              int* __restrict__ sel_e, float* __restrict__ sel_w) {
  int b = blockIdx.x;
  __shared__ float logits[NE];
  int e = threadIdx.x;            // 64 threads
  const float* c = cls + b * DIM;
  const float* w = W + e * DIM;
  float acc = 0.f;
  for (int i = 0; i < DIM; ++i) acc += c[i] * w[i];
  logits[e] = acc + bias[e];
  __syncthreads();
  if (e == 0) {
    int i0 = 0; float l0 = logits[0];
    for (int i = 1; i < NE; ++i) { float v = logits[i]; if (v > l0) { l0 = v; i0 = i; } }
    int i1 = -1; float l1 = -3.4e38f;
    for (int i = 0; i < NE; ++i) {
      if (i == i0) continue;
      float v = logits[i]; if (v > l1) { l1 = v; i1 = i; }
    }
    // softmax->topk->renormalize == pairwise softmax of the two top logits
    float w0 = 1.f / (1.f + expf(l1 - l0));
    sel_e[b * 2]     = i0; sel_e[b * 2 + 1] = i1;
    sel_w[b * 2]     = w0; sel_w[b * 2 + 1] = 1.f - w0;
  }
}

// ---------------------------------------------------------------------------
// Kernel 1: bucket-sort the 4096 nonzeros of each batch by grid row.
// Store (col-as-float, weighted value) interleaved for 8B inner-loop loads.
// ---------------------------------------------------------------------------
__global__ void build_kernel(const float* __restrict__ coeff,
                             const int* __restrict__ lidx,
                             const int* __restrict__ sel_e,
                             const float* __restrict__ sel_w,
                             int* __restrict__ row_start,   // [NB][DIM+1]
                             float2* __restrict__ s_cv) {   // [NB][4096] (colf, val)
  int b = blockIdx.x;
  __shared__ int cnt[DIM];
  __shared__ int base[DIM];
  for (int i = threadIdx.x; i < DIM; i += blockDim.x) cnt[i] = 0;
  __syncthreads();
  int e0 = sel_e[b * 2], e1 = sel_e[b * 2 + 1];
  float w0 = sel_w[b * 2], w1 = sel_w[b * 2 + 1];
  for (int k = threadIdx.x; k < 2 * NFRQ; k += blockDim.x) {
    int t = k >> 11, j = k & (NFRQ - 1);
    int e = t ? e1 : e0;
    int f = lidx[e * NFRQ + j];
    atomicAdd(&cnt[f / DIM], 1);
  }
  __syncthreads();
  if (threadIdx.x == 0) {
    int acc = 0;
    for (int i = 0; i < DIM; ++i) {
      base[i] = acc;
      row_start[b * (DIM + 1) + i] = acc;
      acc += cnt[i];
    }
    row_start[b * (DIM + 1) + DIM] = acc;   // == 4096
  }
  __syncthreads();
  for (int i = threadIdx.x; i < DIM; i += blockDim.x) cnt[i] = 0;
  __syncthreads();
  for (int k = threadIdx.x; k < 2 * NFRQ; k += blockDim.x) {
    int t = k >> 11, j = k & (NFRQ - 1);
    int e = t ? e1 : e0;
    float w = t ? w1 : w0;
    int f = lidx[e * NFRQ + j];
    int r = f / DIM, c = f - r * DIM;
    int pos = base[r] + atomicAdd(&cnt[r], 1);
    s_cv[b * 4096 + pos] = make_float2((float)c, coeff[e * NFRQ + j] * w * SCALE);
  }
}

// ---------------------------------------------------------------------------
// Kernel 2: twiddle matrix A[y][k] bf16: k<768 -> cos(2πyk/768); k>=768 -> -sin
// ---------------------------------------------------------------------------
__global__ void twiddle_kernel(__hip_bfloat16* __restrict__ A) {
  int y = blockIdx.x;
  for (int r = threadIdx.x; r < DIM; r += blockDim.x) {
    int m = (y * r) % DIM;
    float s, c;
    sincosf((TWO_PI / (float)DIM) * (float)m, &s, &c);
    A[y * KDIM + r]       = __float2bfloat16(c);
    A[y * KDIM + DIM + r] = __float2bfloat16(-s);
  }
}

// ---------------------------------------------------------------------------
// Kernel 3 (v3): stage-1 sparse DFT, wave-uniform nonzero stream.
// One wave handles 128 x-values (2 per lane: x and x+64) and 48 rows.
// All 64 lanes walk the SAME rows' nonzeros in lockstep:
//   - cv[p] load is wave-uniform -> 1-cacheline broadcast, no scatter
//   - loop bounds wave-uniform -> zero divergence
//   - 2 x per lane -> 2x arithmetic per load (latency amortization)
// Accumulators are compile-time indexed (8-row register rounds).
// Grid: (6 x-groups, 4 row-quads, 32 batches), 256 thr = 4 waves
// (wave w takes row-group by*4+w) -> 768 blocks = 3/CU.
// ---------------------------------------------------------------------------
__global__ __launch_bounds__(256) void stage1_kernel(const int* __restrict__ row_start,
                                                     const float2* __restrict__ s_cv,
                                                     __hip_bfloat16* __restrict__ BT) {
  int b = blockIdx.z;
  int lane = threadIdx.x & 63;
  int wv = threadIdx.x >> 6;
  int rg = blockIdx.y * 4 + wv;             // row-group in [0,16): 48 rows each
  int x0 = blockIdx.x * 128 + lane;         // first x of this lane
  float xf0 = (float)x0;
  float xf1 = (float)(x0 + 64);
  const int* rs = row_start + b * (DIM + 1);
  const float2* cv = s_cv + b * 4096;

  __hip_bfloat16* bt0 = BT + ((size_t)(b * DIM + x0)) * KDIM;        // x row
  __hip_bfloat16* bt1 = bt0 + (size_t)64 * KDIM;                     // x+64 row

  for (int rnd = 0; rnd < 6; ++rnd) {
    int r0 = rg * 48 + rnd * 8;
    float re0[8], im0[8], re1[8], im1[8];
#pragma unroll
    for (int i = 0; i < 8; ++i) { re0[i] = im0[i] = re1[i] = im1[i] = 0.f; }
#pragma unroll
    for (int i = 0; i < 8; ++i) {
      int s = rs[r0 + i], e = rs[r0 + i + 1];      // wave-uniform bounds
      for (int p = s; p < e; ++p) {
        float2 c = cv[p];                          // wave-uniform -> broadcast
        float rev0 = (c.x * xf0) * INV768;         // c.x*xf integral, exact in f32
        float rev1 = (c.x * xf1) * INV768;
        float f0, f1, sn0, sn1, cs0, cs1;
        asm("v_fract_f32 %0, %1" : "=v"(f0) : "v"(rev0));
        asm("v_fract_f32 %0, %1" : "=v"(f1) : "v"(rev1));
        asm("v_sin_f32 %0, %1" : "=v"(sn0) : "v"(f0));   // sin(2*pi*f)
        asm("v_cos_f32 %0, %1" : "=v"(cs0) : "v"(f0));
        asm("v_sin_f32 %0, %1" : "=v"(sn1) : "v"(f1));
        asm("v_cos_f32 %0, %1" : "=v"(cs1) : "v"(f1));
        re0[i] += c.y * cs0; im0[i] += c.y * sn0;
        re1[i] += c.y * cs1; im1[i] += c.y * sn1;
      }
    }
    union { __hip_bfloat16 h[8]; uint4 v4; } u;
#pragma unroll
    for (int i = 0; i < 8; ++i) u.h[i] = __float2bfloat16(re0[i]);
    *(uint4*)(bt0 + r0) = u.v4;
#pragma unroll
    for (int i = 0; i < 8; ++i) u.h[i] = __float2bfloat16(im0[i]);
    *(uint4*)(bt0 + DIM + r0) = u.v4;
#pragma unroll
    for (int i = 0; i < 8; ++i) u.h[i] = __float2bfloat16(re1[i]);
    *(uint4*)(bt1 + r0) = u.v4;
#pragma unroll
    for (int i = 0; i < 8; ++i) u.h[i] = __float2bfloat16(im1[i]);
    *(uint4*)(bt1 + DIM + r0) = u.v4;
  }
}

// ---------------------------------------------------------------------------
// Kernel 4: out[b] = A[768x1536] * BT[b]^T  (m97-structure gemm_bt, 128² tile)
// A row-major [M=768][K=1536], BT row-major [N=768][K=1536] per batch.
// ---------------------------------------------------------------------------
__device__ inline void gload_lds16(const void* g, void* l) {
  __builtin_amdgcn_global_load_lds((const __attribute__((address_space(1))) void*)g,
                                   (__attribute__((address_space(3))) void*)l, 16, 0, 0);
}

__global__ __launch_bounds__(256) void gemm_kernel(const __hip_bfloat16* __restrict__ A,
                                                   const __hip_bfloat16* __restrict__ BT,
                                                   float* __restrict__ C) {
  int bx = blockIdx.x;            // n tile (x)
  int by = blockIdx.y;            // m tile (y)
  int b  = blockIdx.z;            // batch
  const __hip_bfloat16* Bp = BT + (size_t)b * DIM * KDIM;
  float* Cp = C + (size_t)b * DIM * DIM;
  int y0 = by * 128, x0 = bx * 128;

  __shared__ __align__(16) __hip_bfloat16 As[128 * 32];
  __shared__ __align__(16) __hip_bfloat16 Bs[128 * 32];

  int tid = threadIdx.x;
  int wv = tid >> 6, lane = tid & 63;
  int wr = wv >> 1, wc = wv & 1;        // wave quadrant (64x64)
  int lhi = lane >> 4, llo = lane & 15;

  f32x4 acc[4][4] = {};

  for (int kt = 0; kt < KDIM; kt += 32) {
#pragma unroll
    for (int h = 0; h < 2; ++h) {
      int chunk = tid + h * 256;            // 512 chunks of 16B per 8KB tile
      int row = chunk >> 2, off = (chunk & 3) * 8;
      gload_lds16(A  + (size_t)(y0 + row) * KDIM + kt + off, As + chunk * 8);
      gload_lds16(Bp + (size_t)(x0 + row) * KDIM + kt + off, Bs + chunk * 8);
    }
    __syncthreads();
    bf16x8 af[4], bfr[4];
#pragma unroll
    for (int i = 0; i < 4; ++i) {
      int ar = wr * 64 + i * 16 + llo;
      af[i] = *(const bf16x8*)(As + ar * 32 + lhi * 8);
      int br = wc * 64 + i * 16 + llo;
      bfr[i] = *(const bf16x8*)(Bs + br * 32 + lhi * 8);
    }
#pragma unroll
    for (int i = 0; i < 4; ++i)
#pragma unroll
      for (int j = 0; j < 4; ++j)
        acc[i][j] = __builtin_amdgcn_mfma_f32_16x16x32_bf16(af[i], bfr[j], acc[i][j], 0, 0, 0);
    __syncthreads();
  }
  // C/D layout: col = lane&15, row = (lane>>4)*4 + reg   [m89-verified]
#pragma unroll
  for (int i = 0; i < 4; ++i) {
    int row_base = y0 + wr * 64 + i * 16 + lhi * 4;
#pragma unroll
    for (int j = 0; j < 4; ++j) {
      int col = x0 + wc * 64 + j * 16 + llo;
#pragma unroll
      for (int q = 0; q < 4; ++q)
        Cp[(size_t)(row_base + q) * DIM + col] = acc[i][j][q];
    }
  }
}

// ---------------------------------------------------------------------------
extern "C" void kernel_launch(void* const* d_in, const int* in_sizes, int n_in,
                              void* d_out, int out_size, void* d_ws, size_t ws_size,
                              hipStream_t stream) {
  const float* cls   = (const float*)d_in[0];
  const float* Wr    = (const float*)d_in[1];
  const float* br    = (const float*)d_in[2];
  const float* coeff = (const float*)d_in[3];
  const int*   lidx  = (const int*)d_in[4];
  float* out = (float*)d_out;

  char* ws = (char*)d_ws;
  // ws layout (bytes):
  int*    sel_e     = (int*)(ws + 0);          //      256
  float*  sel_w     = (float*)(ws + 256);      //      256
  int*    row_start = (int*)(ws + 512);        //   98,432  (ends 98,944)
  float2* s_cv      = (float2*)(ws + 98944);   // 1,048,576 (ends 1,147,520)
  __hip_bfloat16* A  = (__hip_bfloat16*)(ws + 1147520);  // 2,359,296 (ends 3,506,816)
  __hip_bfloat16* BT = (__hip_bfloat16*)(ws + 3506816);  // 75,497,472 (~79 MB total)

  router_kernel<<<NB, 64, 0, stream>>>(cls, Wr, br, sel_e, sel_w);
  build_kernel<<<NB, 256, 0, stream>>>(coeff, lidx, sel_e, sel_w, row_start, s_cv);
  twiddle_kernel<<<DIM, 256, 0, stream>>>(A);
  stage1_kernel<<<dim3(6, 4, NB), 256, 0, stream>>>(row_start, s_cv, BT);
  gemm_kernel<<<dim3(6, 6, NB), 256, 0, stream>>>(A, BT, out);
}

// Round 4
// 222.081 us; speedup vs baseline: 2.8663x; 1.1348x over previous
//
#include <hip/hip_runtime.h>
#include <hip/hip_bf16.h>

#define DIM 768
#define NE 64
#define NFRQ 2048
#define NB 32
#define KDIM 1536               // 2*DIM (Re rows then -Im rows)
#define HALF 384                // computed quadrant extent (y,x in [0,384))
#define TWO_PI 6.283185307179586f
#define INV768 (1.0f / 768.0f)
#define SCALE (300.0f / (float)(DIM * DIM))   // ALPHA / (dim*dim), folded into values

typedef __attribute__((ext_vector_type(8))) short bf16x8;   // 8 bf16 (4 VGPRs)
typedef __attribute__((ext_vector_type(4))) float f32x4;    // MFMA accumulator
typedef __attribute__((ext_vector_type(4))) unsigned int u32x4;

static __device__ inline bf16x8 negbf8(bf16x8 v) {
  u32x4 u = __builtin_bit_cast(u32x4, v);
  u ^= 0x80008000u;
  return __builtin_bit_cast(bf16x8, u);
}

// ---------------------------------------------------------------------------
// Kernel 0: router — logits = cls @ W^T + b, top-2, pairwise softmax weights
// ---------------------------------------------------------------------------
__global__ void router_kernel(const float* __restrict__ cls,
                              const float* __restrict__ W,
                              const float* __restrict__ bias,
                              int* __restrict__ sel_e, float* __restrict__ sel_w) {
  int b = blockIdx.x;
  __shared__ float logits[NE];
  int e = threadIdx.x;            // 64 threads
  const float* c = cls + b * DIM;
  const float* w = W + e * DIM;
  float acc = 0.f;
  for (int i = 0; i < DIM; ++i) acc += c[i] * w[i];
  logits[e] = acc + bias[e];
  __syncthreads();
  if (e == 0) {
    int i0 = 0; float l0 = logits[0];
    for (int i = 1; i < NE; ++i) { float v = logits[i]; if (v > l0) { l0 = v; i0 = i; } }
    int i1 = -1; float l1 = -3.4e38f;
    for (int i = 0; i < NE; ++i) {
      if (i == i0) continue;
      float v = logits[i]; if (v > l1) { l1 = v; i1 = i; }
    }
    float w0 = 1.f / (1.f + expf(l1 - l0));
    sel_e[b * 2]     = i0; sel_e[b * 2 + 1] = i1;
    sel_w[b * 2]     = w0; sel_w[b * 2 + 1] = 1.f - w0;
  }
}

// ---------------------------------------------------------------------------
// Kernel 1: bucket-sort the 4096 nonzeros of each batch by grid row.
// ---------------------------------------------------------------------------
__global__ void build_kernel(const float* __restrict__ coeff,
                             const int* __restrict__ lidx,
                             const int* __restrict__ sel_e,
                             const float* __restrict__ sel_w,
                             int* __restrict__ row_start,   // [NB][DIM+1]
                             float2* __restrict__ s_cv) {   // [NB][4096] (colf, val)
  int b = blockIdx.x;
  __shared__ int cnt[DIM];
  __shared__ int base[DIM];
  for (int i = threadIdx.x; i < DIM; i += blockDim.x) cnt[i] = 0;
  __syncthreads();
  int e0 = sel_e[b * 2], e1 = sel_e[b * 2 + 1];
  float w0 = sel_w[b * 2], w1 = sel_w[b * 2 + 1];
  for (int k = threadIdx.x; k < 2 * NFRQ; k += blockDim.x) {
    int t = k >> 11, j = k & (NFRQ - 1);
    int e = t ? e1 : e0;
    int f = lidx[e * NFRQ + j];
    atomicAdd(&cnt[f / DIM], 1);
  }
  __syncthreads();
  if (threadIdx.x == 0) {
    int acc = 0;
    for (int i = 0; i < DIM; ++i) {
      base[i] = acc;
      row_start[b * (DIM + 1) + i] = acc;
      acc += cnt[i];
    }
    row_start[b * (DIM + 1) + DIM] = acc;   // == 4096
  }
  __syncthreads();
  for (int i = threadIdx.x; i < DIM; i += blockDim.x) cnt[i] = 0;
  __syncthreads();
  for (int k = threadIdx.x; k < 2 * NFRQ; k += blockDim.x) {
    int t = k >> 11, j = k & (NFRQ - 1);
    int e = t ? e1 : e0;
    float w = t ? w1 : w0;
    int f = lidx[e * NFRQ + j];
    int r = f / DIM, c = f - r * DIM;
    int pos = base[r] + atomicAdd(&cnt[r], 1);
    s_cv[b * 4096 + pos] = make_float2((float)c, coeff[e * NFRQ + j] * w * SCALE);
  }
}

// ---------------------------------------------------------------------------
// Kernel 2: twiddle A[y][k] bf16 for y=0..383: k<768 -> cos(2*pi*y*k/768);
// k>=768 -> +sin (the minus sign lives in BT's Im half).
// ---------------------------------------------------------------------------
__global__ void twiddle_kernel(__hip_bfloat16* __restrict__ A) {
  int y = blockIdx.x;             // 0..383
  for (int r = threadIdx.x; r < DIM; r += blockDim.x) {
    int m = (y * r) % DIM;
    float s, c;
    sincosf((TWO_PI / (float)DIM) * (float)m, &s, &c);
    A[y * KDIM + r]       = __float2bfloat16(c);
    A[y * KDIM + DIM + r] = __float2bfloat16(s);
  }
}

// ---------------------------------------------------------------------------
// Kernel 3 (v4): stage-1 sparse DFT for x=0..383 only (x-symmetry).
// BT[b][x][r] = Re(inter[r,x]), BT[b][x][768+r] = -Im(inter[r,x])   (bf16)
// Wave-uniform nonzero stream; 2 x per lane; upfront row-boundary loads;
// 1-ahead cv prefetch to break the load->use chain.
// Grid: (3 x-groups of 128, 8 rg-blocks, 32 b), 256 thr = 4 waves;
// wave rg = by*4+wv in [0,32): 24 rows each (3 rounds of 8).
// ---------------------------------------------------------------------------
__global__ __launch_bounds__(256) void stage1_kernel(const int* __restrict__ row_start,
                                                     const float2* __restrict__ s_cv,
                                                     __hip_bfloat16* __restrict__ BT) {
  int b = blockIdx.z;
  int lane = threadIdx.x & 63;
  int wv = threadIdx.x >> 6;
  int rg = blockIdx.y * 4 + wv;             // 0..31, 24 rows each
  int x0 = blockIdx.x * 128 + lane;         // 0..319 (+64 covers up to 383)
  float xf0 = (float)x0;
  float xf1 = (float)(x0 + 64);
  const int* rs = row_start + b * (DIM + 1);
  const float2* cv = s_cv + b * 4096;

  int rb[25];
#pragma unroll
  for (int t = 0; t < 25; ++t) rb[t] = rs[rg * 24 + t];   // all boundaries upfront

  __hip_bfloat16* bt0 = BT + ((size_t)(b * HALF + x0)) * KDIM;
  __hip_bfloat16* bt1 = bt0 + (size_t)64 * KDIM;

#pragma unroll
  for (int rnd = 0; rnd < 3; ++rnd) {
    int r0 = rg * 24 + rnd * 8;
    float re0[8], im0[8], re1[8], im1[8];
#pragma unroll
    for (int i = 0; i < 8; ++i) { re0[i] = im0[i] = re1[i] = im1[i] = 0.f; }
#pragma unroll
    for (int i = 0; i < 8; ++i) {
      int s = rb[rnd * 8 + i], e = rb[rnd * 8 + i + 1];
      if (s < e) {
        float2 c = cv[s];
        for (int p = s; p < e; ++p) {
          int pn = p + 1 < 4096 ? p + 1 : 4095;
          float2 cn = cv[pn];                    // prefetch next (may be dummy)
          float rev0 = (c.x * xf0) * INV768;     // integral product, exact in f32
          float rev1 = (c.x * xf1) * INV768;
          float f0, f1, sn0, sn1, cs0, cs1;
          asm("v_fract_f32 %0, %1" : "=v"(f0) : "v"(rev0));
          asm("v_fract_f32 %0, %1" : "=v"(f1) : "v"(rev1));
          asm("v_sin_f32 %0, %1" : "=v"(sn0) : "v"(f0));
          asm("v_cos_f32 %0, %1" : "=v"(cs0) : "v"(f0));
          asm("v_sin_f32 %0, %1" : "=v"(sn1) : "v"(f1));
          asm("v_cos_f32 %0, %1" : "=v"(cs1) : "v"(f1));
          re0[i] += c.y * cs0; im0[i] += c.y * sn0;
          re1[i] += c.y * cs1; im1[i] += c.y * sn1;
          c = cn;
        }
      }
    }
    union { __hip_bfloat16 h[8]; uint4 v4; } u;
#pragma unroll
    for (int i = 0; i < 8; ++i) u.h[i] = __float2bfloat16(re0[i]);
    *(uint4*)(bt0 + r0) = u.v4;
#pragma unroll
    for (int i = 0; i < 8; ++i) u.h[i] = __float2bfloat16(-im0[i]);   // store -Im
    *(uint4*)(bt0 + DIM + r0) = u.v4;
#pragma unroll
    for (int i = 0; i < 8; ++i) u.h[i] = __float2bfloat16(re1[i]);
    *(uint4*)(bt1 + r0) = u.v4;
#pragma unroll
    for (int i = 0; i < 8; ++i) u.h[i] = __float2bfloat16(-im1[i]);
    *(uint4*)(bt1 + DIM + r0) = u.v4;
  }
}

// ---------------------------------------------------------------------------
// Kernel 4 (v2): quadrant GEMM with dual accumulators + 4-way mirror epilogue.
// acc_d = A[cos|sin] . BT[Re|-Im]   = C1-C2 = out[y,x]   = out[-y,-x]
// acc_s = same but B negated on sin-half = C1+C2 = out[-y,x] = out[y,-x]
// BM=64 (y), BN=128 (x), K=1536, m97 2-barrier skeleton, XCD-swizzled grid.
// ---------------------------------------------------------------------------
__device__ inline void gload_lds16(const void* g, void* l) {
  __builtin_amdgcn_global_load_lds((const __attribute__((address_space(1))) void*)g,
                                   (__attribute__((address_space(3))) void*)l, 16, 0, 0);
}

__global__ __launch_bounds__(256) void gemm_kernel(const __hip_bfloat16* __restrict__ A,
                                                   const __hip_bfloat16* __restrict__ BT,
                                                   float* __restrict__ C) {
  // 576 blocks: bijective XCD swizzle (576 = 8*72), then (b, bx) major / by minor
  // so the 6 m-tiles sharing a BT panel are consecutive on one XCD.
  int bid = blockIdx.x;
  int swz = (bid & 7) * 72 + (bid >> 3);
  int b = swz / 18; int rem = swz - b * 18;
  int bx = rem / 6; int by = rem % 6;

  const __hip_bfloat16* Bp = BT + (size_t)b * HALF * KDIM;
  float* Cp = C + (size_t)b * DIM * DIM;
  int y0 = by * 64, x0 = bx * 128;

  __shared__ __align__(16) __hip_bfloat16 As[64 * 32];
  __shared__ __align__(16) __hip_bfloat16 Bs[128 * 32];

  int tid = threadIdx.x;
  int wv = tid >> 6, lane = tid & 63;
  int wr = wv >> 1, wc = wv & 1;        // wave: 32 rows x 64 cols
  int lhi = lane >> 4, llo = lane & 15;

  f32x4 acc_d[2][4] = {};
  f32x4 acc_s[2][4] = {};

#define GEMM_STEP(NEGS)                                                          \
  {                                                                              \
    {                                                                            \
      int ar = tid >> 2, aoff = (tid & 3) * 8;                                   \
      gload_lds16(A + (size_t)(y0 + ar) * KDIM + kt + aoff, As + tid * 8);       \
      int c2 = tid, c3 = tid + 256;                                              \
      gload_lds16(Bp + (size_t)(x0 + (c2 >> 2)) * KDIM + kt + (c2 & 3) * 8,      \
                  Bs + c2 * 8);                                                  \
      gload_lds16(Bp + (size_t)(x0 + (c3 >> 2)) * KDIM + kt + (c3 & 3) * 8,      \
                  Bs + c3 * 8);                                                  \
    }                                                                            \
    __syncthreads();                                                             \
    bf16x8 af[2], bfr[4];                                                        \
    _Pragma("unroll")                                                            \
    for (int i = 0; i < 2; ++i)                                                  \
      af[i] = *(const bf16x8*)(As + (wr * 32 + i * 16 + llo) * 32 + lhi * 8);    \
    _Pragma("unroll")                                                            \
    for (int j = 0; j < 4; ++j)                                                  \
      bfr[j] = *(const bf16x8*)(Bs + (wc * 64 + j * 16 + llo) * 32 + lhi * 8);   \
    _Pragma("unroll")                                                            \
    for (int i = 0; i < 2; ++i)                                                  \
      _Pragma("unroll")                                                          \
      for (int j = 0; j < 4; ++j) {                                              \
        acc_d[i][j] = __builtin_amdgcn_mfma_f32_16x16x32_bf16(af[i], bfr[j],     \
                                                              acc_d[i][j], 0, 0, 0); \
        bf16x8 bs = NEGS ? negbf8(bfr[j]) : bfr[j];                              \
        acc_s[i][j] = __builtin_amdgcn_mfma_f32_16x16x32_bf16(af[i], bs,         \
                                                              acc_s[i][j], 0, 0, 0); \
      }                                                                          \
    __syncthreads();                                                             \
  }

  for (int kt = 0; kt < DIM; kt += 32) GEMM_STEP(false)        // cos/Re half
  for (int kt = DIM; kt < KDIM; kt += 32) GEMM_STEP(true)      // sin/-Im half
#undef GEMM_STEP

  // C/D layout: col = lane&15, row = (lane>>4)*4 + reg   [m89-verified]
#pragma unroll
  for (int i = 0; i < 2; ++i) {
#pragma unroll
    for (int j = 0; j < 4; ++j) {
      int x = x0 + wc * 64 + j * 16 + llo;
      int xm = x ? DIM - x : 0;
#pragma unroll
      for (int q = 0; q < 4; ++q) {
        int y = y0 + wr * 32 + i * 16 + lhi * 4 + q;
        int ym = y ? DIM - y : 0;
        float vd = acc_d[i][j][q];
        float vs = acc_s[i][j][q];
        Cp[(size_t)y  * DIM + x]  = vd;
        Cp[(size_t)ym * DIM + xm] = vd;
        Cp[(size_t)y  * DIM + xm] = vs;
        Cp[(size_t)ym * DIM + x]  = vs;
      }
    }
  }
}

// ---------------------------------------------------------------------------
// Kernel 5: Nyquist row/col 384 (sin term vanishes there).
//  Re384[r] = sum_{nz in row r} v*(-1)^c      (from s_cv)
//  out[:,384]: y=0..384: sum_r cos(2*pi*r*y/768)*Re384[r], mirrored in y
//  out[384,:]: x=0..383: sum_r (-1)^r * Re[r,x] (from BT), mirrored in x
// ---------------------------------------------------------------------------
__global__ void nyq_kernel(const int* __restrict__ row_start,
                           const float2* __restrict__ s_cv,
                           const __hip_bfloat16* __restrict__ BT,
                           float* __restrict__ out) {
  int b = blockIdx.x;
  int tid = threadIdx.x;
  __shared__ float Re384[DIM];
  __shared__ float costab[DIM];
  const int* rs = row_start + b * (DIM + 1);
  const float2* cv = s_cv + b * 4096;
  for (int t = tid; t < DIM; t += 256) {
    float s, c;
    sincosf((TWO_PI / (float)DIM) * (float)t, &s, &c);
    costab[t] = c;
  }
  for (int r = tid; r < DIM; r += 256) {
    int s = rs[r], e = rs[r + 1];
    float acc = 0.f;
    for (int p = s; p < e; ++p) {
      float2 c = cv[p];
      int ci = (int)c.x;
      acc += (ci & 1) ? -c.y : c.y;
    }
    Re384[r] = acc;
  }
  __syncthreads();
  float* ob = out + (size_t)b * DIM * DIM;
  // column x = 384
  for (int y = tid; y < HALF + 1; y += 256) {
    float acc = 0.f;
    int m = 0;
    for (int r = 0; r < DIM; ++r) {
      acc += costab[m] * Re384[r];
      m += y; if (m >= DIM) m -= DIM;
    }
    int ym = y ? DIM - y : 0;
    ob[(size_t)y  * DIM + HALF] = acc;
    ob[(size_t)ym * DIM + HALF] = acc;
  }
  // row y = 384
  for (int x = tid; x < HALF; x += 256) {
    const __hip_bfloat16* btx = BT + ((size_t)(b * HALF + x)) * KDIM;
    float acc = 0.f;
    for (int r = 0; r < DIM; r += 8) {
      union { uint4 v4; __hip_bfloat16 h[8]; } u;
      u.v4 = *(const uint4*)(btx + r);
#pragma unroll
      for (int t = 0; t < 8; ++t) {
        float v = __bfloat162float(u.h[t]);
        acc += (t & 1) ? -v : v;
      }
    }
    int xm = x ? DIM - x : 0;
    ob[(size_t)HALF * DIM + x]  = acc;
    ob[(size_t)HALF * DIM + xm] = acc;
  }
}

// ---------------------------------------------------------------------------
extern "C" void kernel_launch(void* const* d_in, const int* in_sizes, int n_in,
                              void* d_out, int out_size, void* d_ws, size_t ws_size,
                              hipStream_t stream) {
  const float* cls   = (const float*)d_in[0];
  const float* Wr    = (const float*)d_in[1];
  const float* br    = (const float*)d_in[2];
  const float* coeff = (const float*)d_in[3];
  const int*   lidx  = (const int*)d_in[4];
  float* out = (float*)d_out;

  char* ws = (char*)d_ws;
  int*    sel_e     = (int*)(ws + 0);          //      256
  float*  sel_w     = (float*)(ws + 256);      //      256
  int*    row_start = (int*)(ws + 512);        //   98,432  (ends 98,944)
  float2* s_cv      = (float2*)(ws + 98944);   // 1,048,576 (ends 1,147,520)
  __hip_bfloat16* A  = (__hip_bfloat16*)(ws + 1147520);  // 384*1536*2 = 1,179,648 (ends 2,327,168)
  __hip_bfloat16* BT = (__hip_bfloat16*)(ws + 2327168);  // 32*384*1536*2 = 37,748,736 (~40 MB total)

  router_kernel<<<NB, 64, 0, stream>>>(cls, Wr, br, sel_e, sel_w);
  build_kernel<<<NB, 256, 0, stream>>>(coeff, lidx, sel_e, sel_w, row_start, s_cv);
  twiddle_kernel<<<HALF, 256, 0, stream>>>(A);
  stage1_kernel<<<dim3(3, 8, NB), 256, 0, stream>>>(row_start, s_cv, BT);
  gemm_kernel<<<576, 256, 0, stream>>>(A, BT, out);
  nyq_kernel<<<NB, 256, 0, stream>>>(row_start, s_cv, BT, out);
}

// Round 5
// 180.591 us; speedup vs baseline: 3.5248x; 1.2297x over previous
//
#include <hip/hip_runtime.h>
#include <hip/hip_bf16.h>

#define DIM 768
#define NE 64
#define NFRQ 2048
#define NB 32
#define KDIM 1536               // 2*DIM (Re rows then -Im rows)
#define HALF 384                // computed quadrant extent (y,x in [0,384))
#define TWO_PI 6.283185307179586f
#define INV768 (1.0f / 768.0f)
#define SCALE (300.0f / (float)(DIM * DIM))   // ALPHA / (dim*dim), folded into values

typedef __attribute__((ext_vector_type(8))) short bf16x8;   // 8 bf16 (4 VGPRs)
typedef __attribute__((ext_vector_type(4))) float f32x4;    // MFMA accumulator

// ---------------------------------------------------------------------------
// Kernel 0: router — logits = cls @ W^T + b, top-2, pairwise softmax weights
// ---------------------------------------------------------------------------
__global__ void router_kernel(const float* __restrict__ cls,
                              const float* __restrict__ W,
                              const float* __restrict__ bias,
                              int* __restrict__ sel_e, float* __restrict__ sel_w) {
  int b = blockIdx.x;
  __shared__ float logits[NE];
  int e = threadIdx.x;            // 64 threads
  const float* c = cls + b * DIM;
  const float* w = W + e * DIM;
  float acc = 0.f;
  for (int i = 0; i < DIM; ++i) acc += c[i] * w[i];
  logits[e] = acc + bias[e];
  __syncthreads();
  if (e == 0) {
    int i0 = 0; float l0 = logits[0];
    for (int i = 1; i < NE; ++i) { float v = logits[i]; if (v > l0) { l0 = v; i0 = i; } }
    int i1 = -1; float l1 = -3.4e38f;
    for (int i = 0; i < NE; ++i) {
      if (i == i0) continue;
      float v = logits[i]; if (v > l1) { l1 = v; i1 = i; }
    }
    float w0 = 1.f / (1.f + expf(l1 - l0));
    sel_e[b * 2]     = i0; sel_e[b * 2 + 1] = i1;
    sel_w[b * 2]     = w0; sel_w[b * 2 + 1] = 1.f - w0;
  }
}

// ---------------------------------------------------------------------------
// Kernel 1: bucket-sort the 4096 nonzeros of each batch by grid row.
// v2: parallel block scan (shfl) instead of thread-0 serial prefix sum.
// ---------------------------------------------------------------------------
__global__ __launch_bounds__(256) void build_kernel(const float* __restrict__ coeff,
                             const int* __restrict__ lidx,
                             const int* __restrict__ sel_e,
                             const float* __restrict__ sel_w,
                             int* __restrict__ row_start,   // [NB][DIM+1]
                             float2* __restrict__ s_cv) {   // [NB][4096] (colf, val)
  int b = blockIdx.x;
  __shared__ int cnt[DIM];
  __shared__ int base[DIM];
  __shared__ int wsum[4];
  int tid = threadIdx.x;
  for (int i = tid; i < DIM; i += 256) cnt[i] = 0;
  __syncthreads();
  int e0 = sel_e[b * 2], e1 = sel_e[b * 2 + 1];
  float w0 = sel_w[b * 2], w1 = sel_w[b * 2 + 1];
  for (int k = tid; k < 2 * NFRQ; k += 256) {
    int t = k >> 11, j = k & (NFRQ - 1);
    int e = t ? e1 : e0;
    int f = lidx[e * NFRQ + j];
    atomicAdd(&cnt[f / DIM], 1);
  }
  __syncthreads();
  // parallel exclusive scan of cnt[768]: 3 elements per thread
  {
    int s0 = cnt[3 * tid], s1 = cnt[3 * tid + 1], s2 = cnt[3 * tid + 2];
    int sum = s0 + s1 + s2;
    int lane = tid & 63, wid = tid >> 6;
    int v = sum;
#pragma unroll
    for (int d = 1; d < 64; d <<= 1) {
      int u = __shfl_up(v, d);
      if (lane >= d) v += u;
    }
    if (lane == 63) wsum[wid] = v;
    __syncthreads();
    int woff = 0;
#pragma unroll
    for (int w = 0; w < 4; ++w) if (w < wid) woff += wsum[w];
    int excl = woff + v - sum;
    int* rsg = row_start + b * (DIM + 1);
    base[3 * tid]     = excl;
    base[3 * tid + 1] = excl + s0;
    base[3 * tid + 2] = excl + s0 + s1;
    rsg[3 * tid]     = excl;
    rsg[3 * tid + 1] = excl + s0;
    rsg[3 * tid + 2] = excl + s0 + s1;
    if (tid == 255) rsg[DIM] = excl + sum;   // == 4096
  }
  __syncthreads();
  for (int i = tid; i < DIM; i += 256) cnt[i] = 0;
  __syncthreads();
  for (int k = tid; k < 2 * NFRQ; k += 256) {
    int t = k >> 11, j = k & (NFRQ - 1);
    int e = t ? e1 : e0;
    float w = t ? w1 : w0;
    int f = lidx[e * NFRQ + j];
    int r = f / DIM, c = f - r * DIM;
    int pos = base[r] + atomicAdd(&cnt[r], 1);
    s_cv[b * 4096 + pos] = make_float2((float)c, coeff[e * NFRQ + j] * w * SCALE);
  }
}

// ---------------------------------------------------------------------------
// Kernel 2: twiddle A[y][k] bf16 for y=0..383: k<768 -> cos(2*pi*y*k/768);
// k>=768 -> +sin (the minus sign lives in BT's Im half).
// ---------------------------------------------------------------------------
__global__ void twiddle_kernel(__hip_bfloat16* __restrict__ A) {
  int y = blockIdx.x;             // 0..383
  for (int r = threadIdx.x; r < DIM; r += blockDim.x) {
    int m = (y * r) % DIM;
    float s, c;
    sincosf((TWO_PI / (float)DIM) * (float)m, &s, &c);
    A[y * KDIM + r]       = __float2bfloat16(c);
    A[y * KDIM + DIM + r] = __float2bfloat16(s);
  }
}

// ---------------------------------------------------------------------------
// Kernel 3 (v5): stage-1 sparse DFT for x=0..383 (x-symmetry).
// BT[b][x][r] = Re(inter[r,x]), BT[b][x][768+r] = -Im(inter[r,x])   (bf16)
// Wave-uniform nonzero stream; 2 x per lane; 16 rows/wave (48 groups ->
// 4.5 waves/SIMD); p-unroll x2 for two independent load->trig chains.
// Grid: (3 x-groups of 128, 12 rg-blocks, 32 b), 256 thr = 4 waves.
// ---------------------------------------------------------------------------
__global__ __launch_bounds__(256) void stage1_kernel(const int* __restrict__ row_start,
                                                     const float2* __restrict__ s_cv,
                                                     __hip_bfloat16* __restrict__ BT) {
  int b = blockIdx.z;
  int lane = threadIdx.x & 63;
  int wv = threadIdx.x >> 6;
  int rg = blockIdx.y * 4 + wv;             // 0..47, 16 rows each
  int x0 = blockIdx.x * 128 + lane;         // 0..319 (+64 covers to 383)
  float xf0 = (float)x0;
  float xf1 = (float)(x0 + 64);
  const int* rs = row_start + b * (DIM + 1);
  const float2* cv = s_cv + b * 4096;

  int rb[17];
#pragma unroll
  for (int t = 0; t < 17; ++t) rb[t] = rs[rg * 16 + t];   // boundaries upfront

  __hip_bfloat16* bt0 = BT + ((size_t)(b * HALF + x0)) * KDIM;
  __hip_bfloat16* bt1 = bt0 + (size_t)64 * KDIM;

#pragma unroll
  for (int rnd = 0; rnd < 2; ++rnd) {
    int r0 = rg * 16 + rnd * 8;
    float re0[8], im0[8], re1[8], im1[8];
#pragma unroll
    for (int i = 0; i < 8; ++i) { re0[i] = im0[i] = re1[i] = im1[i] = 0.f; }
#pragma unroll
    for (int i = 0; i < 8; ++i) {
      int s = rb[rnd * 8 + i], e = rb[rnd * 8 + i + 1];
      int p = s;
      for (; p + 1 < e; p += 2) {           // two independent chains/iter
        float2 ca = cv[p];
        float2 cb = cv[p + 1];
        float ra0 = (ca.x * xf0) * INV768, ra1 = (ca.x * xf1) * INV768;
        float rb0 = (cb.x * xf0) * INV768, rb1 = (cb.x * xf1) * INV768;
        float fa0, fa1, fb0, fb1;
        asm("v_fract_f32 %0, %1" : "=v"(fa0) : "v"(ra0));
        asm("v_fract_f32 %0, %1" : "=v"(fa1) : "v"(ra1));
        asm("v_fract_f32 %0, %1" : "=v"(fb0) : "v"(rb0));
        asm("v_fract_f32 %0, %1" : "=v"(fb1) : "v"(rb1));
        float sa0, ca0, sa1, ca1, sb0, cb0, sb1, cb1;
        asm("v_sin_f32 %0, %1" : "=v"(sa0) : "v"(fa0));
        asm("v_cos_f32 %0, %1" : "=v"(ca0) : "v"(fa0));
        asm("v_sin_f32 %0, %1" : "=v"(sa1) : "v"(fa1));
        asm("v_cos_f32 %0, %1" : "=v"(ca1) : "v"(fa1));
        asm("v_sin_f32 %0, %1" : "=v"(sb0) : "v"(fb0));
        asm("v_cos_f32 %0, %1" : "=v"(cb0) : "v"(fb0));
        asm("v_sin_f32 %0, %1" : "=v"(sb1) : "v"(fb1));
        asm("v_cos_f32 %0, %1" : "=v"(cb1) : "v"(fb1));
        re0[i] += ca.y * ca0; im0[i] += ca.y * sa0;
        re1[i] += ca.y * ca1; im1[i] += ca.y * sa1;
        re0[i] += cb.y * cb0; im0[i] += cb.y * sb0;
        re1[i] += cb.y * cb1; im1[i] += cb.y * sb1;
      }
      if (p < e) {
        float2 c = cv[p];
        float r0f = (c.x * xf0) * INV768, r1f = (c.x * xf1) * INV768;
        float f0, f1, sn0, sn1, cs0, cs1;
        asm("v_fract_f32 %0, %1" : "=v"(f0) : "v"(r0f));
        asm("v_fract_f32 %0, %1" : "=v"(f1) : "v"(r1f));
        asm("v_sin_f32 %0, %1" : "=v"(sn0) : "v"(f0));
        asm("v_cos_f32 %0, %1" : "=v"(cs0) : "v"(f0));
        asm("v_sin_f32 %0, %1" : "=v"(sn1) : "v"(f1));
        asm("v_cos_f32 %0, %1" : "=v"(cs1) : "v"(f1));
        re0[i] += c.y * cs0; im0[i] += c.y * sn0;
        re1[i] += c.y * cs1; im1[i] += c.y * sn1;
      }
    }
    union { __hip_bfloat16 h[8]; uint4 v4; } u;
#pragma unroll
    for (int i = 0; i < 8; ++i) u.h[i] = __float2bfloat16(re0[i]);
    *(uint4*)(bt0 + r0) = u.v4;
#pragma unroll
    for (int i = 0; i < 8; ++i) u.h[i] = __float2bfloat16(-im0[i]);   // store -Im
    *(uint4*)(bt0 + DIM + r0) = u.v4;
#pragma unroll
    for (int i = 0; i < 8; ++i) u.h[i] = __float2bfloat16(re1[i]);
    *(uint4*)(bt1 + r0) = u.v4;
#pragma unroll
    for (int i = 0; i < 8; ++i) u.h[i] = __float2bfloat16(-im1[i]);
    *(uint4*)(bt1 + DIM + r0) = u.v4;
  }
}

// ---------------------------------------------------------------------------
// Kernel 4 (v3): quadrant GEMM, split accumulators per K-half (halves MFMA):
//   acc1 = A_cos . Re      (kt in [0,768))
//   acc2 = A_sin . (-Im)   (kt in [768,1536))  == -C2
//   out[y,x]=out[-y,-x]=acc1+acc2 ; out[-y,x]=out[y,-x]=acc1-acc2
// BM=BN=64, 1152 blocks (4.5/CU), double-buffered LDS, ONE barrier per
// K-step with STAGE-next issued before compute (T3-minimal pipeline).
// ---------------------------------------------------------------------------
__device__ inline void gload_lds16(const void* g, void* l) {
  __builtin_amdgcn_global_load_lds((const __attribute__((address_space(1))) void*)g,
                                   (__attribute__((address_space(3))) void*)l, 16, 0, 0);
}

__global__ __launch_bounds__(256) void gemm_kernel(const __hip_bfloat16* __restrict__ A,
                                                   const __hip_bfloat16* __restrict__ BT,
                                                   float* __restrict__ C) {
  // 1152 blocks = 8 * 144: bijective XCD swizzle; by fastest so one batch's
  // 36 tiles (sharing A + BT[b] in L2) land on one XCD.
  int bid = blockIdx.x;
  int swz = (bid & 7) * 144 + (bid >> 3);
  int b = swz / 36; int rem = swz - b * 36;
  int bx = rem / 6, by = rem % 6;

  const __hip_bfloat16* Bp = BT + (size_t)b * HALF * KDIM;
  float* Cp = C + (size_t)b * DIM * DIM;
  int y0 = by * 64, x0 = bx * 64;

  __shared__ __align__(16) __hip_bfloat16 As[2][64 * 32];
  __shared__ __align__(16) __hip_bfloat16 Bs[2][64 * 32];

  int tid = threadIdx.x;
  int wv = tid >> 6, lane = tid & 63;
  int wr = wv >> 1, wc = wv & 1;        // wave: 32x32 sub-tile
  int lhi = lane >> 4, llo = lane & 15;
  int arow = tid >> 2, aoff = (tid & 3) * 8;

  f32x4 acc1[2][2] = {};
  f32x4 acc2[2][2] = {};

  // prologue: stage kt=0 into buf 0
  gload_lds16(A  + (size_t)(y0 + arow) * KDIM + aoff, As[0] + tid * 8);
  gload_lds16(Bp + (size_t)(x0 + arow) * KDIM + aoff, Bs[0] + tid * 8);
  __syncthreads();

  auto step = [&](int t, f32x4 (&acc)[2][2], bool last) {
    int cur = t & 1;
    if (!last) {                       // issue next-tile loads FIRST
      int ktn = (t + 1) * 32;
      gload_lds16(A  + (size_t)(y0 + arow) * KDIM + ktn + aoff, As[cur ^ 1] + tid * 8);
      gload_lds16(Bp + (size_t)(x0 + arow) * KDIM + ktn + aoff, Bs[cur ^ 1] + tid * 8);
    }
    bf16x8 af[2], bfr[2];
#pragma unroll
    for (int i = 0; i < 2; ++i)
      af[i] = *(const bf16x8*)(As[cur] + (wr * 32 + i * 16 + llo) * 32 + lhi * 8);
#pragma unroll
    for (int j = 0; j < 2; ++j)
      bfr[j] = *(const bf16x8*)(Bs[cur] + (wc * 32 + j * 16 + llo) * 32 + lhi * 8);
#pragma unroll
    for (int i = 0; i < 2; ++i)
#pragma unroll
      for (int j = 0; j < 2; ++j)
        acc[i][j] = __builtin_amdgcn_mfma_f32_16x16x32_bf16(af[i], bfr[j], acc[i][j], 0, 0, 0);
    if (!last) __syncthreads();        // one barrier per K-step
  };

  for (int t = 0; t < 24; ++t) step(t, acc1, false);       // cos/Re half
  for (int t = 24; t < 48; ++t) step(t, acc2, t == 47);    // sin/-Im half

  // C/D layout: col = lane&15, row = (lane>>4)*4 + reg   [m89-verified]
#pragma unroll
  for (int i = 0; i < 2; ++i) {
#pragma unroll
    for (int j = 0; j < 2; ++j) {
      int x = x0 + wc * 32 + j * 16 + llo;
      int xm = x ? DIM - x : 0;
#pragma unroll
      for (int q = 0; q < 4; ++q) {
        int y = y0 + wr * 32 + i * 16 + lhi * 4 + q;
        int ym = y ? DIM - y : 0;
        float c1 = acc1[i][j][q], c2 = acc2[i][j][q];
        float vd = c1 + c2;            // out[y,x] = out[-y,-x]
        float vs = c1 - c2;            // out[-y,x] = out[y,-x]
        Cp[(size_t)y  * DIM + x]  = vd;
        Cp[(size_t)ym * DIM + xm] = vd;
        Cp[(size_t)y  * DIM + xm] = vs;
        Cp[(size_t)ym * DIM + x]  = vs;
      }
    }
  }
}

// ---------------------------------------------------------------------------
// Kernel 5: Nyquist row/col 384 (sin term vanishes there).
// ---------------------------------------------------------------------------
__global__ void nyq_kernel(const int* __restrict__ row_start,
                           const float2* __restrict__ s_cv,
                           const __hip_bfloat16* __restrict__ BT,
                           float* __restrict__ out) {
  int b = blockIdx.x;
  int tid = threadIdx.x;
  __shared__ float Re384[DIM];
  __shared__ float costab[DIM];
  const int* rs = row_start + b * (DIM + 1);
  const float2* cv = s_cv + b * 4096;
  for (int t = tid; t < DIM; t += 256) {
    float s, c;
    sincosf((TWO_PI / (float)DIM) * (float)t, &s, &c);
    costab[t] = c;
  }
  for (int r = tid; r < DIM; r += 256) {
    int s = rs[r], e = rs[r + 1];
    float acc = 0.f;
    for (int p = s; p < e; ++p) {
      float2 c = cv[p];
      int ci = (int)c.x;
      acc += (ci & 1) ? -c.y : c.y;
    }
    Re384[r] = acc;
  }
  __syncthreads();
  float* ob = out + (size_t)b * DIM * DIM;
  // column x = 384
  for (int y = tid; y < HALF + 1; y += 256) {
    float acc = 0.f;
    int m = 0;
    for (int r = 0; r < DIM; ++r) {
      acc += costab[m] * Re384[r];
      m += y; if (m >= DIM) m -= DIM;
    }
    int ym = y ? DIM - y : 0;
    ob[(size_t)y  * DIM + HALF] = acc;
    ob[(size_t)ym * DIM + HALF] = acc;
  }
  // row y = 384
  for (int x = tid; x < HALF; x += 256) {
    const __hip_bfloat16* btx = BT + ((size_t)(b * HALF + x)) * KDIM;
    float acc = 0.f;
    for (int r = 0; r < DIM; r += 8) {
      union { uint4 v4; __hip_bfloat16 h[8]; } u;
      u.v4 = *(const uint4*)(btx + r);
#pragma unroll
      for (int t = 0; t < 8; ++t) {
        float v = __bfloat162float(u.h[t]);
        acc += (t & 1) ? -v : v;
      }
    }
    int xm = x ? DIM - x : 0;
    ob[(size_t)HALF * DIM + x]  = acc;
    ob[(size_t)HALF * DIM + xm] = acc;
  }
}

// ---------------------------------------------------------------------------
extern "C" void kernel_launch(void* const* d_in, const int* in_sizes, int n_in,
                              void* d_out, int out_size, void* d_ws, size_t ws_size,
                              hipStream_t stream) {
  const float* cls   = (const float*)d_in[0];
  const float* Wr    = (const float*)d_in[1];
  const float* br    = (const float*)d_in[2];
  const float* coeff = (const float*)d_in[3];
  const int*   lidx  = (const int*)d_in[4];
  float* out = (float*)d_out;

  char* ws = (char*)d_ws;
  int*    sel_e     = (int*)(ws + 0);          //      256
  float*  sel_w     = (float*)(ws + 256);      //      256
  int*    row_start = (int*)(ws + 512);        //   98,432  (ends 98,944)
  float2* s_cv      = (float2*)(ws + 98944);   // 1,048,576 (ends 1,147,520)
  __hip_bfloat16* A  = (__hip_bfloat16*)(ws + 1147520);  // 384*1536*2 = 1,179,648 (ends 2,327,168)
  __hip_bfloat16* BT = (__hip_bfloat16*)(ws + 2327168);  // 32*384*1536*2 = 37,748,736 (~40 MB total)

  router_kernel<<<NB, 64, 0, stream>>>(cls, Wr, br, sel_e, sel_w);
  build_kernel<<<NB, 256, 0, stream>>>(coeff, lidx, sel_e, sel_w, row_start, s_cv);
  twiddle_kernel<<<HALF, 256, 0, stream>>>(A);
  stage1_kernel<<<dim3(3, 12, NB), 256, 0, stream>>>(row_start, s_cv, BT);
  gemm_kernel<<<1152, 256, 0, stream>>>(A, BT, out);
  nyq_kernel<<<NB, 256, 0, stream>>>(row_start, s_cv, BT, out);
}

// Round 6
// 137.283 us; speedup vs baseline: 4.6367x; 1.3155x over previous
//
#include <hip/hip_runtime.h>
#include <hip/hip_bf16.h>

#define DIM 768
#define NE 64
#define NFRQ 2048
#define NB 32
#define KDIM 1536               // 2*DIM (Re rows then -Im rows)
#define HALF 384                // computed quadrant extent (y,x in [0,384))
#define TWO_PI 6.283185307179586f
#define INV768 (1.0f / 768.0f)
#define SCALE (300.0f / (float)(DIM * DIM))   // ALPHA / (dim*dim), folded into values

typedef __attribute__((ext_vector_type(8))) short bf16x8;   // 8 bf16 (4 VGPRs)
typedef __attribute__((ext_vector_type(4))) float f32x4;    // MFMA accumulator

// ---------------------------------------------------------------------------
// Kernel 0 (v2): router — 4 waves: e = tid&63, K-chunk q = tid>>6, float4
// loads, LDS reduce, thread-0 top-2. Breaks the 768-iter serial chain.
// ---------------------------------------------------------------------------
__global__ __launch_bounds__(256) void router_kernel(const float* __restrict__ cls,
                              const float* __restrict__ W,
                              const float* __restrict__ bias,
                              int* __restrict__ sel_e, float* __restrict__ sel_w) {
  int b = blockIdx.x;
  int tid = threadIdx.x;
  int e = tid & 63, q = tid >> 6;
  __shared__ float part[4][NE];
  __shared__ float logits[NE];
  const float* c = cls + b * DIM + q * 192;
  const float* w = W + e * DIM + q * 192;
  float acc = 0.f;
#pragma unroll 4
  for (int i = 0; i < 192; i += 4) {
    float4 cv = *(const float4*)(c + i);
    float4 wv = *(const float4*)(w + i);
    acc += cv.x * wv.x + cv.y * wv.y + cv.z * wv.z + cv.w * wv.w;
  }
  part[q][e] = acc;
  __syncthreads();
  if (tid < NE)
    logits[tid] = part[0][tid] + part[1][tid] + part[2][tid] + part[3][tid] + bias[tid];
  __syncthreads();
  if (tid == 0) {
    int i0 = 0; float l0 = logits[0];
    for (int i = 1; i < NE; ++i) { float v = logits[i]; if (v > l0) { l0 = v; i0 = i; } }
    int i1 = -1; float l1 = -3.4e38f;
    for (int i = 0; i < NE; ++i) {
      if (i == i0) continue;
      float v = logits[i]; if (v > l1) { l1 = v; i1 = i; }
    }
    float w0 = 1.f / (1.f + expf(l1 - l0));
    sel_e[b * 2]     = i0; sel_e[b * 2 + 1] = i1;
    sel_w[b * 2]     = w0; sel_w[b * 2 + 1] = 1.f - w0;
  }
}

// ---------------------------------------------------------------------------
// Kernel 1: bucket-sort the 4096 nonzeros of each batch by grid row.
// Parallel block scan (shfl) for the prefix sum.
// ---------------------------------------------------------------------------
__global__ __launch_bounds__(256) void build_kernel(const float* __restrict__ coeff,
                             const int* __restrict__ lidx,
                             const int* __restrict__ sel_e,
                             const float* __restrict__ sel_w,
                             int* __restrict__ row_start,   // [NB][DIM+1]
                             float2* __restrict__ s_cv) {   // [NB][4096] (colf, val)
  int b = blockIdx.x;
  __shared__ int cnt[DIM];
  __shared__ int base[DIM];
  __shared__ int wsum[4];
  int tid = threadIdx.x;
  for (int i = tid; i < DIM; i += 256) cnt[i] = 0;
  __syncthreads();
  int e0 = sel_e[b * 2], e1 = sel_e[b * 2 + 1];
  float w0 = sel_w[b * 2], w1 = sel_w[b * 2 + 1];
  for (int k = tid; k < 2 * NFRQ; k += 256) {
    int t = k >> 11, j = k & (NFRQ - 1);
    int e = t ? e1 : e0;
    int f = lidx[e * NFRQ + j];
    atomicAdd(&cnt[f / DIM], 1);
  }
  __syncthreads();
  // parallel exclusive scan of cnt[768]: 3 elements per thread
  {
    int s0 = cnt[3 * tid], s1 = cnt[3 * tid + 1], s2 = cnt[3 * tid + 2];
    int sum = s0 + s1 + s2;
    int lane = tid & 63, wid = tid >> 6;
    int v = sum;
#pragma unroll
    for (int d = 1; d < 64; d <<= 1) {
      int u = __shfl_up(v, d);
      if (lane >= d) v += u;
    }
    if (lane == 63) wsum[wid] = v;
    __syncthreads();
    int woff = 0;
#pragma unroll
    for (int w = 0; w < 4; ++w) if (w < wid) woff += wsum[w];
    int excl = woff + v - sum;
    int* rsg = row_start + b * (DIM + 1);
    base[3 * tid]     = excl;
    base[3 * tid + 1] = excl + s0;
    base[3 * tid + 2] = excl + s0 + s1;
    rsg[3 * tid]     = excl;
    rsg[3 * tid + 1] = excl + s0;
    rsg[3 * tid + 2] = excl + s0 + s1;
    if (tid == 255) rsg[DIM] = excl + sum;   // == 4096
  }
  __syncthreads();
  for (int i = tid; i < DIM; i += 256) cnt[i] = 0;
  __syncthreads();
  for (int k = tid; k < 2 * NFRQ; k += 256) {
    int t = k >> 11, j = k & (NFRQ - 1);
    int e = t ? e1 : e0;
    float w = t ? w1 : w0;
    int f = lidx[e * NFRQ + j];
    int r = f / DIM, c = f - r * DIM;
    int pos = base[r] + atomicAdd(&cnt[r], 1);
    s_cv[b * 4096 + pos] = make_float2((float)c, coeff[e * NFRQ + j] * w * SCALE);
  }
}

// ---------------------------------------------------------------------------
// Kernel 2 (v2): twiddle A[y][k] bf16, vectorized ushort4 stores.
// k<768 -> cos(2*pi*y*k/768); k>=768 -> +sin (minus sign lives in BT Im half).
// ---------------------------------------------------------------------------
__global__ void twiddle_kernel(__hip_bfloat16* __restrict__ A) {
  int y = blockIdx.x;             // 0..383
  int tid = threadIdx.x;          // 192 threads, 4 r each
  int r0 = tid * 4;
  union { __hip_bfloat16 h[4]; ushort4 v; } uc, us;
#pragma unroll
  for (int j = 0; j < 4; ++j) {
    int m = (y * (r0 + j)) % DIM;
    float s, c;
    sincosf((TWO_PI / (float)DIM) * (float)m, &s, &c);
    uc.h[j] = __float2bfloat16(c);
    us.h[j] = __float2bfloat16(s);
  }
  *(ushort4*)(A + y * KDIM + r0)       = uc.v;
  *(ushort4*)(A + y * KDIM + DIM + r0) = us.v;
}

// ---------------------------------------------------------------------------
// Kernel 3: stage-1 sparse DFT for x=0..383 (x-symmetry).
// BT[b][x][r] = Re(inter[r,x]), BT[b][x][768+r] = -Im(inter[r,x])   (bf16)
// Wave-uniform nonzero stream; 2 x per lane; 16 rows/wave; p-unroll x2.
// ---------------------------------------------------------------------------
__global__ __launch_bounds__(256) void stage1_kernel(const int* __restrict__ row_start,
                                                     const float2* __restrict__ s_cv,
                                                     __hip_bfloat16* __restrict__ BT) {
  int b = blockIdx.z;
  int lane = threadIdx.x & 63;
  int wv = threadIdx.x >> 6;
  int rg = blockIdx.y * 4 + wv;             // 0..47, 16 rows each
  int x0 = blockIdx.x * 128 + lane;         // 0..319 (+64 covers to 383)
  float xf0 = (float)x0;
  float xf1 = (float)(x0 + 64);
  const int* rs = row_start + b * (DIM + 1);
  const float2* cv = s_cv + b * 4096;

  int rb[17];
#pragma unroll
  for (int t = 0; t < 17; ++t) rb[t] = rs[rg * 16 + t];   // boundaries upfront

  __hip_bfloat16* bt0 = BT + ((size_t)(b * HALF + x0)) * KDIM;
  __hip_bfloat16* bt1 = bt0 + (size_t)64 * KDIM;

#pragma unroll
  for (int rnd = 0; rnd < 2; ++rnd) {
    int r0 = rg * 16 + rnd * 8;
    float re0[8], im0[8], re1[8], im1[8];
#pragma unroll
    for (int i = 0; i < 8; ++i) { re0[i] = im0[i] = re1[i] = im1[i] = 0.f; }
#pragma unroll
    for (int i = 0; i < 8; ++i) {
      int s = rb[rnd * 8 + i], e = rb[rnd * 8 + i + 1];
      int p = s;
      for (; p + 1 < e; p += 2) {           // two independent chains/iter
        float2 ca = cv[p];
        float2 cb = cv[p + 1];
        float ra0 = (ca.x * xf0) * INV768, ra1 = (ca.x * xf1) * INV768;
        float rb0 = (cb.x * xf0) * INV768, rb1 = (cb.x * xf1) * INV768;
        float fa0, fa1, fb0, fb1;
        asm("v_fract_f32 %0, %1" : "=v"(fa0) : "v"(ra0));
        asm("v_fract_f32 %0, %1" : "=v"(fa1) : "v"(ra1));
        asm("v_fract_f32 %0, %1" : "=v"(fb0) : "v"(rb0));
        asm("v_fract_f32 %0, %1" : "=v"(fb1) : "v"(rb1));
        float sa0, ca0, sa1, ca1, sb0, cb0, sb1, cb1;
        asm("v_sin_f32 %0, %1" : "=v"(sa0) : "v"(fa0));
        asm("v_cos_f32 %0, %1" : "=v"(ca0) : "v"(fa0));
        asm("v_sin_f32 %0, %1" : "=v"(sa1) : "v"(fa1));
        asm("v_cos_f32 %0, %1" : "=v"(ca1) : "v"(fa1));
        asm("v_sin_f32 %0, %1" : "=v"(sb0) : "v"(fb0));
        asm("v_cos_f32 %0, %1" : "=v"(cb0) : "v"(fb0));
        asm("v_sin_f32 %0, %1" : "=v"(sb1) : "v"(fb1));
        asm("v_cos_f32 %0, %1" : "=v"(cb1) : "v"(fb1));
        re0[i] += ca.y * ca0; im0[i] += ca.y * sa0;
        re1[i] += ca.y * ca1; im1[i] += ca.y * sa1;
        re0[i] += cb.y * cb0; im0[i] += cb.y * sb0;
        re1[i] += cb.y * cb1; im1[i] += cb.y * sb1;
      }
      if (p < e) {
        float2 c = cv[p];
        float r0f = (c.x * xf0) * INV768, r1f = (c.x * xf1) * INV768;
        float f0, f1, sn0, sn1, cs0, cs1;
        asm("v_fract_f32 %0, %1" : "=v"(f0) : "v"(r0f));
        asm("v_fract_f32 %0, %1" : "=v"(f1) : "v"(r1f));
        asm("v_sin_f32 %0, %1" : "=v"(sn0) : "v"(f0));
        asm("v_cos_f32 %0, %1" : "=v"(cs0) : "v"(f0));
        asm("v_sin_f32 %0, %1" : "=v"(sn1) : "v"(f1));
        asm("v_cos_f32 %0, %1" : "=v"(cs1) : "v"(f1));
        re0[i] += c.y * cs0; im0[i] += c.y * sn0;
        re1[i] += c.y * cs1; im1[i] += c.y * sn1;
      }
    }
    union { __hip_bfloat16 h[8]; uint4 v4; } u;
#pragma unroll
    for (int i = 0; i < 8; ++i) u.h[i] = __float2bfloat16(re0[i]);
    *(uint4*)(bt0 + r0) = u.v4;
#pragma unroll
    for (int i = 0; i < 8; ++i) u.h[i] = __float2bfloat16(-im0[i]);   // store -Im
    *(uint4*)(bt0 + DIM + r0) = u.v4;
#pragma unroll
    for (int i = 0; i < 8; ++i) u.h[i] = __float2bfloat16(re1[i]);
    *(uint4*)(bt1 + r0) = u.v4;
#pragma unroll
    for (int i = 0; i < 8; ++i) u.h[i] = __float2bfloat16(-im1[i]);
    *(uint4*)(bt1 + DIM + r0) = u.v4;
  }
}

// ---------------------------------------------------------------------------
// Kernel 4: quadrant GEMM, split accumulators per K-half:
//   acc1 = A_cos . Re  (kt<768);  acc2 = A_sin . (-Im)  (kt>=768)
//   out[y,x]=out[-y,-x]=acc1+acc2 ; out[-y,x]=out[y,-x]=acc1-acc2
// BM=BN=64, 1152 blocks (4.5/CU), double-buffered LDS, one barrier/K-step.
// ---------------------------------------------------------------------------
__device__ inline void gload_lds16(const void* g, void* l) {
  __builtin_amdgcn_global_load_lds((const __attribute__((address_space(1))) void*)g,
                                   (__attribute__((address_space(3))) void*)l, 16, 0, 0);
}

__global__ __launch_bounds__(256) void gemm_kernel(const __hip_bfloat16* __restrict__ A,
                                                   const __hip_bfloat16* __restrict__ BT,
                                                   float* __restrict__ C) {
  int bid = blockIdx.x;
  int swz = (bid & 7) * 144 + (bid >> 3);
  int b = swz / 36; int rem = swz - b * 36;
  int bx = rem / 6, by = rem % 6;

  const __hip_bfloat16* Bp = BT + (size_t)b * HALF * KDIM;
  float* Cp = C + (size_t)b * DIM * DIM;
  int y0 = by * 64, x0 = bx * 64;

  __shared__ __align__(16) __hip_bfloat16 As[2][64 * 32];
  __shared__ __align__(16) __hip_bfloat16 Bs[2][64 * 32];

  int tid = threadIdx.x;
  int wv = tid >> 6, lane = tid & 63;
  int wr = wv >> 1, wc = wv & 1;        // wave: 32x32 sub-tile
  int lhi = lane >> 4, llo = lane & 15;
  int arow = tid >> 2, aoff = (tid & 3) * 8;

  f32x4 acc1[2][2] = {};
  f32x4 acc2[2][2] = {};

  gload_lds16(A  + (size_t)(y0 + arow) * KDIM + aoff, As[0] + tid * 8);
  gload_lds16(Bp + (size_t)(x0 + arow) * KDIM + aoff, Bs[0] + tid * 8);
  __syncthreads();

  auto step = [&](int t, f32x4 (&acc)[2][2], bool last) {
    int cur = t & 1;
    if (!last) {
      int ktn = (t + 1) * 32;
      gload_lds16(A  + (size_t)(y0 + arow) * KDIM + ktn + aoff, As[cur ^ 1] + tid * 8);
      gload_lds16(Bp + (size_t)(x0 + arow) * KDIM + ktn + aoff, Bs[cur ^ 1] + tid * 8);
    }
    bf16x8 af[2], bfr[2];
#pragma unroll
    for (int i = 0; i < 2; ++i)
      af[i] = *(const bf16x8*)(As[cur] + (wr * 32 + i * 16 + llo) * 32 + lhi * 8);
#pragma unroll
    for (int j = 0; j < 2; ++j)
      bfr[j] = *(const bf16x8*)(Bs[cur] + (wc * 32 + j * 16 + llo) * 32 + lhi * 8);
#pragma unroll
    for (int i = 0; i < 2; ++i)
#pragma unroll
      for (int j = 0; j < 2; ++j)
        acc[i][j] = __builtin_amdgcn_mfma_f32_16x16x32_bf16(af[i], bfr[j], acc[i][j], 0, 0, 0);
    if (!last) __syncthreads();
  };

  for (int t = 0; t < 24; ++t) step(t, acc1, false);       // cos/Re half
  for (int t = 24; t < 48; ++t) step(t, acc2, t == 47);    // sin/-Im half

#pragma unroll
  for (int i = 0; i < 2; ++i) {
#pragma unroll
    for (int j = 0; j < 2; ++j) {
      int x = x0 + wc * 32 + j * 16 + llo;
      int xm = x ? DIM - x : 0;
#pragma unroll
      for (int q = 0; q < 4; ++q) {
        int y = y0 + wr * 32 + i * 16 + lhi * 4 + q;
        int ym = y ? DIM - y : 0;
        float c1 = acc1[i][j][q], c2 = acc2[i][j][q];
        float vd = c1 + c2;
        float vs = c1 - c2;
        Cp[(size_t)y  * DIM + x]  = vd;
        Cp[(size_t)ym * DIM + xm] = vd;
        Cp[(size_t)y  * DIM + xm] = vs;
        Cp[(size_t)ym * DIM + x]  = vs;
      }
    }
  }
}

// ---------------------------------------------------------------------------
// Kernel 5 (v2): Nyquist row/col 384. Grid (4, NB):
//  slice 0..2: column x=384, one y per thread, direct v_cos (no LDS table)
//  slice 3:    row y=384 from BT with uint4 reads
// ---------------------------------------------------------------------------
__global__ __launch_bounds__(256) void nyq_kernel(const int* __restrict__ row_start,
                           const float2* __restrict__ s_cv,
                           const __hip_bfloat16* __restrict__ BT,
                           float* __restrict__ out) {
  int slice = blockIdx.x;
  int b = blockIdx.y;
  int tid = threadIdx.x;
  float* ob = out + (size_t)b * DIM * DIM;

  if (slice == 3) {           // row y = 384: sum_r (-1)^r Re[r,x] from BT
    for (int x = tid; x < HALF; x += 256) {
      const __hip_bfloat16* btx = BT + ((size_t)(b * HALF + x)) * KDIM;
      float acc = 0.f;
      for (int r = 0; r < DIM; r += 8) {
        union { uint4 v4; __hip_bfloat16 h[8]; } u;
        u.v4 = *(const uint4*)(btx + r);
#pragma unroll
        for (int t = 0; t < 8; ++t) {
          float v = __bfloat162float(u.h[t]);
          acc += (t & 1) ? -v : v;
        }
      }
      int xm = x ? DIM - x : 0;
      ob[(size_t)HALF * DIM + x]  = acc;
      ob[(size_t)HALF * DIM + xm] = acc;
    }
    return;
  }

  // slices 0..2: Re384[r] = sum_{nz in row r} v*(-1)^c, then column x=384
  __shared__ float Re384[DIM];
  const int* rs = row_start + b * (DIM + 1);
  const float2* cv = s_cv + b * 4096;
  for (int r = tid; r < DIM; r += 256) {
    int s = rs[r], e = rs[r + 1];
    float acc = 0.f;
    for (int p = s; p < e; ++p) {
      float2 c = cv[p];
      int ci = (int)c.x;
      acc += (ci & 1) ? -c.y : c.y;
    }
    Re384[r] = acc;
  }
  __syncthreads();
  int y = slice * 129 + tid;
  if (tid < 129 && y <= HALF) {
    float yf = (float)y;
    float acc = 0.f;
    for (int r = 0; r < DIM; ++r) {
      float rev = (yf * (float)r) * INV768;   // y*r < 2^24 -> exact
      float f, cs;
      asm("v_fract_f32 %0, %1" : "=v"(f) : "v"(rev));
      asm("v_cos_f32 %0, %1" : "=v"(cs) : "v"(f));
      acc += Re384[r] * cs;
    }
    int ym = y ? DIM - y : 0;
    ob[(size_t)y  * DIM + HALF] = acc;
    ob[(size_t)ym * DIM + HALF] = acc;
  }
}

// ---------------------------------------------------------------------------
extern "C" void kernel_launch(void* const* d_in, const int* in_sizes, int n_in,
                              void* d_out, int out_size, void* d_ws, size_t ws_size,
                              hipStream_t stream) {
  const float* cls   = (const float*)d_in[0];
  const float* Wr    = (const float*)d_in[1];
  const float* br    = (const float*)d_in[2];
  const float* coeff = (const float*)d_in[3];
  const int*   lidx  = (const int*)d_in[4];
  float* out = (float*)d_out;

  char* ws = (char*)d_ws;
  int*    sel_e     = (int*)(ws + 0);          //      256
  float*  sel_w     = (float*)(ws + 256);      //      256
  int*    row_start = (int*)(ws + 512);        //   98,432  (ends 98,944)
  float2* s_cv      = (float2*)(ws + 98944);   // 1,048,576 (ends 1,147,520)
  __hip_bfloat16* A  = (__hip_bfloat16*)(ws + 1147520);  // 384*1536*2 = 1,179,648 (ends 2,327,168)
  __hip_bfloat16* BT = (__hip_bfloat16*)(ws + 2327168);  // 32*384*1536*2 = 37,748,736 (~40 MB total)

  router_kernel<<<NB, 256, 0, stream>>>(cls, Wr, br, sel_e, sel_w);
  build_kernel<<<NB, 256, 0, stream>>>(coeff, lidx, sel_e, sel_w, row_start, s_cv);
  twiddle_kernel<<<HALF, 192, 0, stream>>>(A);
  stage1_kernel<<<dim3(3, 12, NB), 256, 0, stream>>>(row_start, s_cv, BT);
  gemm_kernel<<<1152, 256, 0, stream>>>(A, BT, out);
  nyq_kernel<<<dim3(4, NB), 256, 0, stream>>>(row_start, s_cv, BT, out);
}

// Round 7
// 130.095 us; speedup vs baseline: 4.8929x; 1.0553x over previous
//
#include <hip/hip_runtime.h>
#include <hip/hip_bf16.h>

#define DIM 768
#define NE 64
#define NFRQ 2048
#define NB 32
#define KDIM 1536               // 2*DIM (Re rows then -Im rows)
#define HALF 384                // computed quadrant extent (y,x in [0,384))
#define TWO_PI 6.283185307179586f
#define INV768 (1.0f / 768.0f)
#define SCALE (300.0f / (float)(DIM * DIM))   // ALPHA / (dim*dim), folded into values

typedef __attribute__((ext_vector_type(8))) short bf16x8;   // 8 bf16 (4 VGPRs)
typedef __attribute__((ext_vector_type(4))) float f32x4;    // MFMA accumulator

// ---------------------------------------------------------------------------
// Kernel A "prep" (one launch, 3 roles by blockIdx):
//  bid <  32        : fused router (logits->top2->weights) + bucket-sort build
//  32 <= bid < 416  : A twiddle row y = bid-32   (cos | +sin), bf16
//  bid >= 416       : T2 table row c = bid-416: float2 (cos(2pi c x/768), -sin)
// s_cv entries are (uint byte-offset c*3072 as float bits, weighted val).
// ---------------------------------------------------------------------------
__global__ __launch_bounds__(256) void prep_kernel(const float* __restrict__ cls,
                                                   const float* __restrict__ W,
                                                   const float* __restrict__ bias,
                                                   const float* __restrict__ coeff,
                                                   const int* __restrict__ lidx,
                                                   int* __restrict__ row_start,
                                                   float2* __restrict__ s_cv,
                                                   __hip_bfloat16* __restrict__ A,
                                                   float2* __restrict__ T2) {
  int bid = blockIdx.x;
  int tid = threadIdx.x;

  if (bid >= 32 + HALF) {             // ---- T2 rows ----
    int c = bid - (32 + HALF);        // 0..767
    for (int x = tid; x < HALF; x += 256) {
      float prod = (float)(c * x);    // < 2^24, exact
      float f, sn, cs;
      float rev = prod * INV768;
      asm("v_fract_f32 %0, %1" : "=v"(f) : "v"(rev));
      asm("v_sin_f32 %0, %1" : "=v"(sn) : "v"(f));
      asm("v_cos_f32 %0, %1" : "=v"(cs) : "v"(f));
      T2[(size_t)c * HALF + x] = make_float2(cs, -sn);
    }
    return;
  }
  if (bid >= 32) {                    // ---- A twiddle rows ----
    int y = bid - 32;                 // 0..383
    if (tid < 192) {
      int r0 = tid * 4;
      union { __hip_bfloat16 h[4]; ushort4 v; } uc, us;
#pragma unroll
      for (int j = 0; j < 4; ++j) {
        int m = (y * (r0 + j)) % DIM;
        float s, c;
        sincosf((TWO_PI / (float)DIM) * (float)m, &s, &c);
        uc.h[j] = __float2bfloat16(c);
        us.h[j] = __float2bfloat16(s);
      }
      *(ushort4*)(A + y * KDIM + r0)       = uc.v;
      *(ushort4*)(A + y * KDIM + DIM + r0) = us.v;
    }
    return;
  }

  // ---- router + build, batch b = bid ----
  int b = bid;
  __shared__ int cnt[DIM];
  __shared__ int base[DIM];
  __shared__ int wsum[4];
  __shared__ int sel_i[2];
  __shared__ float sel_f[2];
  float* part   = (float*)cnt;        // 4x64 floats (overlay, consumed pre-build)
  float* logits = (float*)base;       // 64 floats (overlay)

  {
    int e = tid & 63, q = tid >> 6;
    const float* c = cls + b * DIM + q * 192;
    const float* w = W + e * DIM + q * 192;
    float acc = 0.f;
#pragma unroll 4
    for (int i = 0; i < 192; i += 4) {
      float4 cv4 = *(const float4*)(c + i);
      float4 wv4 = *(const float4*)(w + i);
      acc += cv4.x * wv4.x + cv4.y * wv4.y + cv4.z * wv4.z + cv4.w * wv4.w;
    }
    part[q * 64 + e] = acc;
    __syncthreads();
    if (tid < NE)
      logits[tid] = part[tid] + part[64 + tid] + part[128 + tid] + part[192 + tid] + bias[tid];
    __syncthreads();
    if (tid == 0) {
      int i0 = 0; float l0 = logits[0];
      for (int i = 1; i < NE; ++i) { float v = logits[i]; if (v > l0) { l0 = v; i0 = i; } }
      int i1 = -1; float l1 = -3.4e38f;
      for (int i = 0; i < NE; ++i) {
        if (i == i0) continue;
        float v = logits[i]; if (v > l1) { l1 = v; i1 = i; }
      }
      float w0 = 1.f / (1.f + expf(l1 - l0));
      sel_i[0] = i0; sel_i[1] = i1;
      sel_f[0] = w0; sel_f[1] = 1.f - w0;
    }
    __syncthreads();
  }
  int e0 = sel_i[0], e1 = sel_i[1];
  float w0 = sel_f[0], w1 = sel_f[1];

  for (int i = tid; i < DIM; i += 256) cnt[i] = 0;
  __syncthreads();
  for (int k = tid; k < 2 * NFRQ; k += 256) {
    int t = k >> 11, j = k & (NFRQ - 1);
    int e = t ? e1 : e0;
    int f = lidx[e * NFRQ + j];
    atomicAdd(&cnt[f / DIM], 1);
  }
  __syncthreads();
  {  // parallel exclusive scan of cnt[768]: 3 per thread
    int s0 = cnt[3 * tid], s1 = cnt[3 * tid + 1], s2 = cnt[3 * tid + 2];
    int sum = s0 + s1 + s2;
    int lane = tid & 63, wid = tid >> 6;
    int v = sum;
#pragma unroll
    for (int d = 1; d < 64; d <<= 1) {
      int u = __shfl_up(v, d);
      if (lane >= d) v += u;
    }
    if (lane == 63) wsum[wid] = v;
    __syncthreads();
    int woff = 0;
#pragma unroll
    for (int w = 0; w < 4; ++w) if (w < wid) woff += wsum[w];
    int excl = woff + v - sum;
    int* rsg = row_start + b * (DIM + 1);
    base[3 * tid]     = excl;
    base[3 * tid + 1] = excl + s0;
    base[3 * tid + 2] = excl + s0 + s1;
    rsg[3 * tid]     = excl;
    rsg[3 * tid + 1] = excl + s0;
    rsg[3 * tid + 2] = excl + s0 + s1;
    if (tid == 255) rsg[DIM] = excl + sum;   // == 4096
  }
  __syncthreads();
  for (int i = tid; i < DIM; i += 256) cnt[i] = 0;
  __syncthreads();
  for (int k = tid; k < 2 * NFRQ; k += 256) {
    int t = k >> 11, j = k & (NFRQ - 1);
    int e = t ? e1 : e0;
    float w = t ? w1 : w0;
    int f = lidx[e * NFRQ + j];
    int r = f / DIM, c = f - r * DIM;
    int pos = base[r] + atomicAdd(&cnt[r], 1);
    s_cv[b * 4096 + pos] = make_float2(__uint_as_float((unsigned)c * 3072u),
                                       coeff[e * NFRQ + j] * w * SCALE);
  }
}

// ---------------------------------------------------------------------------
// Kernel B: stage-1 as SpMM/axpy over the T2 table (NO trig in hot loop).
// Wave = one row r at a time, all 384 x in registers (2 x per lane x 3 chunks):
//   acc[x] += val * T2[c][x]       (T2 row = 3KB, L2-resident)
// Output transpose via LDS [8 rslot][384 x] tile, flushed as 16B-contiguous
// BT[x][r0..r0+7] stores. Grid (48 row-groups, 32 b), 4 waves: wave w owns
// rows {2w, 2w+1} of each 8-row group, 2 groups per block.
// ---------------------------------------------------------------------------
__global__ __launch_bounds__(256) void stage1_kernel(const int* __restrict__ row_start,
                                                     const float2* __restrict__ s_cv,
                                                     const float2* __restrict__ T2,
                                                     __hip_bfloat16* __restrict__ BT) {
  int b = blockIdx.y;
  int rg = blockIdx.x;                  // 0..47 (16 rows each)
  int tid = threadIdx.x;
  int lane = tid & 63, w = tid >> 6;
  __shared__ __hip_bfloat16 lre[8][HALF];
  __shared__ __hip_bfloat16 lim[8][HALF];
  const int* rs = row_start + b * (DIM + 1);
  const float2* cv = s_cv + b * 4096;
  __hip_bfloat16* BTb = BT + (size_t)b * HALF * KDIM;

  for (int g = 0; g < 2; ++g) {
    int rowBase = rg * 16 + g * 8;
#pragma unroll
    for (int rr = 0; rr < 2; ++rr) {
      int rslot = 2 * w + rr;
      int r = rowBase + rslot;
      int s = rs[r], e = rs[r + 1];
      float acc[12];
#pragma unroll
      for (int k = 0; k < 12; ++k) acc[k] = 0.f;

      int p = s;
      for (; p + 1 < e; p += 2) {       // 2 independent table-row streams
        float2 a = cv[p];
        float2 c2 = cv[p + 1];
        const char* ta = (const char*)T2 + (size_t)__float_as_uint(a.x);
        const char* tb = (const char*)T2 + (size_t)__float_as_uint(c2.x);
        float va = a.y, vb = c2.y;
#pragma unroll
        for (int j = 0; j < 3; ++j) {
          float4 t0 = *(const float4*)(ta + lane * 16 + j * 1024);
          float4 t1 = *(const float4*)(tb + lane * 16 + j * 1024);
          acc[4 * j + 0] += va * t0.x + vb * t1.x;
          acc[4 * j + 1] += va * t0.y + vb * t1.y;
          acc[4 * j + 2] += va * t0.z + vb * t1.z;
          acc[4 * j + 3] += va * t0.w + vb * t1.w;
        }
      }
      if (p < e) {
        float2 a = cv[p];
        const char* ta = (const char*)T2 + (size_t)__float_as_uint(a.x);
        float va = a.y;
#pragma unroll
        for (int j = 0; j < 3; ++j) {
          float4 t0 = *(const float4*)(ta + lane * 16 + j * 1024);
          acc[4 * j + 0] += va * t0.x;
          acc[4 * j + 1] += va * t0.y;
          acc[4 * j + 2] += va * t0.z;
          acc[4 * j + 3] += va * t0.w;
        }
      }
      // write LDS: x-pair packed b32 per chunk; banks 2-way (free)
#pragma unroll
      for (int j = 0; j < 3; ++j) {
        union { __hip_bfloat16 h[2]; unsigned u; } pr, pi;
        pr.h[0] = __float2bfloat16(acc[4 * j + 0]);   // re(x0)
        pr.h[1] = __float2bfloat16(acc[4 * j + 2]);   // re(x1)
        pi.h[0] = __float2bfloat16(acc[4 * j + 1]);   // -im(x0) (T2.y = -sin)
        pi.h[1] = __float2bfloat16(acc[4 * j + 3]);
        int x = 2 * lane + 128 * j;
        *(unsigned*)&lre[rslot][x] = pr.u;
        *(unsigned*)&lim[rslot][x] = pi.u;
      }
    }
    __syncthreads();
    // flush: 16B-contiguous r-chunks per x
    for (int x = tid; x < HALF; x += 256) {
      union { ushort h[8]; uint4 v; } ur, ui;
#pragma unroll
      for (int k = 0; k < 8; ++k) {
        ur.h[k] = *(const ushort*)&lre[k][x];
        ui.h[k] = *(const ushort*)&lim[k][x];
      }
      __hip_bfloat16* dst = BTb + (size_t)x * KDIM + rowBase;
      *(uint4*)dst         = ur.v;
      *(uint4*)(dst + DIM) = ui.v;
    }
    __syncthreads();
  }
}

// ---------------------------------------------------------------------------
// Kernel C: quadrant GEMM (bid < 1152) + folded Nyquist blocks (bid >= 1152).
//   acc1 = A_cos . Re  (kt<768);  acc2 = A_sin . (-Im)  (kt>=768)
//   out[y,x]=out[-y,-x]=acc1+acc2 ; out[-y,x]=out[y,-x]=acc1-acc2
// BM=BN=64, double-buffered LDS, one barrier/K-step, XCD-swizzled.
// ---------------------------------------------------------------------------
__device__ inline void gload_lds16(const void* g, void* l) {
  __builtin_amdgcn_global_load_lds((const __attribute__((address_space(1))) void*)g,
                                   (__attribute__((address_space(3))) void*)l, 16, 0, 0);
}

__global__ __launch_bounds__(256) void gemm_kernel(const __hip_bfloat16* __restrict__ A,
                                                   const __hip_bfloat16* __restrict__ BT,
                                                   const int* __restrict__ row_start,
                                                   const float2* __restrict__ s_cv,
                                                   float* __restrict__ C) {
  int bid = blockIdx.x;
  int tid = threadIdx.x;
  __shared__ __align__(16) __hip_bfloat16 As[2][64 * 32];
  __shared__ __align__(16) __hip_bfloat16 Bs[2][64 * 32];

  if (bid >= 1152) {                  // ---- Nyquist blocks ----
    int t = bid - 1152;
    int slice = t & 3, b = t >> 2;
    float* ob = C + (size_t)b * DIM * DIM;
    if (slice == 3) {                 // row y=384: sum_r (-1)^r Re[r,x] from BT
      for (int x = tid; x < HALF; x += 256) {
        const __hip_bfloat16* btx = BT + ((size_t)(b * HALF + x)) * KDIM;
        float acc = 0.f;
        for (int r = 0; r < DIM; r += 8) {
          union { uint4 v4; __hip_bfloat16 h[8]; } u;
          u.v4 = *(const uint4*)(btx + r);
#pragma unroll
          for (int q = 0; q < 8; ++q) {
            float v = __bfloat162float(u.h[q]);
            acc += (q & 1) ? -v : v;
          }
        }
        int xm = x ? DIM - x : 0;
        ob[(size_t)HALF * DIM + x]  = acc;
        ob[(size_t)HALF * DIM + xm] = acc;
      }
      return;
    }
    // slices 0..2: column x=384
    float* Re384 = (float*)As;        // reuse LDS (3KB of 8KB)
    const int* rs = row_start + b * (DIM + 1);
    const float2* cv = s_cv + b * 4096;
    for (int r = tid; r < DIM; r += 256) {
      int s = rs[r], e = rs[r + 1];
      float acc = 0.f;
      for (int p = s; p < e; ++p) {
        float2 c = cv[p];
        int ci = (int)(__float_as_uint(c.x) / 3072u);
        acc += (ci & 1) ? -c.y : c.y;
      }
      Re384[r] = acc;
    }
    __syncthreads();
    int y = slice * 129 + tid;
    if (tid < 129 && y <= HALF) {
      float yf = (float)y;
      float acc = 0.f;
      for (int r = 0; r < DIM; ++r) {
        float rev = (yf * (float)r) * INV768;
        float f, cs;
        asm("v_fract_f32 %0, %1" : "=v"(f) : "v"(rev));
        asm("v_cos_f32 %0, %1" : "=v"(cs) : "v"(f));
        acc += Re384[r] * cs;
      }
      int ym = y ? DIM - y : 0;
      ob[(size_t)y  * DIM + HALF] = acc;
      ob[(size_t)ym * DIM + HALF] = acc;
    }
    return;
  }

  // ---- GEMM blocks ----
  int swz = (bid & 7) * 144 + (bid >> 3);
  int b = swz / 36; int rem = swz - b * 36;
  int bx = rem / 6, by = rem % 6;

  const __hip_bfloat16* Bp = BT + (size_t)b * HALF * KDIM;
  float* Cp = C + (size_t)b * DIM * DIM;
  int y0 = by * 64, x0 = bx * 64;

  int wv = tid >> 6, lane = tid & 63;
  int wr = wv >> 1, wc = wv & 1;        // wave: 32x32 sub-tile
  int lhi = lane >> 4, llo = lane & 15;
  int arow = tid >> 2, aoff = (tid & 3) * 8;

  f32x4 acc1[2][2] = {};
  f32x4 acc2[2][2] = {};

  gload_lds16(A  + (size_t)(y0 + arow) * KDIM + aoff, As[0] + tid * 8);
  gload_lds16(Bp + (size_t)(x0 + arow) * KDIM + aoff, Bs[0] + tid * 8);
  __syncthreads();

  auto step = [&](int t, f32x4 (&acc)[2][2], bool last) {
    int cur = t & 1;
    if (!last) {
      int ktn = (t + 1) * 32;
      gload_lds16(A  + (size_t)(y0 + arow) * KDIM + ktn + aoff, As[cur ^ 1] + tid * 8);
      gload_lds16(Bp + (size_t)(x0 + arow) * KDIM + ktn + aoff, Bs[cur ^ 1] + tid * 8);
    }
    bf16x8 af[2], bfr[2];
#pragma unroll
    for (int i = 0; i < 2; ++i)
      af[i] = *(const bf16x8*)(As[cur] + (wr * 32 + i * 16 + llo) * 32 + lhi * 8);
#pragma unroll
    for (int j = 0; j < 2; ++j)
      bfr[j] = *(const bf16x8*)(Bs[cur] + (wc * 32 + j * 16 + llo) * 32 + lhi * 8);
#pragma unroll
    for (int i = 0; i < 2; ++i)
#pragma unroll
      for (int j = 0; j < 2; ++j)
        acc[i][j] = __builtin_amdgcn_mfma_f32_16x16x32_bf16(af[i], bfr[j], acc[i][j], 0, 0, 0);
    if (!last) __syncthreads();
  };

  for (int t = 0; t < 24; ++t) step(t, acc1, false);       // cos/Re half
  for (int t = 24; t < 48; ++t) step(t, acc2, t == 47);    // sin/-Im half

#pragma unroll
  for (int i = 0; i < 2; ++i) {
#pragma unroll
    for (int j = 0; j < 2; ++j) {
      int x = x0 + wc * 32 + j * 16 + llo;
      int xm = x ? DIM - x : 0;
#pragma unroll
      for (int q = 0; q < 4; ++q) {
        int y = y0 + wr * 32 + i * 16 + lhi * 4 + q;
        int ym = y ? DIM - y : 0;
        float c1 = acc1[i][j][q], c2 = acc2[i][j][q];
        float vd = c1 + c2;
        float vs = c1 - c2;
        Cp[(size_t)y  * DIM + x]  = vd;
        Cp[(size_t)ym * DIM + xm] = vd;
        Cp[(size_t)y  * DIM + xm] = vs;
        Cp[(size_t)ym * DIM + x]  = vs;
      }
    }
  }
}

// ---------------------------------------------------------------------------
extern "C" void kernel_launch(void* const* d_in, const int* in_sizes, int n_in,
                              void* d_out, int out_size, void* d_ws, size_t ws_size,
                              hipStream_t stream) {
  const float* cls   = (const float*)d_in[0];
  const float* Wr    = (const float*)d_in[1];
  const float* br    = (const float*)d_in[2];
  const float* coeff = (const float*)d_in[3];
  const int*   lidx  = (const int*)d_in[4];
  float* out = (float*)d_out;

  char* ws = (char*)d_ws;
  int*    row_start = (int*)(ws + 0);           //    98,432
  float2* s_cv      = (float2*)(ws + 98944);    // 1,048,576 (ends 1,147,520)
  __hip_bfloat16* A  = (__hip_bfloat16*)(ws + 1147520);  // 1,179,648 (ends 2,327,168)
  float2* T2        = (float2*)(ws + 2327168);  // 2,359,296 (ends 4,686,464)
  __hip_bfloat16* BT = (__hip_bfloat16*)(ws + 4686464);  // 37,748,736 (~42.4 MB total)

  prep_kernel<<<32 + HALF + DIM, 256, 0, stream>>>(cls, Wr, br, coeff, lidx,
                                                   row_start, s_cv, A, T2);
  stage1_kernel<<<dim3(48, NB), 256, 0, stream>>>(row_start, s_cv, T2, BT);
  gemm_kernel<<<1152 + 4 * NB, 256, 0, stream>>>(A, BT, row_start, s_cv, out);
}

// Round 8
// 128.603 us; speedup vs baseline: 4.9497x; 1.0116x over previous
//
#include <hip/hip_runtime.h>
#include <hip/hip_bf16.h>

#define DIM 768
#define NE 64
#define NFRQ 2048
#define NB 32
#define KDIM 1536               // 2*DIM (Re rows then -Im rows)
#define HALF 384                // computed quadrant extent (y,x in [0,384))
#define TWO_PI 6.283185307179586f
#define INV768 (1.0f / 768.0f)
#define SCALE (300.0f / (float)(DIM * DIM))   // ALPHA / (dim*dim), folded into values

typedef __attribute__((ext_vector_type(8))) short bf16x8;   // 8 bf16 (4 VGPRs)
typedef __attribute__((ext_vector_type(4))) float f32x4;    // MFMA accumulator

// ---------------------------------------------------------------------------
// Kernel A "prep" (one launch, 3 roles by blockIdx):
//  bid <  32        : fused router (logits->top2->weights) + bucket-sort build
//  32 <= bid < 416  : A twiddle row y = bid-32   (cos | +sin), bf16
//  bid >= 416       : T2 table row c = bid-416: float2 (cos(2pi c x/768), -sin)
// s_cv entries are (uint byte-offset c*3072 as float bits, weighted val).
// ---------------------------------------------------------------------------
__global__ __launch_bounds__(256) void prep_kernel(const float* __restrict__ cls,
                                                   const float* __restrict__ W,
                                                   const float* __restrict__ bias,
                                                   const float* __restrict__ coeff,
                                                   const int* __restrict__ lidx,
                                                   int* __restrict__ row_start,
                                                   float2* __restrict__ s_cv,
                                                   __hip_bfloat16* __restrict__ A,
                                                   float2* __restrict__ T2) {
  int bid = blockIdx.x;
  int tid = threadIdx.x;

  if (bid >= 32 + HALF) {             // ---- T2 rows ----
    int c = bid - (32 + HALF);        // 0..767
    for (int x = tid; x < HALF; x += 256) {
      float prod = (float)(c * x);    // < 2^24, exact
      float f, sn, cs;
      float rev = prod * INV768;
      asm("v_fract_f32 %0, %1" : "=v"(f) : "v"(rev));
      asm("v_sin_f32 %0, %1" : "=v"(sn) : "v"(f));
      asm("v_cos_f32 %0, %1" : "=v"(cs) : "v"(f));
      T2[(size_t)c * HALF + x] = make_float2(cs, -sn);
    }
    return;
  }
  if (bid >= 32) {                    // ---- A twiddle rows ----
    int y = bid - 32;                 // 0..383
    if (tid < 192) {
      int r0 = tid * 4;
      union { __hip_bfloat16 h[4]; ushort4 v; } uc, us;
#pragma unroll
      for (int j = 0; j < 4; ++j) {
        int m = (y * (r0 + j)) % DIM;
        float s, c;
        sincosf((TWO_PI / (float)DIM) * (float)m, &s, &c);
        uc.h[j] = __float2bfloat16(c);
        us.h[j] = __float2bfloat16(s);
      }
      *(ushort4*)(A + y * KDIM + r0)       = uc.v;
      *(ushort4*)(A + y * KDIM + DIM + r0) = us.v;
    }
    return;
  }

  // ---- router + build, batch b = bid ----
  int b = bid;
  __shared__ int cnt[DIM];
  __shared__ int base[DIM];
  __shared__ int wsum[4];
  __shared__ int sel_i[2];
  __shared__ float sel_f[2];
  float* part   = (float*)cnt;        // 4x64 floats (overlay, consumed pre-build)
  float* logits = (float*)base;       // 64 floats (overlay)

  {
    int e = tid & 63, q = tid >> 6;
    const float* c = cls + b * DIM + q * 192;
    const float* w = W + e * DIM + q * 192;
    float acc = 0.f;
#pragma unroll 4
    for (int i = 0; i < 192; i += 4) {
      float4 cv4 = *(const float4*)(c + i);
      float4 wv4 = *(const float4*)(w + i);
      acc += cv4.x * wv4.x + cv4.y * wv4.y + cv4.z * wv4.z + cv4.w * wv4.w;
    }
    part[q * 64 + e] = acc;
    __syncthreads();
    if (tid < NE)
      logits[tid] = part[tid] + part[64 + tid] + part[128 + tid] + part[192 + tid] + bias[tid];
    __syncthreads();
    if (tid == 0) {
      int i0 = 0; float l0 = logits[0];
      for (int i = 1; i < NE; ++i) { float v = logits[i]; if (v > l0) { l0 = v; i0 = i; } }
      int i1 = -1; float l1 = -3.4e38f;
      for (int i = 0; i < NE; ++i) {
        if (i == i0) continue;
        float v = logits[i]; if (v > l1) { l1 = v; i1 = i; }
      }
      float w0 = 1.f / (1.f + expf(l1 - l0));
      sel_i[0] = i0; sel_i[1] = i1;
      sel_f[0] = w0; sel_f[1] = 1.f - w0;
    }
    __syncthreads();
  }
  int e0 = sel_i[0], e1 = sel_i[1];
  float w0 = sel_f[0], w1 = sel_f[1];

  for (int i = tid; i < DIM; i += 256) cnt[i] = 0;
  __syncthreads();
  for (int k = tid; k < 2 * NFRQ; k += 256) {
    int t = k >> 11, j = k & (NFRQ - 1);
    int e = t ? e1 : e0;
    int f = lidx[e * NFRQ + j];
    atomicAdd(&cnt[f / DIM], 1);
  }
  __syncthreads();
  {  // parallel exclusive scan of cnt[768]: 3 per thread
    int s0 = cnt[3 * tid], s1 = cnt[3 * tid + 1], s2 = cnt[3 * tid + 2];
    int sum = s0 + s1 + s2;
    int lane = tid & 63, wid = tid >> 6;
    int v = sum;
#pragma unroll
    for (int d = 1; d < 64; d <<= 1) {
      int u = __shfl_up(v, d);
      if (lane >= d) v += u;
    }
    if (lane == 63) wsum[wid] = v;
    __syncthreads();
    int woff = 0;
#pragma unroll
    for (int w = 0; w < 4; ++w) if (w < wid) woff += wsum[w];
    int excl = woff + v - sum;
    int* rsg = row_start + b * (DIM + 1);
    base[3 * tid]     = excl;
    base[3 * tid + 1] = excl + s0;
    base[3 * tid + 2] = excl + s0 + s1;
    rsg[3 * tid]     = excl;
    rsg[3 * tid + 1] = excl + s0;
    rsg[3 * tid + 2] = excl + s0 + s1;
    if (tid == 255) rsg[DIM] = excl + sum;   // == 4096
  }
  __syncthreads();
  for (int i = tid; i < DIM; i += 256) cnt[i] = 0;
  __syncthreads();
  for (int k = tid; k < 2 * NFRQ; k += 256) {
    int t = k >> 11, j = k & (NFRQ - 1);
    int e = t ? e1 : e0;
    float w = t ? w1 : w0;
    int f = lidx[e * NFRQ + j];
    int r = f / DIM, c = f - r * DIM;
    int pos = base[r] + atomicAdd(&cnt[r], 1);
    s_cv[b * 4096 + pos] = make_float2(__uint_as_float((unsigned)c * 3072u),
                                       coeff[e * NFRQ + j] * w * SCALE);
  }
}

// ---------------------------------------------------------------------------
// Kernel B: stage-1 as SpMM/axpy over the T2 table (NO trig in hot loop).
// ---------------------------------------------------------------------------
__global__ __launch_bounds__(256) void stage1_kernel(const int* __restrict__ row_start,
                                                     const float2* __restrict__ s_cv,
                                                     const float2* __restrict__ T2,
                                                     __hip_bfloat16* __restrict__ BT) {
  int b = blockIdx.y;
  int rg = blockIdx.x;                  // 0..47 (16 rows each)
  int tid = threadIdx.x;
  int lane = tid & 63, w = tid >> 6;
  __shared__ __hip_bfloat16 lre[8][HALF];
  __shared__ __hip_bfloat16 lim[8][HALF];
  const int* rs = row_start + b * (DIM + 1);
  const float2* cv = s_cv + b * 4096;
  __hip_bfloat16* BTb = BT + (size_t)b * HALF * KDIM;

  for (int g = 0; g < 2; ++g) {
    int rowBase = rg * 16 + g * 8;
#pragma unroll
    for (int rr = 0; rr < 2; ++rr) {
      int rslot = 2 * w + rr;
      int r = rowBase + rslot;
      int s = rs[r], e = rs[r + 1];
      float acc[12];
#pragma unroll
      for (int k = 0; k < 12; ++k) acc[k] = 0.f;

      int p = s;
      for (; p + 1 < e; p += 2) {       // 2 independent table-row streams
        float2 a = cv[p];
        float2 c2 = cv[p + 1];
        const char* ta = (const char*)T2 + (size_t)__float_as_uint(a.x);
        const char* tb = (const char*)T2 + (size_t)__float_as_uint(c2.x);
        float va = a.y, vb = c2.y;
#pragma unroll
        for (int j = 0; j < 3; ++j) {
          float4 t0 = *(const float4*)(ta + lane * 16 + j * 1024);
          float4 t1 = *(const float4*)(tb + lane * 16 + j * 1024);
          acc[4 * j + 0] += va * t0.x + vb * t1.x;
          acc[4 * j + 1] += va * t0.y + vb * t1.y;
          acc[4 * j + 2] += va * t0.z + vb * t1.z;
          acc[4 * j + 3] += va * t0.w + vb * t1.w;
        }
      }
      if (p < e) {
        float2 a = cv[p];
        const char* ta = (const char*)T2 + (size_t)__float_as_uint(a.x);
        float va = a.y;
#pragma unroll
        for (int j = 0; j < 3; ++j) {
          float4 t0 = *(const float4*)(ta + lane * 16 + j * 1024);
          acc[4 * j + 0] += va * t0.x;
          acc[4 * j + 1] += va * t0.y;
          acc[4 * j + 2] += va * t0.z;
          acc[4 * j + 3] += va * t0.w;
        }
      }
#pragma unroll
      for (int j = 0; j < 3; ++j) {
        union { __hip_bfloat16 h[2]; unsigned u; } pr, pi;
        pr.h[0] = __float2bfloat16(acc[4 * j + 0]);
        pr.h[1] = __float2bfloat16(acc[4 * j + 2]);
        pi.h[0] = __float2bfloat16(acc[4 * j + 1]);
        pi.h[1] = __float2bfloat16(acc[4 * j + 3]);
        int x = 2 * lane + 128 * j;
        *(unsigned*)&lre[rslot][x] = pr.u;
        *(unsigned*)&lim[rslot][x] = pi.u;
      }
    }
    __syncthreads();
    for (int x = tid; x < HALF; x += 256) {
      union { ushort h[8]; uint4 v; } ur, ui;
#pragma unroll
      for (int k = 0; k < 8; ++k) {
        ur.h[k] = *(const ushort*)&lre[k][x];
        ui.h[k] = *(const ushort*)&lim[k][x];
      }
      __hip_bfloat16* dst = BTb + (size_t)x * KDIM + rowBase;
      *(uint4*)dst         = ur.v;
      *(uint4*)(dst + DIM) = ui.v;
    }
    __syncthreads();
  }
}

// ---------------------------------------------------------------------------
// Kernel C: nyq blocks FIRST (bid < 128), then quadrant GEMM with a
// depth-3 counted-vmcnt pipeline (T4): 4 LDS buffer pairs, raw s_barrier,
// s_waitcnt vmcnt(4) in steady state (never 0 until the tail).
//   acc1 = A_cos . Re  (kt<768);  acc2 = A_sin . (-Im)  (kt>=768)
//   out[y,x]=out[-y,-x]=acc1+acc2 ; out[-y,x]=out[y,-x]=acc1-acc2
// ---------------------------------------------------------------------------
__device__ inline void gload_lds16(const void* g, void* l) {
  __builtin_amdgcn_global_load_lds((const __attribute__((address_space(1))) void*)g,
                                   (__attribute__((address_space(3))) void*)l, 16, 0, 0);
}

__global__ __launch_bounds__(256) void gemm_kernel(const __hip_bfloat16* __restrict__ A,
                                                   const __hip_bfloat16* __restrict__ BT,
                                                   const int* __restrict__ row_start,
                                                   const float2* __restrict__ s_cv,
                                                   float* __restrict__ C) {
  int bid = blockIdx.x;
  int tid = threadIdx.x;
  __shared__ __align__(16) __hip_bfloat16 As[4][64 * 32];   // 16KB
  __shared__ __align__(16) __hip_bfloat16 Bs[4][64 * 32];   // 16KB

  if (bid < 4 * NB) {                 // ---- Nyquist blocks (overlap the GEMM) ----
    int slice = bid & 3, b = bid >> 2;
    float* ob = C + (size_t)b * DIM * DIM;
    if (slice == 3) {                 // row y=384: sum_r (-1)^r Re[r,x] from BT
      for (int x = tid; x < HALF; x += 256) {
        const __hip_bfloat16* btx = BT + ((size_t)(b * HALF + x)) * KDIM;
        float acc = 0.f;
        for (int r = 0; r < DIM; r += 8) {
          union { uint4 v4; __hip_bfloat16 h[8]; } u;
          u.v4 = *(const uint4*)(btx + r);
#pragma unroll
          for (int q = 0; q < 8; ++q) {
            float v = __bfloat162float(u.h[q]);
            acc += (q & 1) ? -v : v;
          }
        }
        int xm = x ? DIM - x : 0;
        ob[(size_t)HALF * DIM + x]  = acc;
        ob[(size_t)HALF * DIM + xm] = acc;
      }
      return;
    }
    // slices 0..2: column x=384
    float* Re384 = (float*)As;        // reuse LDS
    const int* rs = row_start + b * (DIM + 1);
    const float2* cv = s_cv + b * 4096;
    for (int r = tid; r < DIM; r += 256) {
      int s = rs[r], e = rs[r + 1];
      float acc = 0.f;
      for (int p = s; p < e; ++p) {
        float2 c = cv[p];
        int ci = (int)(__float_as_uint(c.x) / 3072u);
        acc += (ci & 1) ? -c.y : c.y;
      }
      Re384[r] = acc;
    }
    __syncthreads();
    int y = slice * 129 + tid;
    if (tid < 129 && y <= HALF) {
      float yf = (float)y;
      float a0 = 0.f, a1 = 0.f, a2 = 0.f, a3 = 0.f;   // 4 independent chains
      for (int r = 0; r < DIM; r += 4) {
        float f0, f1, f2, f3, c0, c1, c2, c3;
        float v0 = (yf * (float)(r + 0)) * INV768;
        float v1 = (yf * (float)(r + 1)) * INV768;
        float v2 = (yf * (float)(r + 2)) * INV768;
        float v3 = (yf * (float)(r + 3)) * INV768;
        asm("v_fract_f32 %0, %1" : "=v"(f0) : "v"(v0));
        asm("v_fract_f32 %0, %1" : "=v"(f1) : "v"(v1));
        asm("v_fract_f32 %0, %1" : "=v"(f2) : "v"(v2));
        asm("v_fract_f32 %0, %1" : "=v"(f3) : "v"(v3));
        asm("v_cos_f32 %0, %1" : "=v"(c0) : "v"(f0));
        asm("v_cos_f32 %0, %1" : "=v"(c1) : "v"(f1));
        asm("v_cos_f32 %0, %1" : "=v"(c2) : "v"(f2));
        asm("v_cos_f32 %0, %1" : "=v"(c3) : "v"(f3));
        a0 += Re384[r + 0] * c0;
        a1 += Re384[r + 1] * c1;
        a2 += Re384[r + 2] * c2;
        a3 += Re384[r + 3] * c3;
      }
      float acc = (a0 + a1) + (a2 + a3);
      int ym = y ? DIM - y : 0;
      ob[(size_t)y  * DIM + HALF] = acc;
      ob[(size_t)ym * DIM + HALF] = acc;
    }
    return;
  }

  // ---- GEMM blocks ----
  int gbid = bid - 4 * NB;
  int swz = (gbid & 7) * 144 + (gbid >> 3);
  int b = swz / 36; int rem = swz - b * 36;
  int bx = rem / 6, by = rem % 6;

  const __hip_bfloat16* Bp = BT + (size_t)b * HALF * KDIM;
  float* Cp = C + (size_t)b * DIM * DIM;
  int y0 = by * 64, x0 = bx * 64;

  int wv = tid >> 6, lane = tid & 63;
  int wr = wv >> 1, wc = wv & 1;        // wave: 32x32 sub-tile
  int lhi = lane >> 4, llo = lane & 15;
  int arow = tid >> 2, aoff = (tid & 3) * 8;

  f32x4 acc1[2][2] = {};
  f32x4 acc2[2][2] = {};

  const __hip_bfloat16* Aip = A  + (size_t)(y0 + arow) * KDIM + aoff;
  const __hip_bfloat16* Bip = Bp + (size_t)(x0 + arow) * KDIM + aoff;

  auto stage = [&](int t) {             // 2 vmem instr per wave
    int buf = t & 3;
    int kt = t * 32;
    gload_lds16(Aip + kt, As[buf] + tid * 8);
    gload_lds16(Bip + kt, Bs[buf] + tid * 8);
  };
  auto compute = [&](int t, f32x4 (&acc)[2][2]) {
    int buf = t & 3;
    bf16x8 af[2], bfr[2];
#pragma unroll
    for (int i = 0; i < 2; ++i)
      af[i] = *(const bf16x8*)(As[buf] + (wr * 32 + i * 16 + llo) * 32 + lhi * 8);
#pragma unroll
    for (int j = 0; j < 2; ++j)
      bfr[j] = *(const bf16x8*)(Bs[buf] + (wc * 32 + j * 16 + llo) * 32 + lhi * 8);
#pragma unroll
    for (int i = 0; i < 2; ++i)
#pragma unroll
      for (int j = 0; j < 2; ++j)
        acc[i][j] = __builtin_amdgcn_mfma_f32_16x16x32_bf16(af[i], bfr[j], acc[i][j], 0, 0, 0);
  };

  stage(0); stage(1); stage(2);         // depth-3 prologue (6 vmem in flight)

  for (int t = 0; t < 24; ++t) {        // cos/Re half
    asm volatile("s_waitcnt vmcnt(4)" ::: "memory");   // wait stage t only
    __builtin_amdgcn_s_barrier();
    __builtin_amdgcn_sched_barrier(0);
    stage(t + 3);
    compute(t, acc1);
  }
  for (int t = 24; t < 46; ++t) {       // sin/-Im half
    asm volatile("s_waitcnt vmcnt(4)" ::: "memory");
    __builtin_amdgcn_s_barrier();
    __builtin_amdgcn_sched_barrier(0);
    if (t < 45) stage(t + 3);
    compute(t, acc2);
  }
  asm volatile("s_waitcnt vmcnt(2)" ::: "memory");     // tail: stage 46
  __builtin_amdgcn_s_barrier();
  __builtin_amdgcn_sched_barrier(0);
  compute(46, acc2);
  asm volatile("s_waitcnt vmcnt(0)" ::: "memory");     // tail: stage 47
  __builtin_amdgcn_s_barrier();
  __builtin_amdgcn_sched_barrier(0);
  compute(47, acc2);

  // C/D layout: col = lane&15, row = (lane>>4)*4 + reg   [m89-verified]
#pragma unroll
  for (int i = 0; i < 2; ++i) {
#pragma unroll
    for (int j = 0; j < 2; ++j) {
      int x = x0 + wc * 32 + j * 16 + llo;
      int xm = x ? DIM - x : 0;
#pragma unroll
      for (int q = 0; q < 4; ++q) {
        int y = y0 + wr * 32 + i * 16 + lhi * 4 + q;
        int ym = y ? DIM - y : 0;
        float c1 = acc1[i][j][q], c2 = acc2[i][j][q];
        float vd = c1 + c2;
        float vs = c1 - c2;
        Cp[(size_t)y  * DIM + x]  = vd;
        Cp[(size_t)ym * DIM + xm] = vd;
        Cp[(size_t)y  * DIM + xm] = vs;
        Cp[(size_t)ym * DIM + x]  = vs;
      }
    }
  }
}

// ---------------------------------------------------------------------------
extern "C" void kernel_launch(void* const* d_in, const int* in_sizes, int n_in,
                              void* d_out, int out_size, void* d_ws, size_t ws_size,
                              hipStream_t stream) {
  const float* cls   = (const float*)d_in[0];
  const float* Wr    = (const float*)d_in[1];
  const float* br    = (const float*)d_in[2];
  const float* coeff = (const float*)d_in[3];
  const int*   lidx  = (const int*)d_in[4];
  float* out = (float*)d_out;

  char* ws = (char*)d_ws;
  int*    row_start = (int*)(ws + 0);           //    98,432
  float2* s_cv      = (float2*)(ws + 98944);    // 1,048,576 (ends 1,147,520)
  __hip_bfloat16* A  = (__hip_bfloat16*)(ws + 1147520);  // 1,179,648 (ends 2,327,168)
  float2* T2        = (float2*)(ws + 2327168);  // 2,359,296 (ends 4,686,464)
  __hip_bfloat16* BT = (__hip_bfloat16*)(ws + 4686464);  // 37,748,736 (~42.4 MB total)

  prep_kernel<<<32 + HALF + DIM, 256, 0, stream>>>(cls, Wr, br, coeff, lidx,
                                                   row_start, s_cv, A, T2);
  stage1_kernel<<<dim3(48, NB), 256, 0, stream>>>(row_start, s_cv, T2, BT);
  gemm_kernel<<<4 * NB + 1152, 256, 0, stream>>>(A, BT, row_start, s_cv, out);
}

// Round 9
// 128.143 us; speedup vs baseline: 4.9674x; 1.0036x over previous
//
#include <hip/hip_runtime.h>
#include <hip/hip_bf16.h>

#define DIM 768
#define NE 64
#define NFRQ 2048
#define NB 32
#define KDIM 1536               // 2*DIM (Re rows then -Im rows)
#define HALF 384                // computed quadrant extent (y,x in [0,384))
#define TWO_PI 6.283185307179586f
#define INV768 (1.0f / 768.0f)
#define SCALE (300.0f / (float)(DIM * DIM))   // ALPHA / (dim*dim), folded into values

typedef __attribute__((ext_vector_type(8))) short bf16x8;   // 8 bf16 (4 VGPRs)
typedef __attribute__((ext_vector_type(4))) float f32x4;    // MFMA accumulator

// ---------------------------------------------------------------------------
// Kernel A "prep" (one launch, 3 roles by blockIdx):
//  bid <  32        : fused router (logits->top2->weights) + bucket-sort build
//  32 <= bid < 416  : A twiddle row y = bid-32   (cos | +sin), bf16
//  bid >= 416       : T2 table row c = bid-416: float2 (cos(2pi c x/768), -sin)
// s_cv entries are (uint byte-offset c*3072 as float bits, weighted val).
// ---------------------------------------------------------------------------
__global__ __launch_bounds__(256) void prep_kernel(const float* __restrict__ cls,
                                                   const float* __restrict__ W,
                                                   const float* __restrict__ bias,
                                                   const float* __restrict__ coeff,
                                                   const int* __restrict__ lidx,
                                                   int* __restrict__ row_start,
                                                   float2* __restrict__ s_cv,
                                                   __hip_bfloat16* __restrict__ A,
                                                   float2* __restrict__ T2) {
  int bid = blockIdx.x;
  int tid = threadIdx.x;

  if (bid >= 32 + HALF) {             // ---- T2 rows ----
    int c = bid - (32 + HALF);        // 0..767
    for (int x = tid; x < HALF; x += 256) {
      float prod = (float)(c * x);    // < 2^24, exact
      float f, sn, cs;
      float rev = prod * INV768;
      asm("v_fract_f32 %0, %1" : "=v"(f) : "v"(rev));
      asm("v_sin_f32 %0, %1" : "=v"(sn) : "v"(f));
      asm("v_cos_f32 %0, %1" : "=v"(cs) : "v"(f));
      T2[(size_t)c * HALF + x] = make_float2(cs, -sn);
    }
    return;
  }
  if (bid >= 32) {                    // ---- A twiddle rows ----
    int y = bid - 32;                 // 0..383
    if (tid < 192) {
      int r0 = tid * 4;
      union { __hip_bfloat16 h[4]; ushort4 v; } uc, us;
#pragma unroll
      for (int j = 0; j < 4; ++j) {
        int m = (y * (r0 + j)) % DIM;
        float s, c;
        sincosf((TWO_PI / (float)DIM) * (float)m, &s, &c);
        uc.h[j] = __float2bfloat16(c);
        us.h[j] = __float2bfloat16(s);
      }
      *(ushort4*)(A + y * KDIM + r0)       = uc.v;
      *(ushort4*)(A + y * KDIM + DIM + r0) = us.v;
    }
    return;
  }

  // ---- router + build, batch b = bid ----
  int b = bid;
  __shared__ int cnt[DIM];
  __shared__ int base[DIM];
  __shared__ int wsum[4];
  __shared__ int sel_i[2];
  __shared__ float sel_f[2];
  float* part   = (float*)cnt;        // 4x64 floats (overlay, consumed pre-build)
  float* logits = (float*)base;       // 64 floats (overlay)

  {
    int e = tid & 63, q = tid >> 6;
    const float* c = cls + b * DIM + q * 192;
    const float* w = W + e * DIM + q * 192;
    float acc = 0.f;
#pragma unroll 4
    for (int i = 0; i < 192; i += 4) {
      float4 cv4 = *(const float4*)(c + i);
      float4 wv4 = *(const float4*)(w + i);
      acc += cv4.x * wv4.x + cv4.y * wv4.y + cv4.z * wv4.z + cv4.w * wv4.w;
    }
    part[q * 64 + e] = acc;
    __syncthreads();
    if (tid < NE)
      logits[tid] = part[tid] + part[64 + tid] + part[128 + tid] + part[192 + tid] + bias[tid];
    __syncthreads();
    if (tid == 0) {
      int i0 = 0; float l0 = logits[0];
      for (int i = 1; i < NE; ++i) { float v = logits[i]; if (v > l0) { l0 = v; i0 = i; } }
      int i1 = -1; float l1 = -3.4e38f;
      for (int i = 0; i < NE; ++i) {
        if (i == i0) continue;
        float v = logits[i]; if (v > l1) { l1 = v; i1 = i; }
      }
      float w0 = 1.f / (1.f + expf(l1 - l0));
      sel_i[0] = i0; sel_i[1] = i1;
      sel_f[0] = w0; sel_f[1] = 1.f - w0;
    }
    __syncthreads();
  }
  int e0 = sel_i[0], e1 = sel_i[1];
  float w0 = sel_f[0], w1 = sel_f[1];

  for (int i = tid; i < DIM; i += 256) cnt[i] = 0;
  __syncthreads();
  for (int k = tid; k < 2 * NFRQ; k += 256) {
    int t = k >> 11, j = k & (NFRQ - 1);
    int e = t ? e1 : e0;
    int f = lidx[e * NFRQ + j];
    atomicAdd(&cnt[f / DIM], 1);
  }
  __syncthreads();
  {  // parallel exclusive scan of cnt[768]: 3 per thread
    int s0 = cnt[3 * tid], s1 = cnt[3 * tid + 1], s2 = cnt[3 * tid + 2];
    int sum = s0 + s1 + s2;
    int lane = tid & 63, wid = tid >> 6;
    int v = sum;
#pragma unroll
    for (int d = 1; d < 64; d <<= 1) {
      int u = __shfl_up(v, d);
      if (lane >= d) v += u;
    }
    if (lane == 63) wsum[wid] = v;
    __syncthreads();
    int woff = 0;
#pragma unroll
    for (int w = 0; w < 4; ++w) if (w < wid) woff += wsum[w];
    int excl = woff + v - sum;
    int* rsg = row_start + b * (DIM + 1);
    base[3 * tid]     = excl;
    base[3 * tid + 1] = excl + s0;
    base[3 * tid + 2] = excl + s0 + s1;
    rsg[3 * tid]     = excl;
    rsg[3 * tid + 1] = excl + s0;
    rsg[3 * tid + 2] = excl + s0 + s1;
    if (tid == 255) rsg[DIM] = excl + sum;   // == 4096
  }
  __syncthreads();
  for (int i = tid; i < DIM; i += 256) cnt[i] = 0;
  __syncthreads();
  for (int k = tid; k < 2 * NFRQ; k += 256) {
    int t = k >> 11, j = k & (NFRQ - 1);
    int e = t ? e1 : e0;
    float w = t ? w1 : w0;
    int f = lidx[e * NFRQ + j];
    int r = f / DIM, c = f - r * DIM;
    int pos = base[r] + atomicAdd(&cnt[r], 1);
    s_cv[b * 4096 + pos] = make_float2(__uint_as_float((unsigned)c * 3072u),
                                       coeff[e * NFRQ + j] * w * SCALE);
  }
}

// ---------------------------------------------------------------------------
// Kernel B: stage-1 as SpMM/axpy over the T2 table (NO trig in hot loop).
// ---------------------------------------------------------------------------
__global__ __launch_bounds__(256) void stage1_kernel(const int* __restrict__ row_start,
                                                     const float2* __restrict__ s_cv,
                                                     const float2* __restrict__ T2,
                                                     __hip_bfloat16* __restrict__ BT) {
  int b = blockIdx.y;
  int rg = blockIdx.x;                  // 0..47 (16 rows each)
  int tid = threadIdx.x;
  int lane = tid & 63, w = tid >> 6;
  __shared__ __hip_bfloat16 lre[8][HALF];
  __shared__ __hip_bfloat16 lim[8][HALF];
  const int* rs = row_start + b * (DIM + 1);
  const float2* cv = s_cv + b * 4096;
  __hip_bfloat16* BTb = BT + (size_t)b * HALF * KDIM;

  for (int g = 0; g < 2; ++g) {
    int rowBase = rg * 16 + g * 8;
#pragma unroll
    for (int rr = 0; rr < 2; ++rr) {
      int rslot = 2 * w + rr;
      int r = rowBase + rslot;
      int s = rs[r], e = rs[r + 1];
      float acc[12];
#pragma unroll
      for (int k = 0; k < 12; ++k) acc[k] = 0.f;

      int p = s;
      for (; p + 1 < e; p += 2) {       // 2 independent table-row streams
        float2 a = cv[p];
        float2 c2 = cv[p + 1];
        const char* ta = (const char*)T2 + (size_t)__float_as_uint(a.x);
        const char* tb = (const char*)T2 + (size_t)__float_as_uint(c2.x);
        float va = a.y, vb = c2.y;
#pragma unroll
        for (int j = 0; j < 3; ++j) {
          float4 t0 = *(const float4*)(ta + lane * 16 + j * 1024);
          float4 t1 = *(const float4*)(tb + lane * 16 + j * 1024);
          acc[4 * j + 0] += va * t0.x + vb * t1.x;
          acc[4 * j + 1] += va * t0.y + vb * t1.y;
          acc[4 * j + 2] += va * t0.z + vb * t1.z;
          acc[4 * j + 3] += va * t0.w + vb * t1.w;
        }
      }
      if (p < e) {
        float2 a = cv[p];
        const char* ta = (const char*)T2 + (size_t)__float_as_uint(a.x);
        float va = a.y;
#pragma unroll
        for (int j = 0; j < 3; ++j) {
          float4 t0 = *(const float4*)(ta + lane * 16 + j * 1024);
          acc[4 * j + 0] += va * t0.x;
          acc[4 * j + 1] += va * t0.y;
          acc[4 * j + 2] += va * t0.z;
          acc[4 * j + 3] += va * t0.w;
        }
      }
#pragma unroll
      for (int j = 0; j < 3; ++j) {
        union { __hip_bfloat16 h[2]; unsigned u; } pr, pi;
        pr.h[0] = __float2bfloat16(acc[4 * j + 0]);
        pr.h[1] = __float2bfloat16(acc[4 * j + 2]);
        pi.h[0] = __float2bfloat16(acc[4 * j + 1]);
        pi.h[1] = __float2bfloat16(acc[4 * j + 3]);
        int x = 2 * lane + 128 * j;
        *(unsigned*)&lre[rslot][x] = pr.u;
        *(unsigned*)&lim[rslot][x] = pi.u;
      }
    }
    __syncthreads();
    for (int x = tid; x < HALF; x += 256) {
      union { ushort h[8]; uint4 v; } ur, ui;
#pragma unroll
      for (int k = 0; k < 8; ++k) {
        ur.h[k] = *(const ushort*)&lre[k][x];
        ui.h[k] = *(const ushort*)&lim[k][x];
      }
      __hip_bfloat16* dst = BTb + (size_t)x * KDIM + rowBase;
      *(uint4*)dst         = ur.v;
      *(uint4*)(dst + DIM) = ui.v;
    }
    __syncthreads();
  }
}

// ---------------------------------------------------------------------------
// Kernel C: nyq blocks FIRST (bid < 128), then quadrant GEMM with the
// depth-3 counted-vmcnt pipeline + T2 LDS XOR-swizzle (both-sides, rule #21):
//   physical 16B slot = logical slot ^ ((row>>1)&3)
//   write side: inverse-permuted GLOBAL source, linear LDS dest (gload_lds)
//   read side : xslot = lhi ^ ((llo>>1)&3)  (lane-constant)
// ---------------------------------------------------------------------------
__device__ inline void gload_lds16(const void* g, void* l) {
  __builtin_amdgcn_global_load_lds((const __attribute__((address_space(1))) void*)g,
                                   (__attribute__((address_space(3))) void*)l, 16, 0, 0);
}

__global__ __launch_bounds__(256) void gemm_kernel(const __hip_bfloat16* __restrict__ A,
                                                   const __hip_bfloat16* __restrict__ BT,
                                                   const int* __restrict__ row_start,
                                                   const float2* __restrict__ s_cv,
                                                   float* __restrict__ C) {
  int bid = blockIdx.x;
  int tid = threadIdx.x;
  __shared__ __align__(16) __hip_bfloat16 As[4][64 * 32];   // 16KB
  __shared__ __align__(16) __hip_bfloat16 Bs[4][64 * 32];   // 16KB

  if (bid < 4 * NB) {                 // ---- Nyquist blocks (overlap the GEMM) ----
    int slice = bid & 3, b = bid >> 2;
    float* ob = C + (size_t)b * DIM * DIM;
    if (slice == 3) {                 // row y=384: sum_r (-1)^r Re[r,x] from BT
      for (int x = tid; x < HALF; x += 256) {
        const __hip_bfloat16* btx = BT + ((size_t)(b * HALF + x)) * KDIM;
        float acc = 0.f;
        for (int r = 0; r < DIM; r += 8) {
          union { uint4 v4; __hip_bfloat16 h[8]; } u;
          u.v4 = *(const uint4*)(btx + r);
#pragma unroll
          for (int q = 0; q < 8; ++q) {
            float v = __bfloat162float(u.h[q]);
            acc += (q & 1) ? -v : v;
          }
        }
        int xm = x ? DIM - x : 0;
        ob[(size_t)HALF * DIM + x]  = acc;
        ob[(size_t)HALF * DIM + xm] = acc;
      }
      return;
    }
    // slices 0..2: column x=384
    float* Re384 = (float*)As;        // reuse LDS
    const int* rs = row_start + b * (DIM + 1);
    const float2* cv = s_cv + b * 4096;
    for (int r = tid; r < DIM; r += 256) {
      int s = rs[r], e = rs[r + 1];
      float acc = 0.f;
      for (int p = s; p < e; ++p) {
        float2 c = cv[p];
        int ci = (int)(__float_as_uint(c.x) / 3072u);
        acc += (ci & 1) ? -c.y : c.y;
      }
      Re384[r] = acc;
    }
    __syncthreads();
    int y = slice * 129 + tid;
    if (tid < 129 && y <= HALF) {
      float yf = (float)y;
      float a0 = 0.f, a1 = 0.f, a2 = 0.f, a3 = 0.f;   // 4 independent chains
      for (int r = 0; r < DIM; r += 4) {
        float f0, f1, f2, f3, c0, c1, c2, c3;
        float v0 = (yf * (float)(r + 0)) * INV768;
        float v1 = (yf * (float)(r + 1)) * INV768;
        float v2 = (yf * (float)(r + 2)) * INV768;
        float v3 = (yf * (float)(r + 3)) * INV768;
        asm("v_fract_f32 %0, %1" : "=v"(f0) : "v"(v0));
        asm("v_fract_f32 %0, %1" : "=v"(f1) : "v"(v1));
        asm("v_fract_f32 %0, %1" : "=v"(f2) : "v"(v2));
        asm("v_fract_f32 %0, %1" : "=v"(f3) : "v"(v3));
        asm("v_cos_f32 %0, %1" : "=v"(c0) : "v"(f0));
        asm("v_cos_f32 %0, %1" : "=v"(c1) : "v"(f1));
        asm("v_cos_f32 %0, %1" : "=v"(c2) : "v"(f2));
        asm("v_cos_f32 %0, %1" : "=v"(c3) : "v"(f3));
        a0 += Re384[r + 0] * c0;
        a1 += Re384[r + 1] * c1;
        a2 += Re384[r + 2] * c2;
        a3 += Re384[r + 3] * c3;
      }
      float acc = (a0 + a1) + (a2 + a3);
      int ym = y ? DIM - y : 0;
      ob[(size_t)y  * DIM + HALF] = acc;
      ob[(size_t)ym * DIM + HALF] = acc;
    }
    return;
  }

  // ---- GEMM blocks ----
  int gbid = bid - 4 * NB;
  int swz = (gbid & 7) * 144 + (gbid >> 3);
  int b = swz / 36; int rem = swz - b * 36;
  int bx = rem / 6, by = rem % 6;

  const __hip_bfloat16* Bp = BT + (size_t)b * HALF * KDIM;
  float* Cp = C + (size_t)b * DIM * DIM;
  int y0 = by * 64, x0 = bx * 64;

  int wv = tid >> 6, lane = tid & 63;
  int wr = wv >> 1, wc = wv & 1;        // wave: 32x32 sub-tile
  int lhi = lane >> 4, llo = lane & 15;
  int arow = tid >> 2;
  // write-side swizzle: thread (row=tid>>2, pslot=tid&3) sources logical slot
  // pslot ^ ((row>>1)&3)   [same cachelines -> coalescing unchanged]
  int soff = (((tid & 3) ^ ((tid >> 3) & 3))) * 8;
  // read-side swizzle: physical slot for logical lhi of row (..+llo)
  int xslot8 = (lhi ^ ((llo >> 1) & 3)) * 8;

  f32x4 acc1[2][2] = {};
  f32x4 acc2[2][2] = {};

  const __hip_bfloat16* Aip = A  + (size_t)(y0 + arow) * KDIM + soff;
  const __hip_bfloat16* Bip = Bp + (size_t)(x0 + arow) * KDIM + soff;

  auto stage = [&](int t) {             // 2 vmem instr per wave
    int buf = t & 3;
    int kt = t * 32;
    gload_lds16(Aip + kt, As[buf] + tid * 8);
    gload_lds16(Bip + kt, Bs[buf] + tid * 8);
  };
  auto compute = [&](int t, f32x4 (&acc)[2][2]) {
    int buf = t & 3;
    bf16x8 af[2], bfr[2];
#pragma unroll
    for (int i = 0; i < 2; ++i)
      af[i] = *(const bf16x8*)(As[buf] + (wr * 32 + i * 16 + llo) * 32 + xslot8);
#pragma unroll
    for (int j = 0; j < 2; ++j)
      bfr[j] = *(const bf16x8*)(Bs[buf] + (wc * 32 + j * 16 + llo) * 32 + xslot8);
#pragma unroll
    for (int i = 0; i < 2; ++i)
#pragma unroll
      for (int j = 0; j < 2; ++j)
        acc[i][j] = __builtin_amdgcn_mfma_f32_16x16x32_bf16(af[i], bfr[j], acc[i][j], 0, 0, 0);
  };

  stage(0); stage(1); stage(2);         // depth-3 prologue (6 vmem in flight)

  for (int t = 0; t < 24; ++t) {        // cos/Re half
    asm volatile("s_waitcnt vmcnt(4)" ::: "memory");   // wait stage t only
    __builtin_amdgcn_s_barrier();
    __builtin_amdgcn_sched_barrier(0);
    stage(t + 3);
    compute(t, acc1);
  }
  for (int t = 24; t < 46; ++t) {       // sin/-Im half
    asm volatile("s_waitcnt vmcnt(4)" ::: "memory");
    __builtin_amdgcn_s_barrier();
    __builtin_amdgcn_sched_barrier(0);
    if (t < 45) stage(t + 3);
    compute(t, acc2);
  }
  asm volatile("s_waitcnt vmcnt(2)" ::: "memory");     // tail: stage 46
  __builtin_amdgcn_s_barrier();
  __builtin_amdgcn_sched_barrier(0);
  compute(46, acc2);
  asm volatile("s_waitcnt vmcnt(0)" ::: "memory");     // tail: stage 47
  __builtin_amdgcn_s_barrier();
  __builtin_amdgcn_sched_barrier(0);
  compute(47, acc2);

  // C/D layout: col = lane&15, row = (lane>>4)*4 + reg   [m89-verified]
#pragma unroll
  for (int i = 0; i < 2; ++i) {
#pragma unroll
    for (int j = 0; j < 2; ++j) {
      int x = x0 + wc * 32 + j * 16 + llo;
      int xm = x ? DIM - x : 0;
#pragma unroll
      for (int q = 0; q < 4; ++q) {
        int y = y0 + wr * 32 + i * 16 + lhi * 4 + q;
        int ym = y ? DIM - y : 0;
        float c1 = acc1[i][j][q], c2 = acc2[i][j][q];
        float vd = c1 + c2;
        float vs = c1 - c2;
        Cp[(size_t)y  * DIM + x]  = vd;
        Cp[(size_t)ym * DIM + xm] = vd;
        Cp[(size_t)y  * DIM + xm] = vs;
        Cp[(size_t)ym * DIM + x]  = vs;
      }
    }
  }
}

// ---------------------------------------------------------------------------
extern "C" void kernel_launch(void* const* d_in, const int* in_sizes, int n_in,
                              void* d_out, int out_size, void* d_ws, size_t ws_size,
                              hipStream_t stream) {
  const float* cls   = (const float*)d_in[0];
  const float* Wr    = (const float*)d_in[1];
  const float* br    = (const float*)d_in[2];
  const float* coeff = (const float*)d_in[3];
  const int*   lidx  = (const int*)d_in[4];
  float* out = (float*)d_out;

  char* ws = (char*)d_ws;
  int*    row_start = (int*)(ws + 0);           //    98,432
  float2* s_cv      = (float2*)(ws + 98944);    // 1,048,576 (ends 1,147,520)
  __hip_bfloat16* A  = (__hip_bfloat16*)(ws + 1147520);  // 1,179,648 (ends 2,327,168)
  float2* T2        = (float2*)(ws + 2327168);  // 2,359,296 (ends 4,686,464)
  __hip_bfloat16* BT = (__hip_bfloat16*)(ws + 4686464);  // 37,748,736 (~42.4 MB total)

  prep_kernel<<<32 + HALF + DIM, 256, 0, stream>>>(cls, Wr, br, coeff, lidx,
                                                   row_start, s_cv, A, T2);
  stage1_kernel<<<dim3(48, NB), 256, 0, stream>>>(row_start, s_cv, T2, BT);
  gemm_kernel<<<4 * NB + 1152, 256, 0, stream>>>(A, BT, row_start, s_cv, out);
}

// Round 10
// 115.922 us; speedup vs baseline: 5.4912x; 1.1054x over previous
//
#include <hip/hip_runtime.h>
#include <hip/hip_bf16.h>

#define DIM 768
#define NE 64
#define NFRQ 2048
#define NB 32
#define HALF 384                // computed quadrant extent (y,x in [0,384))
#define KROW 1536               // BT per-x row elems: [ReP|-ImP|ReM|-ImM] x 384
#define KG 768                  // GEMM K per parity (384 cos + 384 sin)
#define TWO_PI 6.283185307179586f
#define INV768 (1.0f / 768.0f)
#define SCALE (300.0f / (float)(DIM * DIM))   // ALPHA / (dim*dim), folded into values

typedef __attribute__((ext_vector_type(8))) short bf16x8;   // 8 bf16 (4 VGPRs)
typedef __attribute__((ext_vector_type(4))) float f32x4;    // MFMA accumulator

// ---------------------------------------------------------------------------
// Kernel A "prep" (one launch, 3 roles by blockIdx):
//  bid <  32        : fused router (logits->top2->weights) + bucket-sort build
//  32 <= bid < 416  : A twiddle row idx = bid-32: par=idx/192, t=idx%192,
//                     y=2t+par; row = [cos(2pi y r/768) r<384 | sin(...)]
//  bid >= 416       : T2 table row c = bid-416: float2 (cos(2pi c x/768), -sin)
// s_cv entries are (uint byte-offset c*3072 as float bits, weighted val).
// ---------------------------------------------------------------------------
__global__ __launch_bounds__(256) void prep_kernel(const float* __restrict__ cls,
                                                   const float* __restrict__ W,
                                                   const float* __restrict__ bias,
                                                   const float* __restrict__ coeff,
                                                   const int* __restrict__ lidx,
                                                   int* __restrict__ row_start,
                                                   float2* __restrict__ s_cv,
                                                   __hip_bfloat16* __restrict__ A,
                                                   float2* __restrict__ T2) {
  int bid = blockIdx.x;
  int tid = threadIdx.x;

  if (bid >= 32 + 2 * 192) {          // ---- T2 rows ----
    int c = bid - (32 + 2 * 192);     // 0..767
    for (int x = tid; x < HALF; x += 256) {
      float prod = (float)(c * x);    // < 2^24, exact
      float f, sn, cs;
      float rev = prod * INV768;
      asm("v_fract_f32 %0, %1" : "=v"(f) : "v"(rev));
      asm("v_sin_f32 %0, %1" : "=v"(sn) : "v"(f));
      asm("v_cos_f32 %0, %1" : "=v"(cs) : "v"(f));
      T2[(size_t)c * HALF + x] = make_float2(cs, -sn);
    }
    return;
  }
  if (bid >= 32) {                    // ---- A twiddle rows (parity layout) ----
    int idx = bid - 32;               // 0..383 ; row idx = par*192 + t
    int y = 2 * (idx % 192) + (idx / 192);
    if (tid < 96) {
      int r0 = tid * 4;
      union { __hip_bfloat16 h[4]; ushort4 v; } uc, us;
#pragma unroll
      for (int j = 0; j < 4; ++j) {
        int m = (y * (r0 + j)) % DIM;
        float s, c;
        sincosf((TWO_PI / (float)DIM) * (float)m, &s, &c);
        uc.h[j] = __float2bfloat16(c);
        us.h[j] = __float2bfloat16(s);
      }
      *(ushort4*)(A + (size_t)idx * KG + r0)        = uc.v;
      *(ushort4*)(A + (size_t)idx * KG + HALF + r0) = us.v;
    }
    return;
  }

  // ---- router + build, batch b = bid ----
  int b = bid;
  __shared__ int cnt[DIM];
  __shared__ int base[DIM];
  __shared__ int wsum[4];
  __shared__ int sel_i[2];
  __shared__ float sel_f[2];
  float* part   = (float*)cnt;
  float* logits = (float*)base;

  {
    int e = tid & 63, q = tid >> 6;
    const float* c = cls + b * DIM + q * 192;
    const float* w = W + e * DIM + q * 192;
    float acc = 0.f;
#pragma unroll 4
    for (int i = 0; i < 192; i += 4) {
      float4 cv4 = *(const float4*)(c + i);
      float4 wv4 = *(const float4*)(w + i);
      acc += cv4.x * wv4.x + cv4.y * wv4.y + cv4.z * wv4.z + cv4.w * wv4.w;
    }
    part[q * 64 + e] = acc;
    __syncthreads();
    if (tid < NE)
      logits[tid] = part[tid] + part[64 + tid] + part[128 + tid] + part[192 + tid] + bias[tid];
    __syncthreads();
    if (tid == 0) {
      int i0 = 0; float l0 = logits[0];
      for (int i = 1; i < NE; ++i) { float v = logits[i]; if (v > l0) { l0 = v; i0 = i; } }
      int i1 = -1; float l1 = -3.4e38f;
      for (int i = 0; i < NE; ++i) {
        if (i == i0) continue;
        float v = logits[i]; if (v > l1) { l1 = v; i1 = i; }
      }
      float w0 = 1.f / (1.f + expf(l1 - l0));
      sel_i[0] = i0; sel_i[1] = i1;
      sel_f[0] = w0; sel_f[1] = 1.f - w0;
    }
    __syncthreads();
  }
  int e0 = sel_i[0], e1 = sel_i[1];
  float w0 = sel_f[0], w1 = sel_f[1];

  for (int i = tid; i < DIM; i += 256) cnt[i] = 0;
  __syncthreads();
  for (int k = tid; k < 2 * NFRQ; k += 256) {
    int t = k >> 11, j = k & (NFRQ - 1);
    int e = t ? e1 : e0;
    int f = lidx[e * NFRQ + j];
    atomicAdd(&cnt[f / DIM], 1);
  }
  __syncthreads();
  {  // parallel exclusive scan of cnt[768]: 3 per thread
    int s0 = cnt[3 * tid], s1 = cnt[3 * tid + 1], s2 = cnt[3 * tid + 2];
    int sum = s0 + s1 + s2;
    int lane = tid & 63, wid = tid >> 6;
    int v = sum;
#pragma unroll
    for (int d = 1; d < 64; d <<= 1) {
      int u = __shfl_up(v, d);
      if (lane >= d) v += u;
    }
    if (lane == 63) wsum[wid] = v;
    __syncthreads();
    int woff = 0;
#pragma unroll
    for (int w = 0; w < 4; ++w) if (w < wid) woff += wsum[w];
    int excl = woff + v - sum;
    int* rsg = row_start + b * (DIM + 1);
    base[3 * tid]     = excl;
    base[3 * tid + 1] = excl + s0;
    base[3 * tid + 2] = excl + s0 + s1;
    rsg[3 * tid]     = excl;
    rsg[3 * tid + 1] = excl + s0;
    rsg[3 * tid + 2] = excl + s0 + s1;
    if (tid == 255) rsg[DIM] = excl + sum;   // == 4096
  }
  __syncthreads();
  for (int i = tid; i < DIM; i += 256) cnt[i] = 0;
  __syncthreads();
  for (int k = tid; k < 2 * NFRQ; k += 256) {
    int t = k >> 11, j = k & (NFRQ - 1);
    int e = t ? e1 : e0;
    float w = t ? w1 : w0;
    int f = lidx[e * NFRQ + j];
    int r = f / DIM, c = f - r * DIM;
    int pos = base[r] + atomicAdd(&cnt[r], 1);
    s_cv[b * 4096 + pos] = make_float2(__uint_as_float((unsigned)c * 3072u),
                                       coeff[e * NFRQ + j] * w * SCALE);
  }
}

// ---------------------------------------------------------------------------
// Kernel B: stage-1 SpMM over T2 with PARITY COMBINE.
// Pair rp pairs rows (rp, rp+384); dual-stream both rows' nonzeros (2x ILP),
// then write P = A+B, M = A-B to BT row [x]: [ReP|-ImP|ReM|-ImM] (KROW=1536).
// Grid (48, 32): block = 8 pairs, 4 waves x 2 pairs.
// ---------------------------------------------------------------------------
__global__ __launch_bounds__(256) void stage1_kernel(const int* __restrict__ row_start,
                                                     const float2* __restrict__ s_cv,
                                                     const float2* __restrict__ T2,
                                                     __hip_bfloat16* __restrict__ BT) {
  int b = blockIdx.y;
  int rg = blockIdx.x;                  // 0..47 -> pairs rg*8..rg*8+7
  int tid = threadIdx.x;
  int lane = tid & 63, w = tid >> 6;
  __shared__ __hip_bfloat16 lreP[8][HALF];
  __shared__ __hip_bfloat16 limP[8][HALF];
  __shared__ __hip_bfloat16 lreM[8][HALF];
  __shared__ __hip_bfloat16 limM[8][HALF];
  const int* rs = row_start + b * (DIM + 1);
  const float2* cv = s_cv + b * 4096;
  __hip_bfloat16* BTb = BT + (size_t)b * HALF * KROW;
  int rowBase = rg * 8;

#pragma unroll
  for (int rr = 0; rr < 2; ++rr) {
    int rslot = 2 * w + rr;
    int rp = rowBase + rslot;
    int sA = rs[rp],       eA = rs[rp + 1];
    int sB = rs[rp + 384], eB = rs[rp + 385];
    float accA[12], accB[12];
#pragma unroll
    for (int k = 0; k < 12; ++k) { accA[k] = 0.f; accB[k] = 0.f; }

    int pa = sA, pb = sB;
    for (; pa < eA && pb < eB; ++pa, ++pb) {    // dual independent streams
      float2 a  = cv[pa];
      float2 bq = cv[pb];
      const char* ta = (const char*)T2 + (size_t)__float_as_uint(a.x);
      const char* tb = (const char*)T2 + (size_t)__float_as_uint(bq.x);
      float va = a.y, vb = bq.y;
#pragma unroll
      for (int j = 0; j < 3; ++j) {
        float4 t0 = *(const float4*)(ta + lane * 16 + j * 1024);
        float4 t1 = *(const float4*)(tb + lane * 16 + j * 1024);
        accA[4 * j + 0] += va * t0.x; accB[4 * j + 0] += vb * t1.x;
        accA[4 * j + 1] += va * t0.y; accB[4 * j + 1] += vb * t1.y;
        accA[4 * j + 2] += va * t0.z; accB[4 * j + 2] += vb * t1.z;
        accA[4 * j + 3] += va * t0.w; accB[4 * j + 3] += vb * t1.w;
      }
    }
    for (; pa < eA; ++pa) {
      float2 a = cv[pa];
      const char* ta = (const char*)T2 + (size_t)__float_as_uint(a.x);
      float va = a.y;
#pragma unroll
      for (int j = 0; j < 3; ++j) {
        float4 t0 = *(const float4*)(ta + lane * 16 + j * 1024);
        accA[4 * j + 0] += va * t0.x;
        accA[4 * j + 1] += va * t0.y;
        accA[4 * j + 2] += va * t0.z;
        accA[4 * j + 3] += va * t0.w;
      }
    }
    for (; pb < eB; ++pb) {
      float2 bq = cv[pb];
      const char* tb = (const char*)T2 + (size_t)__float_as_uint(bq.x);
      float vb = bq.y;
#pragma unroll
      for (int j = 0; j < 3; ++j) {
        float4 t1 = *(const float4*)(tb + lane * 16 + j * 1024);
        accB[4 * j + 0] += vb * t1.x;
        accB[4 * j + 1] += vb * t1.y;
        accB[4 * j + 2] += vb * t1.z;
        accB[4 * j + 3] += vb * t1.w;
      }
    }
    // combine P = A+B, M = A-B; layout per j: [0]=re(x0) [1]=-im(x0) [2]=re(x1) [3]=-im(x1)
#pragma unroll
    for (int j = 0; j < 3; ++j) {
      union { __hip_bfloat16 h[2]; unsigned u; } rP, iP, rM, iM;
      rP.h[0] = __float2bfloat16(accA[4 * j + 0] + accB[4 * j + 0]);
      rP.h[1] = __float2bfloat16(accA[4 * j + 2] + accB[4 * j + 2]);
      iP.h[0] = __float2bfloat16(accA[4 * j + 1] + accB[4 * j + 1]);
      iP.h[1] = __float2bfloat16(accA[4 * j + 3] + accB[4 * j + 3]);
      rM.h[0] = __float2bfloat16(accA[4 * j + 0] - accB[4 * j + 0]);
      rM.h[1] = __float2bfloat16(accA[4 * j + 2] - accB[4 * j + 2]);
      iM.h[0] = __float2bfloat16(accA[4 * j + 1] - accB[4 * j + 1]);
      iM.h[1] = __float2bfloat16(accA[4 * j + 3] - accB[4 * j + 3]);
      int x = 2 * lane + 128 * j;
      *(unsigned*)&lreP[rslot][x] = rP.u;
      *(unsigned*)&limP[rslot][x] = iP.u;
      *(unsigned*)&lreM[rslot][x] = rM.u;
      *(unsigned*)&limM[rslot][x] = iM.u;
    }
  }
  __syncthreads();
  for (int x = tid; x < HALF; x += 256) {
    union { ushort h[8]; uint4 v; } uP, vP, uM, vM;
#pragma unroll
    for (int k = 0; k < 8; ++k) {
      uP.h[k] = *(const ushort*)&lreP[k][x];
      vP.h[k] = *(const ushort*)&limP[k][x];
      uM.h[k] = *(const ushort*)&lreM[k][x];
      vM.h[k] = *(const ushort*)&limM[k][x];
    }
    __hip_bfloat16* dst = BTb + (size_t)x * KROW + rowBase;
    *(uint4*)(dst)        = uP.v;
    *(uint4*)(dst + 384)  = vP.v;
    *(uint4*)(dst + 768)  = uM.v;
    *(uint4*)(dst + 1152) = vM.v;
  }
}

// ---------------------------------------------------------------------------
// Kernel C: nyq blocks (bid<128) + parity quadrant GEMM (K=768, 24 steps,
// depth-3 counted-vmcnt pipeline, LDS XOR swizzle both-sides).
//   acc1 = A_cos . ReP/M  (t<12);  acc2 = A_sin . (-ImP/M)  (t>=12)
//   y = 2*tt+par; out[y,x]=out[-y,-x]=acc1+acc2 ; out[-y,x]=out[y,-x]=acc1-acc2
// ---------------------------------------------------------------------------
__device__ inline void gload_lds16(const void* g, void* l) {
  __builtin_amdgcn_global_load_lds((const __attribute__((address_space(1))) void*)g,
                                   (__attribute__((address_space(3))) void*)l, 16, 0, 0);
}

__global__ __launch_bounds__(256) void gemm_kernel(const __hip_bfloat16* __restrict__ A,
                                                   const __hip_bfloat16* __restrict__ BT,
                                                   const int* __restrict__ row_start,
                                                   const float2* __restrict__ s_cv,
                                                   float* __restrict__ C) {
  int bid = blockIdx.x;
  int tid = threadIdx.x;
  __shared__ __align__(16) __hip_bfloat16 As[4][64 * 32];   // 16KB
  __shared__ __align__(16) __hip_bfloat16 Bs[4][64 * 32];   // 16KB

  if (bid < 4 * NB) {                 // ---- Nyquist blocks ----
    int slice = bid & 3, b = bid >> 2;
    float* ob = C + (size_t)b * DIM * DIM;
    if (slice == 3) {                 // row y=384: sum_rp (-1)^rp ReP[rp,x]
      for (int x = tid; x < HALF; x += 256) {
        const __hip_bfloat16* btx = BT + ((size_t)(b * HALF + x)) * KROW;
        float acc = 0.f;
        for (int r = 0; r < HALF; r += 8) {
          union { uint4 v4; __hip_bfloat16 h[8]; } u;
          u.v4 = *(const uint4*)(btx + r);
#pragma unroll
          for (int q = 0; q < 8; ++q) {
            float v = __bfloat162float(u.h[q]);
            acc += (q & 1) ? -v : v;
          }
        }
        int xm = x ? DIM - x : 0;
        ob[(size_t)HALF * DIM + x]  = acc;
        ob[(size_t)HALF * DIM + xm] = acc;
      }
      return;
    }
    // slices 0..2: column x=384
    float* Re384 = (float*)As;        // reuse LDS
    const int* rs = row_start + b * (DIM + 1);
    const float2* cv = s_cv + b * 4096;
    for (int r = tid; r < DIM; r += 256) {
      int s = rs[r], e = rs[r + 1];
      float acc = 0.f;
      for (int p = s; p < e; ++p) {
        float2 c = cv[p];
        int ci = (int)(__float_as_uint(c.x) / 3072u);
        acc += (ci & 1) ? -c.y : c.y;
      }
      Re384[r] = acc;
    }
    __syncthreads();
    int y = slice * 129 + tid;
    if (tid < 129 && y <= HALF) {
      float yf = (float)y;
      float a0 = 0.f, a1 = 0.f, a2 = 0.f, a3 = 0.f;
      for (int r = 0; r < DIM; r += 4) {
        float f0, f1, f2, f3, c0, c1, c2, c3;
        float v0 = (yf * (float)(r + 0)) * INV768;
        float v1 = (yf * (float)(r + 1)) * INV768;
        float v2 = (yf * (float)(r + 2)) * INV768;
        float v3 = (yf * (float)(r + 3)) * INV768;
        asm("v_fract_f32 %0, %1" : "=v"(f0) : "v"(v0));
        asm("v_fract_f32 %0, %1" : "=v"(f1) : "v"(v1));
        asm("v_fract_f32 %0, %1" : "=v"(f2) : "v"(v2));
        asm("v_fract_f32 %0, %1" : "=v"(f3) : "v"(v3));
        asm("v_cos_f32 %0, %1" : "=v"(c0) : "v"(f0));
        asm("v_cos_f32 %0, %1" : "=v"(c1) : "v"(f1));
        asm("v_cos_f32 %0, %1" : "=v"(c2) : "v"(f2));
        asm("v_cos_f32 %0, %1" : "=v"(c3) : "v"(f3));
        a0 += Re384[r + 0] * c0;
        a1 += Re384[r + 1] * c1;
        a2 += Re384[r + 2] * c2;
        a3 += Re384[r + 3] * c3;
      }
      float acc = (a0 + a1) + (a2 + a3);
      int ym = y ? DIM - y : 0;
      ob[(size_t)y  * DIM + HALF] = acc;
      ob[(size_t)ym * DIM + HALF] = acc;
    }
    return;
  }

  // ---- GEMM blocks: 1152 = 8*144; 36 tiles/batch = 2 par x 6 bx x 3 by ----
  int gbid = bid - 4 * NB;
  int swz = (gbid & 7) * 144 + (gbid >> 3);
  int b = swz / 36; int rem = swz - b * 36;
  int par = rem / 18; int r2 = rem - par * 18;
  int bx = r2 / 3, by = r2 % 3;

  float* Cp = C + (size_t)b * DIM * DIM;
  int y0 = by * 64, x0 = bx * 64;     // y0 in t-space [0,192)

  int wv = tid >> 6, lane = tid & 63;
  int wr = wv >> 1, wc = wv & 1;      // wave: 32x32 sub-tile
  int lhi = lane >> 4, llo = lane & 15;
  int arow = tid >> 2;
  int soff = (((tid & 3) ^ ((tid >> 3) & 3))) * 8;   // write-side swizzle
  int xslot8 = (lhi ^ ((llo >> 1) & 3)) * 8;         // read-side swizzle

  f32x4 acc1[2][2] = {};
  f32x4 acc2[2][2] = {};

  const __hip_bfloat16* Aip = A  + ((size_t)(par * 192 + y0 + arow)) * KG + soff;
  const __hip_bfloat16* Bip = BT + ((size_t)(b * HALF + x0 + arow)) * KROW + par * KG + soff;

  auto stage = [&](int t) {
    int buf = t & 3;
    int kt = t * 32;
    gload_lds16(Aip + kt, As[buf] + tid * 8);
    gload_lds16(Bip + kt, Bs[buf] + tid * 8);
  };
  auto compute = [&](int t, f32x4 (&acc)[2][2]) {
    int buf = t & 3;
    bf16x8 af[2], bfr[2];
#pragma unroll
    for (int i = 0; i < 2; ++i)
      af[i] = *(const bf16x8*)(As[buf] + (wr * 32 + i * 16 + llo) * 32 + xslot8);
#pragma unroll
    for (int j = 0; j < 2; ++j)
      bfr[j] = *(const bf16x8*)(Bs[buf] + (wc * 32 + j * 16 + llo) * 32 + xslot8);
#pragma unroll
    for (int i = 0; i < 2; ++i)
#pragma unroll
      for (int j = 0; j < 2; ++j)
        acc[i][j] = __builtin_amdgcn_mfma_f32_16x16x32_bf16(af[i], bfr[j], acc[i][j], 0, 0, 0);
  };

  stage(0); stage(1); stage(2);       // depth-3 prologue

  for (int t = 0; t < 12; ++t) {      // cos half
    asm volatile("s_waitcnt vmcnt(4)" ::: "memory");
    __builtin_amdgcn_s_barrier();
    __builtin_amdgcn_sched_barrier(0);
    stage(t + 3);
    compute(t, acc1);
  }
  for (int t = 12; t < 21; ++t) {     // sin half (staged portion)
    asm volatile("s_waitcnt vmcnt(4)" ::: "memory");
    __builtin_amdgcn_s_barrier();
    __builtin_amdgcn_sched_barrier(0);
    stage(t + 3);
    compute(t, acc2);
  }
  asm volatile("s_waitcnt vmcnt(4)" ::: "memory");
  __builtin_amdgcn_s_barrier();
  __builtin_amdgcn_sched_barrier(0);
  compute(21, acc2);
  asm volatile("s_waitcnt vmcnt(2)" ::: "memory");
  __builtin_amdgcn_s_barrier();
  __builtin_amdgcn_sched_barrier(0);
  compute(22, acc2);
  asm volatile("s_waitcnt vmcnt(0)" ::: "memory");
  __builtin_amdgcn_s_barrier();
  __builtin_amdgcn_sched_barrier(0);
  compute(23, acc2);

  // C/D layout: col = lane&15, row = (lane>>4)*4 + reg   [m89-verified]
#pragma unroll
  for (int i = 0; i < 2; ++i) {
#pragma unroll
    for (int j = 0; j < 2; ++j) {
      int x = x0 + wc * 32 + j * 16 + llo;
      int xm = x ? DIM - x : 0;
#pragma unroll
      for (int q = 0; q < 4; ++q) {
        int tt = y0 + wr * 32 + i * 16 + lhi * 4 + q;
        int y = 2 * tt + par;
        int ym = y ? DIM - y : 0;
        float c1 = acc1[i][j][q], c2 = acc2[i][j][q];
        float vd = c1 + c2;
        float vs = c1 - c2;
        Cp[(size_t)y  * DIM + x]  = vd;
        Cp[(size_t)ym * DIM + xm] = vd;
        Cp[(size_t)y  * DIM + xm] = vs;
        Cp[(size_t)ym * DIM + x]  = vs;
      }
    }
  }
}

// ---------------------------------------------------------------------------
extern "C" void kernel_launch(void* const* d_in, const int* in_sizes, int n_in,
                              void* d_out, int out_size, void* d_ws, size_t ws_size,
                              hipStream_t stream) {
  const float* cls   = (const float*)d_in[0];
  const float* Wr    = (const float*)d_in[1];
  const float* br    = (const float*)d_in[2];
  const float* coeff = (const float*)d_in[3];
  const int*   lidx  = (const int*)d_in[4];
  float* out = (float*)d_out;

  char* ws = (char*)d_ws;
  int*    row_start = (int*)(ws + 0);           //    98,432
  float2* s_cv      = (float2*)(ws + 98944);    // 1,048,576 (ends 1,147,520)
  __hip_bfloat16* A  = (__hip_bfloat16*)(ws + 1147520);  // 384*768*2 = 589,824 (ends 1,737,344)
  float2* T2        = (float2*)(ws + 1737344);  // 2,359,296 (ends 4,096,640)
  __hip_bfloat16* BT = (__hip_bfloat16*)(ws + 4096640);  // 32*384*1536*2 = 37,748,736 (~42 MB)

  prep_kernel<<<32 + 384 + DIM, 256, 0, stream>>>(cls, Wr, br, coeff, lidx,
                                                  row_start, s_cv, A, T2);
  stage1_kernel<<<dim3(48, NB), 256, 0, stream>>>(row_start, s_cv, T2, BT);
  gemm_kernel<<<4 * NB + 1152, 256, 0, stream>>>(A, BT, row_start, s_cv, out);
}

// Round 12
// 113.233 us; speedup vs baseline: 5.6215x; 1.0237x over previous
//
#include <hip/hip_runtime.h>
#include <hip/hip_bf16.h>

#define DIM 768
#define NE 64
#define NFRQ 2048
#define NB 32
#define HALF 384                // computed quadrant extent (y,x in [0,384))
#define KROW 1536               // BT per-x row elems: [ReP|-ImP|ReM|-ImM] x 384
#define KG 768                  // GEMM K per parity (384 cos + 384 sin)
#define TWO_PI 6.283185307179586f
#define INV768 (1.0f / 768.0f)
#define SCALE (300.0f / (float)(DIM * DIM))   // ALPHA / (dim*dim), folded into values

typedef __attribute__((ext_vector_type(8))) short bf16x8;   // 8 bf16 (4 VGPRs)
typedef __attribute__((ext_vector_type(4))) float f32x4;    // MFMA accumulator

// ---------------------------------------------------------------------------
// Kernel A "prep" (one launch, 3 roles by blockIdx):
//  bid <  32        : fused router (logits->top2->weights) + bucket-sort build
//  32 <= bid < 416  : A twiddle row idx = bid-32: par=idx/192, t=idx%192,
//                     y=2t+par; row = [cos(2pi y r/768) r<384 | sin(...)]
//  bid >= 416       : T2 table row c = bid-416: float2 (cos(2pi c x/768), -sin)
// s_cv entries are (uint byte-offset c*3072 as float bits, weighted val).
// ---------------------------------------------------------------------------
__global__ __launch_bounds__(256) void prep_kernel(const float* __restrict__ cls,
                                                   const float* __restrict__ W,
                                                   const float* __restrict__ bias,
                                                   const float* __restrict__ coeff,
                                                   const int* __restrict__ lidx,
                                                   int* __restrict__ row_start,
                                                   float2* __restrict__ s_cv,
                                                   __hip_bfloat16* __restrict__ A,
                                                   float2* __restrict__ T2) {
  int bid = blockIdx.x;
  int tid = threadIdx.x;

  if (bid >= 32 + 2 * 192) {          // ---- T2 rows ----
    int c = bid - (32 + 2 * 192);     // 0..767
    for (int x = tid; x < HALF; x += 256) {
      float prod = (float)(c * x);    // < 2^24, exact
      float f, sn, cs;
      float rev = prod * INV768;
      asm("v_fract_f32 %0, %1" : "=v"(f) : "v"(rev));
      asm("v_sin_f32 %0, %1" : "=v"(sn) : "v"(f));
      asm("v_cos_f32 %0, %1" : "=v"(cs) : "v"(f));
      T2[(size_t)c * HALF + x] = make_float2(cs, -sn);
    }
    return;
  }
  if (bid >= 32) {                    // ---- A twiddle rows (parity layout) ----
    int idx = bid - 32;               // 0..383 ; row idx = par*192 + t
    int y = 2 * (idx % 192) + (idx / 192);
    if (tid < 96) {
      int r0 = tid * 4;
      union { __hip_bfloat16 h[4]; ushort4 v; } uc, us;
#pragma unroll
      for (int j = 0; j < 4; ++j) {
        int m = (y * (r0 + j)) % DIM;
        float s, c;
        sincosf((TWO_PI / (float)DIM) * (float)m, &s, &c);
        uc.h[j] = __float2bfloat16(c);
        us.h[j] = __float2bfloat16(s);
      }
      *(ushort4*)(A + (size_t)idx * KG + r0)        = uc.v;
      *(ushort4*)(A + (size_t)idx * KG + HALF + r0) = us.v;
    }
    return;
  }

  // ---- router + build, batch b = bid ----
  int b = bid;
  __shared__ int cnt[DIM];
  __shared__ int base[DIM];
  __shared__ int wsum[4];
  __shared__ int sel_i[2];
  __shared__ float sel_f[2];
  float* part   = (float*)cnt;
  float* logits = (float*)base;

  {
    int e = tid & 63, q = tid >> 6;
    const float* c = cls + b * DIM + q * 192;
    const float* w = W + e * DIM + q * 192;
    float acc = 0.f;
#pragma unroll 4
    for (int i = 0; i < 192; i += 4) {
      float4 cv4 = *(const float4*)(c + i);
      float4 wv4 = *(const float4*)(w + i);
      acc += cv4.x * wv4.x + cv4.y * wv4.y + cv4.z * wv4.z + cv4.w * wv4.w;
    }
    part[q * 64 + e] = acc;
    __syncthreads();
    if (tid < NE)
      logits[tid] = part[tid] + part[64 + tid] + part[128 + tid] + part[192 + tid] + bias[tid];
    __syncthreads();
    if (tid == 0) {
      int i0 = 0; float l0 = logits[0];
      for (int i = 1; i < NE; ++i) { float v = logits[i]; if (v > l0) { l0 = v; i0 = i; } }
      int i1 = -1; float l1 = -3.4e38f;
      for (int i = 0; i < NE; ++i) {
        if (i == i0) continue;
        float v = logits[i]; if (v > l1) { l1 = v; i1 = i; }
      }
      float w0 = 1.f / (1.f + expf(l1 - l0));
      sel_i[0] = i0; sel_i[1] = i1;
      sel_f[0] = w0; sel_f[1] = 1.f - w0;
    }
    __syncthreads();
  }
  int e0 = sel_i[0], e1 = sel_i[1];
  float w0 = sel_f[0], w1 = sel_f[1];

  for (int i = tid; i < DIM; i += 256) cnt[i] = 0;
  __syncthreads();
  for (int k = tid; k < 2 * NFRQ; k += 256) {
    int t = k >> 11, j = k & (NFRQ - 1);
    int e = t ? e1 : e0;
    int f = lidx[e * NFRQ + j];
    atomicAdd(&cnt[f / DIM], 1);
  }
  __syncthreads();
  {  // parallel exclusive scan of cnt[768]: 3 per thread
    int s0 = cnt[3 * tid], s1 = cnt[3 * tid + 1], s2 = cnt[3 * tid + 2];
    int sum = s0 + s1 + s2;
    int lane = tid & 63, wid = tid >> 6;
    int v = sum;
#pragma unroll
    for (int d = 1; d < 64; d <<= 1) {
      int u = __shfl_up(v, d);
      if (lane >= d) v += u;
    }
    if (lane == 63) wsum[wid] = v;
    __syncthreads();
    int woff = 0;
#pragma unroll
    for (int w = 0; w < 4; ++w) if (w < wid) woff += wsum[w];
    int excl = woff + v - sum;
    int* rsg = row_start + b * (DIM + 1);
    base[3 * tid]     = excl;
    base[3 * tid + 1] = excl + s0;
    base[3 * tid + 2] = excl + s0 + s1;
    rsg[3 * tid]     = excl;
    rsg[3 * tid + 1] = excl + s0;
    rsg[3 * tid + 2] = excl + s0 + s1;
    if (tid == 255) rsg[DIM] = excl + sum;   // == 4096
  }
  __syncthreads();
  for (int i = tid; i < DIM; i += 256) cnt[i] = 0;
  __syncthreads();
  for (int k = tid; k < 2 * NFRQ; k += 256) {
    int t = k >> 11, j = k & (NFRQ - 1);
    int e = t ? e1 : e0;
    float w = t ? w1 : w0;
    int f = lidx[e * NFRQ + j];
    int r = f / DIM, c = f - r * DIM;
    int pos = base[r] + atomicAdd(&cnt[r], 1);
    s_cv[b * 4096 + pos] = make_float2(__uint_as_float((unsigned)c * 3072u),
                                       coeff[e * NFRQ + j] * w * SCALE);
  }
}

// ---------------------------------------------------------------------------
// Kernel B: stage-1 SpMM over T2 with PARITY COMBINE.
// Pair rp pairs rows (rp, rp+384); dual-stream both rows' nonzeros (2x ILP),
// then write P = A+B, M = A-B to BT row [x]: [ReP|-ImP|ReM|-ImM] (KROW=1536).
// ---------------------------------------------------------------------------
__global__ __launch_bounds__(256) void stage1_kernel(const int* __restrict__ row_start,
                                                     const float2* __restrict__ s_cv,
                                                     const float2* __restrict__ T2,
                                                     __hip_bfloat16* __restrict__ BT) {
  int b = blockIdx.y;
  int rg = blockIdx.x;                  // 0..47 -> pairs rg*8..rg*8+7
  int tid = threadIdx.x;
  int lane = tid & 63, w = tid >> 6;
  __shared__ __hip_bfloat16 lreP[8][HALF];
  __shared__ __hip_bfloat16 limP[8][HALF];
  __shared__ __hip_bfloat16 lreM[8][HALF];
  __shared__ __hip_bfloat16 limM[8][HALF];
  const int* rs = row_start + b * (DIM + 1);
  const float2* cv = s_cv + b * 4096;
  __hip_bfloat16* BTb = BT + (size_t)b * HALF * KROW;
  int rowBase = rg * 8;

#pragma unroll
  for (int rr = 0; rr < 2; ++rr) {
    int rslot = 2 * w + rr;
    int rp = rowBase + rslot;
    int sA = rs[rp],       eA = rs[rp + 1];
    int sB = rs[rp + 384], eB = rs[rp + 385];
    float accA[12], accB[12];
#pragma unroll
    for (int k = 0; k < 12; ++k) { accA[k] = 0.f; accB[k] = 0.f; }

    int pa = sA, pb = sB;
    for (; pa < eA && pb < eB; ++pa, ++pb) {    // dual independent streams
      float2 a  = cv[pa];
      float2 bq = cv[pb];
      const char* ta = (const char*)T2 + (size_t)__float_as_uint(a.x);
      const char* tb = (const char*)T2 + (size_t)__float_as_uint(bq.x);
      float va = a.y, vb = bq.y;
#pragma unroll
      for (int j = 0; j < 3; ++j) {
        float4 t0 = *(const float4*)(ta + lane * 16 + j * 1024);
        float4 t1 = *(const float4*)(tb + lane * 16 + j * 1024);
        accA[4 * j + 0] += va * t0.x; accB[4 * j + 0] += vb * t1.x;
        accA[4 * j + 1] += va * t0.y; accB[4 * j + 1] += vb * t1.y;
        accA[4 * j + 2] += va * t0.z; accB[4 * j + 2] += vb * t1.z;
        accA[4 * j + 3] += va * t0.w; accB[4 * j + 3] += vb * t1.w;
      }
    }
    for (; pa < eA; ++pa) {
      float2 a = cv[pa];
      const char* ta = (const char*)T2 + (size_t)__float_as_uint(a.x);
      float va = a.y;
#pragma unroll
      for (int j = 0; j < 3; ++j) {
        float4 t0 = *(const float4*)(ta + lane * 16 + j * 1024);
        accA[4 * j + 0] += va * t0.x;
        accA[4 * j + 1] += va * t0.y;
        accA[4 * j + 2] += va * t0.z;
        accA[4 * j + 3] += va * t0.w;
      }
    }
    for (; pb < eB; ++pb) {
      float2 bq = cv[pb];
      const char* tb = (const char*)T2 + (size_t)__float_as_uint(bq.x);
      float vb = bq.y;
#pragma unroll
      for (int j = 0; j < 3; ++j) {
        float4 t1 = *(const float4*)(tb + lane * 16 + j * 1024);
        accB[4 * j + 0] += vb * t1.x;
        accB[4 * j + 1] += vb * t1.y;
        accB[4 * j + 2] += vb * t1.z;
        accB[4 * j + 3] += vb * t1.w;
      }
    }
    // combine P = A+B, M = A-B
#pragma unroll
    for (int j = 0; j < 3; ++j) {
      union { __hip_bfloat16 h[2]; unsigned u; } rP, iP, rM, iM;
      rP.h[0] = __float2bfloat16(accA[4 * j + 0] + accB[4 * j + 0]);
      rP.h[1] = __float2bfloat16(accA[4 * j + 2] + accB[4 * j + 2]);
      iP.h[0] = __float2bfloat16(accA[4 * j + 1] + accB[4 * j + 1]);
      iP.h[1] = __float2bfloat16(accA[4 * j + 3] + accB[4 * j + 3]);
      rM.h[0] = __float2bfloat16(accA[4 * j + 0] - accB[4 * j + 0]);
      rM.h[1] = __float2bfloat16(accA[4 * j + 2] - accB[4 * j + 2]);
      iM.h[0] = __float2bfloat16(accA[4 * j + 1] - accB[4 * j + 1]);
      iM.h[1] = __float2bfloat16(accA[4 * j + 3] - accB[4 * j + 3]);
      int x = 2 * lane + 128 * j;
      *(unsigned*)&lreP[rslot][x] = rP.u;
      *(unsigned*)&limP[rslot][x] = iP.u;
      *(unsigned*)&lreM[rslot][x] = rM.u;
      *(unsigned*)&limM[rslot][x] = iM.u;
    }
  }
  __syncthreads();
  for (int x = tid; x < HALF; x += 256) {
    union { ushort h[8]; uint4 v; } uP, vP, uM, vM;
#pragma unroll
    for (int k = 0; k < 8; ++k) {
      uP.h[k] = *(const ushort*)&lreP[k][x];
      vP.h[k] = *(const ushort*)&limP[k][x];
      uM.h[k] = *(const ushort*)&lreM[k][x];
      vM.h[k] = *(const ushort*)&limM[k][x];
    }
    __hip_bfloat16* dst = BTb + (size_t)x * KROW + rowBase;
    *(uint4*)(dst)        = uP.v;
    *(uint4*)(dst + 384)  = vP.v;
    *(uint4*)(dst + 768)  = uM.v;
    *(uint4*)(dst + 1152) = vM.v;
  }
}

// ---------------------------------------------------------------------------
// Kernel C: nyq blocks (bid<128) + parity quadrant GEMM.
// v3: BK=64, 12 steps, DOUBLE-buffer + __syncthreads (full drain — the
// provably-safe R5 ordering; R11's counted-vmcnt 3-slot raced).
// 8-slot XOR swizzle retained (both-sides, rule #21):
//   phys 16B slot = logical ^ (row&7);  read phys = (lhi+4*kh) ^ (llo&7)
// ---------------------------------------------------------------------------
__device__ inline void gload_lds16(const void* g, void* l) {
  __builtin_amdgcn_global_load_lds((const __attribute__((address_space(1))) void*)g,
                                   (__attribute__((address_space(3))) void*)l, 16, 0, 0);
}

__global__ __launch_bounds__(256) void gemm_kernel(const __hip_bfloat16* __restrict__ A,
                                                   const __hip_bfloat16* __restrict__ BT,
                                                   const int* __restrict__ row_start,
                                                   const float2* __restrict__ s_cv,
                                                   float* __restrict__ C) {
  int bid = blockIdx.x;
  int tid = threadIdx.x;
  __shared__ __align__(16) __hip_bfloat16 As[2][64 * 64];   // 16KB
  __shared__ __align__(16) __hip_bfloat16 Bs[2][64 * 64];   // 16KB

  if (bid < 4 * NB) {                 // ---- Nyquist blocks ----
    int slice = bid & 3, b = bid >> 2;
    float* ob = C + (size_t)b * DIM * DIM;
    if (slice == 3) {                 // row y=384: sum_rp (-1)^rp ReP[rp,x]
      for (int x = tid; x < HALF; x += 256) {
        const __hip_bfloat16* btx = BT + ((size_t)(b * HALF + x)) * KROW;
        float acc = 0.f;
        for (int r = 0; r < HALF; r += 8) {
          union { uint4 v4; __hip_bfloat16 h[8]; } u;
          u.v4 = *(const uint4*)(btx + r);
#pragma unroll
          for (int q = 0; q < 8; ++q) {
            float v = __bfloat162float(u.h[q]);
            acc += (q & 1) ? -v : v;
          }
        }
        int xm = x ? DIM - x : 0;
        ob[(size_t)HALF * DIM + x]  = acc;
        ob[(size_t)HALF * DIM + xm] = acc;
      }
      return;
    }
    // slices 0..2: column x=384
    float* Re384 = (float*)As;        // reuse LDS
    const int* rs = row_start + b * (DIM + 1);
    const float2* cv = s_cv + b * 4096;
    for (int r = tid; r < DIM; r += 256) {
      int s = rs[r], e = rs[r + 1];
      float acc = 0.f;
      for (int p = s; p < e; ++p) {
        float2 c = cv[p];
        int ci = (int)(__float_as_uint(c.x) / 3072u);
        acc += (ci & 1) ? -c.y : c.y;
      }
      Re384[r] = acc;
    }
    __syncthreads();
    int y = slice * 129 + tid;
    if (tid < 129 && y <= HALF) {
      float yf = (float)y;
      float a0 = 0.f, a1 = 0.f, a2 = 0.f, a3 = 0.f;
      for (int r = 0; r < DIM; r += 4) {
        float f0, f1, f2, f3, c0, c1, c2, c3;
        float v0 = (yf * (float)(r + 0)) * INV768;
        float v1 = (yf * (float)(r + 1)) * INV768;
        float v2 = (yf * (float)(r + 2)) * INV768;
        float v3 = (yf * (float)(r + 3)) * INV768;
        asm("v_fract_f32 %0, %1" : "=v"(f0) : "v"(v0));
        asm("v_fract_f32 %0, %1" : "=v"(f1) : "v"(v1));
        asm("v_fract_f32 %0, %1" : "=v"(f2) : "v"(v2));
        asm("v_fract_f32 %0, %1" : "=v"(f3) : "v"(v3));
        asm("v_cos_f32 %0, %1" : "=v"(c0) : "v"(f0));
        asm("v_cos_f32 %0, %1" : "=v"(c1) : "v"(f1));
        asm("v_cos_f32 %0, %1" : "=v"(c2) : "v"(f2));
        asm("v_cos_f32 %0, %1" : "=v"(c3) : "v"(f3));
        a0 += Re384[r + 0] * c0;
        a1 += Re384[r + 1] * c1;
        a2 += Re384[r + 2] * c2;
        a3 += Re384[r + 3] * c3;
      }
      float acc = (a0 + a1) + (a2 + a3);
      int ym = y ? DIM - y : 0;
      ob[(size_t)y  * DIM + HALF] = acc;
      ob[(size_t)ym * DIM + HALF] = acc;
    }
    return;
  }

  // ---- GEMM blocks: 1152 = 8*144; 36 tiles/batch = 2 par x 6 bx x 3 by ----
  int gbid = bid - 4 * NB;
  int swz = (gbid & 7) * 144 + (gbid >> 3);
  int b = swz / 36; int rem = swz - b * 36;
  int par = rem / 18; int r2 = rem - par * 18;
  int bx = r2 / 3, by = r2 % 3;

  float* Cp = C + (size_t)b * DIM * DIM;
  int y0 = by * 64, x0 = bx * 64;     // y0 in t-space [0,192)

  int wv = tid >> 6, lane = tid & 63;
  int wr = wv >> 1, wc = wv & 1;      // wave: 32x32 sub-tile
  int lhi = lane >> 4, llo = lane & 15;

  // staging: chunk c in [0,512): row = c>>3, phys slot = c&7;
  // logical slot at (row,phys) = phys ^ (row&7) -> global elem off ((c&7)^((c>>3)&7))*8
  int c0 = tid, c1 = tid + 256;
  int row0 = c0 >> 3, row1 = c1 >> 3;
  int so0 = (((c0 & 7) ^ (row0 & 7))) * 8;
  int so1 = (((c1 & 7) ^ (row1 & 7))) * 8;

  f32x4 acc1[2][2] = {};
  f32x4 acc2[2][2] = {};

  const __hip_bfloat16* A0 = A  + ((size_t)(par * 192 + y0 + row0)) * KG + so0;
  const __hip_bfloat16* A1 = A  + ((size_t)(par * 192 + y0 + row1)) * KG + so1;
  const __hip_bfloat16* B0 = BT + ((size_t)(b * HALF + x0 + row0)) * KROW + par * KG + so0;
  const __hip_bfloat16* B1 = BT + ((size_t)(b * HALF + x0 + row1)) * KROW + par * KG + so1;

  // prologue: stage kt=0 into buf 0, full drain
  gload_lds16(A0, As[0] + c0 * 8);
  gload_lds16(A1, As[0] + c1 * 8);
  gload_lds16(B0, Bs[0] + c0 * 8);
  gload_lds16(B1, Bs[0] + c1 * 8);
  __syncthreads();

  auto step = [&](int t, f32x4 (&acc)[2][2], bool last) {
    int cur = t & 1;
    if (!last) {                      // issue next-tile loads FIRST
      int ktn = (t + 1) * 64;
      gload_lds16(A0 + ktn, As[cur ^ 1] + c0 * 8);
      gload_lds16(A1 + ktn, As[cur ^ 1] + c1 * 8);
      gload_lds16(B0 + ktn, Bs[cur ^ 1] + c0 * 8);
      gload_lds16(B1 + ktn, Bs[cur ^ 1] + c1 * 8);
    }
    bf16x8 af[2][2], bfr[2][2];
#pragma unroll
    for (int i = 0; i < 2; ++i)
#pragma unroll
      for (int kh = 0; kh < 2; ++kh) {
        int row = wr * 32 + i * 16 + llo;
        int phys = ((lhi + 4 * kh) ^ (llo & 7)) * 8;
        af[i][kh] = *(const bf16x8*)(As[cur] + row * 64 + phys);
      }
#pragma unroll
    for (int j = 0; j < 2; ++j)
#pragma unroll
      for (int kh = 0; kh < 2; ++kh) {
        int row = wc * 32 + j * 16 + llo;
        int phys = ((lhi + 4 * kh) ^ (llo & 7)) * 8;
        bfr[j][kh] = *(const bf16x8*)(Bs[cur] + row * 64 + phys);
      }
#pragma unroll
    for (int kh = 0; kh < 2; ++kh)
#pragma unroll
      for (int i = 0; i < 2; ++i)
#pragma unroll
        for (int j = 0; j < 2; ++j)
          acc[i][j] = __builtin_amdgcn_mfma_f32_16x16x32_bf16(af[i][kh], bfr[j][kh],
                                                              acc[i][j], 0, 0, 0);
    if (!last) __syncthreads();       // full drain: vmcnt(0)+lgkmcnt(0)+barrier
  };

  for (int t = 0; t < 6; ++t)  step(t, acc1, false);       // cos half
  for (int t = 6; t < 12; ++t) step(t, acc2, t == 11);     // sin half

  // C/D layout: col = lane&15, row = (lane>>4)*4 + reg   [m89-verified]
#pragma unroll
  for (int i = 0; i < 2; ++i) {
#pragma unroll
    for (int j = 0; j < 2; ++j) {
      int x = x0 + wc * 32 + j * 16 + llo;
      int xm = x ? DIM - x : 0;
#pragma unroll
      for (int q = 0; q < 4; ++q) {
        int tt = y0 + wr * 32 + i * 16 + lhi * 4 + q;
        int y = 2 * tt + par;
        int ym = y ? DIM - y : 0;
        float c1 = acc1[i][j][q], c2 = acc2[i][j][q];
        float vd = c1 + c2;
        float vs = c1 - c2;
        Cp[(size_t)y  * DIM + x]  = vd;
        Cp[(size_t)ym * DIM + xm] = vd;
        Cp[(size_t)y  * DIM + xm] = vs;
        Cp[(size_t)ym * DIM + x]  = vs;
      }
    }
  }
}

// ---------------------------------------------------------------------------
extern "C" void kernel_launch(void* const* d_in, const int* in_sizes, int n_in,
                              void* d_out, int out_size, void* d_ws, size_t ws_size,
                              hipStream_t stream) {
  const float* cls   = (const float*)d_in[0];
  const float* Wr    = (const float*)d_in[1];
  const float* br    = (const float*)d_in[2];
  const float* coeff = (const float*)d_in[3];
  const int*   lidx  = (const int*)d_in[4];
  float* out = (float*)d_out;

  char* ws = (char*)d_ws;
  int*    row_start = (int*)(ws + 0);           //    98,432
  float2* s_cv      = (float2*)(ws + 98944);    // 1,048,576 (ends 1,147,520)
  __hip_bfloat16* A  = (__hip_bfloat16*)(ws + 1147520);  // 384*768*2 = 589,824 (ends 1,737,344)
  float2* T2        = (float2*)(ws + 1737344);  // 2,359,296 (ends 4,096,640)
  __hip_bfloat16* BT = (__hip_bfloat16*)(ws + 4096640);  // 32*384*1536*2 = 37,748,736 (~42 MB)

  prep_kernel<<<32 + 384 + DIM, 256, 0, stream>>>(cls, Wr, br, coeff, lidx,
                                                  row_start, s_cv, A, T2);
  stage1_kernel<<<dim3(48, NB), 256, 0, stream>>>(row_start, s_cv, T2, BT);
  gemm_kernel<<<4 * NB + 1152, 256, 0, stream>>>(A, BT, row_start, s_cv, out);
}